// Round 9
// baseline (465.674 us; speedup 1.0000x reference)
//
#include <hip/hip_runtime.h>

#define NN 50000
#define NE 800000
#define NG 256
#define NBUCKET 16
#define PARTSZ (NBUCKET * 256)

// bucketed CSR build params
#define NBKT 391      // node buckets of 128 (391*128 = 50048 >= NN)
#define ABLK 391      // A-pass blocks
#define ASLICE 2048   // edges per A-pass block (391*2048 >= NE)
#define BCAP 2560     // LDS staging capacity per bucket (mean 2046, +11 sigma)

// ---------------- prologue ----------------
__global__ void k_init(float* part) {
    int i = blockIdx.x * blockDim.x + threadIdx.x;
    if (i < 5 * PARTSZ) part[i] = 0.f;
}

// A1: per-(block,bucket) edge counts via LDS histogram
__global__ void kA1(const int* __restrict__ col, int* __restrict__ bb, int e) {
    __shared__ int cnt[NBKT];
    for (int j = threadIdx.x; j < NBKT; j += 256) cnt[j] = 0;
    __syncthreads();
    int start = blockIdx.x * ASLICE;
    int end = min(start + ASLICE, e);
    for (int i = start + threadIdx.x; i < end; i += 256)
        atomicAdd(&cnt[col[i] >> 7], 1);
    __syncthreads();
    for (int j = threadIdx.x; j < NBKT; j += 256) bb[blockIdx.x * NBKT + j] = cnt[j];
}

// A2a: per-bucket exclusive scan over blocks (in place), bucket totals out
__global__ void kA2a(int* __restrict__ bb, int* __restrict__ totals) {
    __shared__ int v[ABLK];
    int k = blockIdx.x;
    for (int b = threadIdx.x; b < ABLK; b += 256) v[b] = bb[b * NBKT + k];
    __syncthreads();
    if (threadIdx.x == 0) {
        int run = 0;
        for (int b = 0; b < ABLK; ++b) { int t = v[b]; v[b] = run; run += t; }
        totals[k] = run;
    }
    __syncthreads();
    for (int b = threadIdx.x; b < ABLK; b += 256) bb[b * NBKT + k] = v[b];
}

// A2b: exclusive scan of bucket totals -> bucketbase[NBKT+1]
__global__ void kA2b(const int* __restrict__ totals, int* __restrict__ bucketbase) {
    __shared__ int v[NBKT];
    for (int j = threadIdx.x; j < NBKT; j += 256) v[j] = totals[j];
    __syncthreads();
    if (threadIdx.x == 0) {
        int run = 0;
        for (int k = 0; k < NBKT; ++k) { int t = v[k]; v[k] = run; run += t; }
        bucketbase[NBKT] = run;
    }
    __syncthreads();
    for (int j = threadIdx.x; j < NBKT; j += 256) bucketbase[j] = v[j];
}

// A3: scatter edges into per-(block,bucket) private contiguous staging ranges
__global__ void kA3(const int* __restrict__ row, const int* __restrict__ col,
                    const float* __restrict__ ew, const int* __restrict__ bb,
                    const int* __restrict__ bucketbase, int2* __restrict__ staging, int e) {
    __shared__ int cur[NBKT];
    for (int j = threadIdx.x; j < NBKT; j += 256)
        cur[j] = bucketbase[j] + bb[blockIdx.x * NBKT + j];
    __syncthreads();
    int start = blockIdx.x * ASLICE;
    int end = min(start + ASLICE, e);
    for (int i = start + threadIdx.x; i < end; i += 256) {
        int c = col[i];
        int p = atomicAdd(&cur[c >> 7], 1);
        staging[p] = make_int2(row[i] | ((c & 127) << 16), __float_as_int(ew[i]));
    }
}

// B: per-bucket LDS counting sort -> csr {src, raw_ew}, ptr, deg->dis
__global__ void __launch_bounds__(256) kB(const int* __restrict__ bucketbase,
                                          const int2* __restrict__ staging,
                                          int2* __restrict__ csr, int* __restrict__ ptr,
                                          float* __restrict__ dis, int n) {
    __shared__ int2 st[BCAP];
    __shared__ int2 outb[BCAP];
    __shared__ int hist[129];
    __shared__ int cur[128];
    int k = blockIdx.x, t = threadIdx.x;
    int base = bucketbase[k], cnt = bucketbase[k + 1] - base;
    int node0 = k << 7;
    int ncov = min(128, n - node0);
    if (t < 129) hist[t] = 0;
    __syncthreads();
    if (cnt <= BCAP) {
        for (int i = t; i < cnt; i += 256) {
            int2 v = staging[base + i];
            st[i] = v;
            atomicAdd(&hist[v.x >> 16], 1);
        }
        __syncthreads();
        if (t == 0) {
            int run = 0;
            for (int j = 0; j < 128; ++j) { int h = hist[j]; hist[j] = run; run += h; }
            hist[128] = run;
        }
        __syncthreads();
        if (t < 128) cur[t] = hist[t];
        if (t < ncov) ptr[node0 + t] = base + hist[t];
        __syncthreads();
        for (int i = t; i < cnt; i += 256) {
            int2 v = st[i];
            int j = v.x >> 16;
            int p = atomicAdd(&cur[j], 1);
            outb[p] = make_int2(v.x & 0xFFFF, v.y);
        }
        __syncthreads();
        for (int i = t; i < cnt; i += 256) csr[base + i] = outb[i];
        if (t < ncov) {
            float s = 1.f;
            int a = hist[t], b2 = hist[t + 1];
            for (int p = a; p < b2; ++p) s += __int_as_float(outb[p].y);
            dis[node0 + t] = rsqrtf(s);
        }
    } else {
        for (int i = t; i < cnt; i += 256) atomicAdd(&hist[staging[base + i].x >> 16], 1);
        __syncthreads();
        if (t == 0) {
            int run = 0;
            for (int j = 0; j < 128; ++j) { int h = hist[j]; hist[j] = run; run += h; }
            hist[128] = run;
        }
        __syncthreads();
        if (t < 128) cur[t] = hist[t];
        if (t < ncov) ptr[node0 + t] = base + hist[t];
        __syncthreads();
        for (int i = t; i < cnt; i += 256) {
            int2 v = staging[base + i];
            int j = v.x >> 16;
            int p = atomicAdd(&cur[j], 1);
            csr[base + p] = make_int2(v.x & 0xFFFF, v.y);
        }
        __threadfence_block();
        __syncthreads();
        if (t < ncov) {
            float s = 1.f;
            int a = hist[t], b2 = hist[t + 1];
            for (int p = a; p < b2; ++p) s += __int_as_float(csr[base + p].y);
            dis[node0 + t] = rsqrtf(s);
        }
    }
    if (k == gridDim.x - 1 && t == 0) ptr[n] = bucketbase[NBKT];
}

// ---------------- gather ----------------
// EP: edge-parallel lanes per node (cuts the dependent edge-walk ~EP x).
// Lane layout per node: LPN = TPN*EP lanes; r = e0*TPN + l4. Butterfly-reduce across e0.
// POSTAFF (L2/L3/L4): out = sc*A + sh*(dis^2 + sum w); PREAFF (L5): per-edge relu(sc*u+sh);
// EPI (L1, EP==1 only): out = relu(A + bias), stats -> partOut.
template <int D, int EP, int POSTAFF, int PREAFF, int EPI>
__global__ void k_gather(const float* __restrict__ src, const int* __restrict__ ptr,
                         const int2* __restrict__ csr, const float* __restrict__ dis,
                         const float* __restrict__ partIn, const float* __restrict__ gmv,
                         const float* __restrict__ btv,
                         const float* __restrict__ bias, float* __restrict__ partOut,
                         float* __restrict__ out, int n) {
    const int TPN = D / 4;
    const int LPN = TPN * EP;
    const int CONSUME = POSTAFF || PREAFF;
    __shared__ float ls[EPI ? D : 1], lq[EPI ? D : 1];
    __shared__ float scs[CONSUME ? D : 4], shs[CONSUME ? D : 4];
    int tid = threadIdx.x;
    if (EPI && tid < D) { ls[tid] = 0.f; lq[tid] = 0.f; }
    if (CONSUME && tid < D) {
        float s = 0.f, q = 0.f;
#pragma unroll
        for (int b2 = 0; b2 < NBUCKET; ++b2) {
            s += partIn[b2 * 256 + tid];
            q += partIn[b2 * 256 + 128 + tid];
        }
        float mu = s / (float)n;
        float var = q / (float)n - mu * mu;
        float a = gmv[tid] * rsqrtf(var + 1e-5f);
        scs[tid] = a;
        shs[tid] = btv[tid] - mu * a;
    }
    if (EPI || CONSUME) __syncthreads();

    int t = blockIdx.x * blockDim.x + tid;
    int node = t / LPN;
    int r = t - node * LPN;
    int e0 = r / TPN;
    int l4 = r - e0 * TPN;
    bool valid = node < n;
    int nc = valid ? node : n - 1;

    float4 sc = {0,0,0,0}, sh = {0,0,0,0};
    if (CONSUME) {
        sc = ((const float4*)scs)[l4];
        sh = ((const float4*)shs)[l4];
    }
    const float4* s4 = (const float4*)src;
    float4 acc = {0.f, 0.f, 0.f, 0.f};
    float sumw = 0.f;
    if (e0 == 0) {
        float d = dis[nc];
        float w0 = d * d;
        float4 v = s4[nc * TPN + l4];
        if (PREAFF) {
            v.x = fmaxf(sc.x * v.x + sh.x, 0.f); v.y = fmaxf(sc.y * v.y + sh.y, 0.f);
            v.z = fmaxf(sc.z * v.z + sh.z, 0.f); v.w = fmaxf(sc.w * v.w + sh.w, 0.f);
        }
        acc.x = w0 * v.x; acc.y = w0 * v.y; acc.z = w0 * v.z; acc.w = w0 * v.w;
        sumw = w0;
    }
    int p0 = ptr[nc], p1 = ptr[nc + 1];
    int p = p0 + e0;
    for (; p + 3 * EP < p1; p += 4 * EP) {
        int2 c0 = csr[p], c1 = csr[p + EP], c2 = csr[p + 2 * EP], c3 = csr[p + 3 * EP];
        float e0w = __int_as_float(c0.y), e1w = __int_as_float(c1.y);
        float e2w = __int_as_float(c2.y), e3w = __int_as_float(c3.y);
        float4 u0 = s4[c0.x * TPN + l4];
        float4 u1 = s4[c1.x * TPN + l4];
        float4 u2 = s4[c2.x * TPN + l4];
        float4 u3 = s4[c3.x * TPN + l4];
        if (PREAFF) {
            u0.x = fmaxf(sc.x*u0.x+sh.x,0.f); u0.y = fmaxf(sc.y*u0.y+sh.y,0.f);
            u0.z = fmaxf(sc.z*u0.z+sh.z,0.f); u0.w = fmaxf(sc.w*u0.w+sh.w,0.f);
            u1.x = fmaxf(sc.x*u1.x+sh.x,0.f); u1.y = fmaxf(sc.y*u1.y+sh.y,0.f);
            u1.z = fmaxf(sc.z*u1.z+sh.z,0.f); u1.w = fmaxf(sc.w*u1.w+sh.w,0.f);
            u2.x = fmaxf(sc.x*u2.x+sh.x,0.f); u2.y = fmaxf(sc.y*u2.y+sh.y,0.f);
            u2.z = fmaxf(sc.z*u2.z+sh.z,0.f); u2.w = fmaxf(sc.w*u2.w+sh.w,0.f);
            u3.x = fmaxf(sc.x*u3.x+sh.x,0.f); u3.y = fmaxf(sc.y*u3.y+sh.y,0.f);
            u3.z = fmaxf(sc.z*u3.z+sh.z,0.f); u3.w = fmaxf(sc.w*u3.w+sh.w,0.f);
        }
        acc.x += e0w*u0.x + e1w*u1.x + e2w*u2.x + e3w*u3.x;
        acc.y += e0w*u0.y + e1w*u1.y + e2w*u2.y + e3w*u3.y;
        acc.z += e0w*u0.z + e1w*u1.z + e2w*u2.z + e3w*u3.z;
        acc.w += e0w*u0.w + e1w*u1.w + e2w*u2.w + e3w*u3.w;
        if (POSTAFF) sumw += e0w + e1w + e2w + e3w;
    }
    for (; p < p1; p += EP) {
        int2 ce = csr[p];
        float w = __int_as_float(ce.y);
        float4 u = s4[ce.x * TPN + l4];
        if (PREAFF) {
            u.x = fmaxf(sc.x*u.x+sh.x,0.f); u.y = fmaxf(sc.y*u.y+sh.y,0.f);
            u.z = fmaxf(sc.z*u.z+sh.z,0.f); u.w = fmaxf(sc.w*u.w+sh.w,0.f);
        }
        acc.x += w*u.x; acc.y += w*u.y; acc.z += w*u.z; acc.w += w*u.w;
        if (POSTAFF) sumw += w;
    }
    if (EP > 1) {
#pragma unroll
        for (int off = TPN; off < LPN; off <<= 1) {
            acc.x += __shfl_xor(acc.x, off, 64);
            acc.y += __shfl_xor(acc.y, off, 64);
            acc.z += __shfl_xor(acc.z, off, 64);
            acc.w += __shfl_xor(acc.w, off, 64);
            if (POSTAFF) sumw += __shfl_xor(sumw, off, 64);
        }
    }
    if (POSTAFF) {
        acc.x = sc.x * acc.x + sh.x * sumw;
        acc.y = sc.y * acc.y + sh.y * sumw;
        acc.z = sc.z * acc.z + sh.z * sumw;
        acc.w = sc.w * acc.w + sh.w * sumw;
    }
    if (EPI) {
        float4 b = ((const float4*)bias)[l4];
        acc.x = fmaxf(acc.x + b.x, 0.f);
        acc.y = fmaxf(acc.y + b.y, 0.f);
        acc.z = fmaxf(acc.z + b.z, 0.f);
        acc.w = fmaxf(acc.w + b.w, 0.f);
        if (valid) ((float4*)out)[nc * TPN + l4] = acc;
        float s0 = valid ? acc.x : 0.f, s1 = valid ? acc.y : 0.f;
        float s2 = valid ? acc.z : 0.f, s3 = valid ? acc.w : 0.f;
        float q0 = s0*s0, q1 = s1*s1, q2 = s2*s2, q3 = s3*s3;
        for (int off = TPN; off < 64; off <<= 1) {
            s0 += __shfl_down(s0, off, 64); s1 += __shfl_down(s1, off, 64);
            s2 += __shfl_down(s2, off, 64); s3 += __shfl_down(s3, off, 64);
            q0 += __shfl_down(q0, off, 64); q1 += __shfl_down(q1, off, 64);
            q2 += __shfl_down(q2, off, 64); q3 += __shfl_down(q3, off, 64);
        }
        int lane = tid & 63;
        if (lane < TPN) {
            atomicAdd(&ls[4*lane+0], s0); atomicAdd(&ls[4*lane+1], s1);
            atomicAdd(&ls[4*lane+2], s2); atomicAdd(&ls[4*lane+3], s3);
            atomicAdd(&lq[4*lane+0], q0); atomicAdd(&lq[4*lane+1], q1);
            atomicAdd(&lq[4*lane+2], q2); atomicAdd(&lq[4*lane+3], q3);
        }
        __syncthreads();
        int bkt = (blockIdx.x & (NBUCKET - 1)) * 256;
        if (tid < D) {
            atomicAdd(&partOut[bkt + tid], ls[tid]);
            atomicAdd(&partOut[bkt + 128 + tid], lq[tid]);
        }
    } else {
        if (valid && e0 == 0) ((float4*)out)[nc * TPN + l4] = acc;
    }
}

// ---------------- node-blocked GEMM; SCALE=1 adds extra blocks doing the CSR rescale ----
template <int DIN, int DOUT, int RELU, int EPI, int NPT, int SCALE>
__global__ void k_gemm(const float* __restrict__ h, const float* __restrict__ W,
                       const float* __restrict__ bias, float* __restrict__ partOut,
                       float* __restrict__ m, int n,
                       const int* __restrict__ ptr, int2* __restrict__ csr,
                       const float* __restrict__ dis, int gemmBlocks) {
    if (SCALE && (int)blockIdx.x >= gemmBlocks) {
        int i = ((int)blockIdx.x - gemmBlocks) * 256 + threadIdx.x;
        if (i < n) {
            float dc = dis[i];
            int pp1 = ptr[i + 1];
            for (int p = ptr[i]; p < pp1; ++p) {
                int2 v = csr[p];
                csr[p].y = __float_as_int(dis[v.x] * __int_as_float(v.y) * dc);
            }
        }
        return;
    }
    const int TPN = DOUT / 4;
    const int GPB = 256 / TPN;
    __shared__ float Wl[DIN * DOUT];
    __shared__ float ls[EPI ? DOUT : 1], lq[EPI ? DOUT : 1];
    int tid = threadIdx.x;
    for (int i = tid; i < DIN * DOUT / 4; i += 256)
        ((float4*)Wl)[i] = ((const float4*)W)[i];
    if (EPI && tid < DOUT) { ls[tid] = 0.f; lq[tid] = 0.f; }
    __syncthreads();

    int jq = tid % TPN;
    int group = tid / TPN;
    int node0 = (blockIdx.x * GPB + group) * NPT;
    const float4* h4 = (const float4*)h;
    int hb[NPT];
    bool val[NPT];
#pragma unroll
    for (int i = 0; i < NPT; ++i) {
        int nd = node0 + i;
        val[i] = nd < n;
        hb[i] = (val[i] ? nd : n - 1) * (DIN / 4);
    }
    float4 acc[NPT];
#pragma unroll
    for (int i = 0; i < NPT; ++i) acc[i] = {0.f, 0.f, 0.f, 0.f};

#pragma unroll 4
    for (int k4 = 0; k4 < DIN / 4; ++k4) {
        const float* wb = &Wl[(k4 * 4) * DOUT + jq * 4];
        float4 w0 = *(const float4*)(wb);
        float4 w1 = *(const float4*)(wb + DOUT);
        float4 w2 = *(const float4*)(wb + 2 * DOUT);
        float4 w3 = *(const float4*)(wb + 3 * DOUT);
#pragma unroll
        for (int i = 0; i < NPT; ++i) {
            float4 hv = h4[hb[i] + k4];
            acc[i].x += hv.x*w0.x + hv.y*w1.x + hv.z*w2.x + hv.w*w3.x;
            acc[i].y += hv.x*w0.y + hv.y*w1.y + hv.z*w2.y + hv.w*w3.y;
            acc[i].z += hv.x*w0.z + hv.y*w1.z + hv.z*w2.z + hv.w*w3.z;
            acc[i].w += hv.x*w0.w + hv.y*w1.w + hv.z*w2.w + hv.w*w3.w;
        }
    }

    float4 bv = {0,0,0,0};
    if (EPI) bv = ((const float4*)bias)[jq];
    float4 sv = {0,0,0,0}, qv = {0,0,0,0};
#pragma unroll
    for (int i = 0; i < NPT; ++i) {
        float4 a = acc[i];
        if (EPI) {
            a.x += bv.x; a.y += bv.y; a.z += bv.z; a.w += bv.w;
            if (RELU) {
                a.x = fmaxf(a.x, 0.f); a.y = fmaxf(a.y, 0.f);
                a.z = fmaxf(a.z, 0.f); a.w = fmaxf(a.w, 0.f);
            }
        }
        if (val[i]) {
            ((float4*)m)[(node0 + i) * TPN + jq] = a;
            if (EPI) {
                sv.x += a.x; sv.y += a.y; sv.z += a.z; sv.w += a.w;
                qv.x += a.x*a.x; qv.y += a.y*a.y; qv.z += a.z*a.z; qv.w += a.w*a.w;
            }
        }
    }
    if (EPI) {
        for (int off = TPN; off < 64; off <<= 1) {
            sv.x += __shfl_down(sv.x, off, 64); sv.y += __shfl_down(sv.y, off, 64);
            sv.z += __shfl_down(sv.z, off, 64); sv.w += __shfl_down(sv.w, off, 64);
            qv.x += __shfl_down(qv.x, off, 64); qv.y += __shfl_down(qv.y, off, 64);
            qv.z += __shfl_down(qv.z, off, 64); qv.w += __shfl_down(qv.w, off, 64);
        }
        int lane = tid & 63;
        if (lane < TPN) {
            atomicAdd(&ls[4*lane+0], sv.x); atomicAdd(&ls[4*lane+1], sv.y);
            atomicAdd(&ls[4*lane+2], sv.z); atomicAdd(&ls[4*lane+3], sv.w);
            atomicAdd(&lq[4*lane+0], qv.x); atomicAdd(&lq[4*lane+1], qv.y);
            atomicAdd(&lq[4*lane+2], qv.z); atomicAdd(&lq[4*lane+3], qv.w);
        }
        __syncthreads();
        int bkt = (blockIdx.x & (NBUCKET - 1)) * 256;
        if (tid < DOUT) {
            atomicAdd(&partOut[bkt + tid], ls[tid]);
            atomicAdd(&partOut[bkt + 128 + tid], lq[tid]);
        }
    }
}

// ---------------- fused pool (BN5 consumed inline) + MLP head ----------------
__global__ void k_poolhead(const float* __restrict__ h, const int* __restrict__ batch,
                           const float* __restrict__ partIn, const float* __restrict__ gmv,
                           const float* __restrict__ btv,
                           const float* __restrict__ fc1w, const float* __restrict__ fc1b,
                           const float* __restrict__ fc2w, const float* __restrict__ fc2b,
                           float* __restrict__ out, int n) {
    __shared__ float tmp[256];
    __shared__ float pl[128];
    __shared__ float scs[128], shs[128];
    int g = blockIdx.x;
    int tid = threadIdx.x;
    if (tid < 128) {
        float s = 0.f, q = 0.f;
#pragma unroll
        for (int b2 = 0; b2 < NBUCKET; ++b2) {
            s += partIn[b2 * 256 + tid];
            q += partIn[b2 * 256 + 128 + tid];
        }
        float mu = s / (float)n;
        float var = q / (float)n - mu * mu;
        float a = gmv[tid] * rsqrtf(var + 1e-5f);
        scs[tid] = a;
        shs[tid] = btv[tid] - mu * a;
    }
    int j = tid & 127, prt = tid >> 7;
    int a = 0, b = n;
    while (a < b) { int mid = (a + b) >> 1; if (batch[mid] < g) a = mid + 1; else b = mid; }
    int lo = a;
    b = n;
    while (a < b) { int mid = (a + b) >> 1; if (batch[mid] < g + 1) a = mid + 1; else b = mid; }
    int hi = a;

    float acc = 0.f;
    for (int node = lo + prt; node < hi; node += 2) acc += h[(long)node * 128 + j];
    tmp[tid] = acc;
    __syncthreads();
    if (tid < 128) {
        float cnt = (float)(hi - lo);
        float p = scs[tid] * (tmp[tid] + tmp[tid + 128]) + shs[tid] * cnt;
        pl[tid] = fmaxf(p, 0.f);
    }
    __syncthreads();
    if (tid < 64) {
        float v1 = fc1b[tid];
        for (int k = 0; k < 128; ++k) v1 += pl[k] * fc1w[k * 64 + tid];
        v1 = fmaxf(v1, 0.f);
        float v = v1 * fc2w[tid];
        for (int off = 32; off > 0; off >>= 1) v += __shfl_down(v, off, 64);
        if (tid == 0) out[g] = v + fc2b[0];
    }
}

// ---------------- driver ----------------
extern "C" void kernel_launch(void* const* d_in, const int* in_sizes, int n_in,
                              void* d_out, int out_size, void* d_ws, size_t ws_size,
                              hipStream_t stream) {
    const float* x     = (const float*)d_in[0];
    const int*   ei    = (const int*)d_in[1];
    const float* ew    = (const float*)d_in[2];
    const int*   batch = (const int*)d_in[3];
    const float *W[5], *b[5], *gm[5], *bt[5];
    for (int i = 0; i < 5; ++i) {
        W[i]  = (const float*)d_in[4 + 4 * i];
        b[i]  = (const float*)d_in[5 + 4 * i];
        gm[i] = (const float*)d_in[6 + 4 * i];
        bt[i] = (const float*)d_in[7 + 4 * i];
    }
    const float* fc1w = (const float*)d_in[24];
    const float* fc1b = (const float*)d_in[25];
    const float* fc2w = (const float*)d_in[26];
    const float* fc2b = (const float*)d_in[27];
    float* out = (float*)d_out;

    // workspace layout
    char* wsb = (char*)d_ws;
    float* dis    = (float*)wsb;  wsb += sizeof(float) * NN;
    int*   ptr    = (int*)wsb;    wsb += sizeof(int) * (NN + 4);
    int*   bb     = (int*)wsb;    wsb += sizeof(int) * ABLK * NBKT;
    int*   totals = (int*)wsb;    wsb += sizeof(int) * (NBKT + 1);
    int*   bbase  = (int*)wsb;    wsb += sizeof(int) * (NBKT + 3);
    int2*  staging= (int2*)wsb;   wsb += sizeof(int2) * NE;
    int2*  csr    = (int2*)wsb;   wsb += sizeof(int2) * NE;
    float* part   = (float*)wsb;  wsb += sizeof(float) * 5 * PARTSZ;
    float* buf1   = (float*)wsb;  wsb += sizeof(float) * (long)NN * 128;
    float* buf2   = (float*)wsb;  wsb += sizeof(float) * (long)NN * 128;

    const int* row = ei;
    const int* col = ei + NE;
    const int B = 256;
    const int NB_N = (NN + B - 1) / B;   // 196

    // prologue: bucketed CSR build
    k_init<<<(5 * PARTSZ + B - 1) / B, B, 0, stream>>>(part);
    kA1<<<ABLK, B, 0, stream>>>(col, bb, NE);
    kA2a<<<NBKT, B, 0, stream>>>(bb, totals);
    kA2b<<<1, B, 0, stream>>>(totals, bbase);
    kA3<<<ABLK, B, 0, stream>>>(row, col, ew, bb, bbase, staging, NE);
    kB<<<NBKT, B, 0, stream>>>(bbase, staging, csr, ptr, dis, NN);

    auto grid4 = [](long threads) { return (int)((threads + 255) / 256); };
    auto ggrid = [](int npb) { return (NN + npb - 1) / npb; };

    // L1: gemm 128->16 (NPT=2) + fused CSR rescale in extra blocks; then gather16 EPI
    {
        int gemmBlocks = ggrid((256 / 4) * 2);
        k_gemm<128, 16, 0, 0, 2, 1><<<gemmBlocks + NB_N, B, 0, stream>>>(
            x, W[0], b[0], nullptr, buf1, NN, ptr, csr, dis, gemmBlocks);
    }
    k_gather<16, 1, 0, 0, 1><<<grid4((long)NN * 4), B, 0, stream>>>(buf1, ptr, csr, dis,
                                                                    nullptr, nullptr, nullptr,
                                                                    b[0], part + 0 * PARTSZ, buf2, NN);

    // L2: gather16 (consume part[0]), gemm 16->32 (produce part[1])
    k_gather<16, 1, 1, 0, 0><<<grid4((long)NN * 4), B, 0, stream>>>(buf2, ptr, csr, dis,
                                                                    part + 0 * PARTSZ, gm[0], bt[0],
                                                                    nullptr, nullptr, buf1, NN);
    k_gemm<16, 32, 1, 1, 4, 0><<<ggrid((256/8)*4), B, 0, stream>>>(buf1, W[1], b[1], part + 1 * PARTSZ,
                                                                   buf2, NN, nullptr, nullptr, nullptr, 0);

    // L3: gather32 EP=4 (consume part[1]), gemm 32->64 (produce part[2])
    k_gather<32, 4, 1, 0, 0><<<grid4((long)NN * 32), B, 0, stream>>>(buf2, ptr, csr, dis,
                                                                     part + 1 * PARTSZ, gm[1], bt[1],
                                                                     nullptr, nullptr, buf1, NN);
    k_gemm<32, 64, 1, 1, 4, 0><<<ggrid((256/16)*4), B, 0, stream>>>(buf1, W[2], b[2], part + 2 * PARTSZ,
                                                                    buf2, NN, nullptr, nullptr, nullptr, 0);

    // L4: gather64 EP=4 (consume part[2]), gemm 64->64 (produce part[3]; relu post-BN)
    k_gather<64, 4, 1, 0, 0><<<grid4((long)NN * 64), B, 0, stream>>>(buf2, ptr, csr, dis,
                                                                     part + 2 * PARTSZ, gm[2], bt[2],
                                                                     nullptr, nullptr, buf1, NN);
    k_gemm<64, 64, 0, 1, 4, 0><<<ggrid((256/16)*4), B, 0, stream>>>(buf1, W[3], b[3], part + 3 * PARTSZ,
                                                                    buf2, NN, nullptr, nullptr, nullptr, 0);

    // L5: gather64 EP=4 (consume part[3]; BN4+relu per-edge), gemm 64->128 (produce part[4])
    k_gather<64, 4, 0, 1, 0><<<grid4((long)NN * 64), B, 0, stream>>>(buf2, ptr, csr, dis,
                                                                     part + 3 * PARTSZ, gm[3], bt[3],
                                                                     nullptr, nullptr, buf1, NN);
    k_gemm<64, 128, 0, 1, 4, 0><<<ggrid((256/32)*4), B, 0, stream>>>(buf1, W[4], b[4], part + 4 * PARTSZ,
                                                                     buf2, NN, nullptr, nullptr, nullptr, 0);

    // fused pool (consume part[4] -> BN5) + head
    k_poolhead<<<NG, 256, 0, stream>>>(buf2, batch, part + 4 * PARTSZ, gm[4], bt[4],
                                       fc1w, fc1b, fc2w, fc2b, out, NN);
}

// Round 10
// 442.091 us; speedup vs baseline: 1.0533x; 1.0533x over previous
//
#include <hip/hip_runtime.h>

#define NN 50000
#define NE 800000
#define NG 256
#define NBUCKET 16
#define PARTSZ (NBUCKET * 256)

// bucketed CSR build params
#define NBKT 391      // node buckets of 128 (391*128 = 50048 >= NN)
#define ABLK 391      // A-pass blocks
#define ASLICE 2048   // edges per A-pass block (391*2048 >= NE)
#define BCAP 2560     // LDS staging capacity per bucket (mean 2046, +11 sigma)

// ---------------- prologue ----------------
__global__ void k_init(float* part) {
    int i = blockIdx.x * blockDim.x + threadIdx.x;
    if (i < 5 * PARTSZ) part[i] = 0.f;
}

// A1: per-(block,bucket) edge counts via LDS histogram
__global__ void kA1(const int* __restrict__ col, int* __restrict__ bb, int e) {
    __shared__ int cnt[NBKT];
    for (int j = threadIdx.x; j < NBKT; j += 256) cnt[j] = 0;
    __syncthreads();
    int start = blockIdx.x * ASLICE;
    int end = min(start + ASLICE, e);
    for (int i = start + threadIdx.x; i < end; i += 256)
        atomicAdd(&cnt[col[i] >> 7], 1);
    __syncthreads();
    for (int j = threadIdx.x; j < NBKT; j += 256) bb[blockIdx.x * NBKT + j] = cnt[j];
}

// A2a: per-bucket exclusive scan over blocks (in place), bucket totals out
__global__ void kA2a(int* __restrict__ bb, int* __restrict__ totals) {
    __shared__ int v[ABLK];
    int k = blockIdx.x;
    for (int b = threadIdx.x; b < ABLK; b += 256) v[b] = bb[b * NBKT + k];
    __syncthreads();
    if (threadIdx.x == 0) {
        int run = 0;
        for (int b = 0; b < ABLK; ++b) { int t = v[b]; v[b] = run; run += t; }
        totals[k] = run;
    }
    __syncthreads();
    for (int b = threadIdx.x; b < ABLK; b += 256) bb[b * NBKT + k] = v[b];
}

// A2b: exclusive scan of bucket totals -> bucketbase[NBKT+1]
__global__ void kA2b(const int* __restrict__ totals, int* __restrict__ bucketbase) {
    __shared__ int v[NBKT];
    for (int j = threadIdx.x; j < NBKT; j += 256) v[j] = totals[j];
    __syncthreads();
    if (threadIdx.x == 0) {
        int run = 0;
        for (int k = 0; k < NBKT; ++k) { int t = v[k]; v[k] = run; run += t; }
        bucketbase[NBKT] = run;
    }
    __syncthreads();
    for (int j = threadIdx.x; j < NBKT; j += 256) bucketbase[j] = v[j];
}

// A3: scatter edges into per-(block,bucket) private contiguous staging ranges
__global__ void kA3(const int* __restrict__ row, const int* __restrict__ col,
                    const float* __restrict__ ew, const int* __restrict__ bb,
                    const int* __restrict__ bucketbase, int2* __restrict__ staging, int e) {
    __shared__ int cur[NBKT];
    for (int j = threadIdx.x; j < NBKT; j += 256)
        cur[j] = bucketbase[j] + bb[blockIdx.x * NBKT + j];
    __syncthreads();
    int start = blockIdx.x * ASLICE;
    int end = min(start + ASLICE, e);
    for (int i = start + threadIdx.x; i < end; i += 256) {
        int c = col[i];
        int p = atomicAdd(&cur[c >> 7], 1);
        staging[p] = make_int2(row[i] | ((c & 127) << 16), __float_as_int(ew[i]));
    }
}

// B: per-bucket LDS counting sort -> csr {src, raw_ew}, ptr, deg->dis
__global__ void __launch_bounds__(256) kB(const int* __restrict__ bucketbase,
                                          const int2* __restrict__ staging,
                                          int2* __restrict__ csr, int* __restrict__ ptr,
                                          float* __restrict__ dis, int n) {
    __shared__ int2 st[BCAP];
    __shared__ int2 outb[BCAP];
    __shared__ int hist[129];
    __shared__ int cur[128];
    int k = blockIdx.x, t = threadIdx.x;
    int base = bucketbase[k], cnt = bucketbase[k + 1] - base;
    int node0 = k << 7;
    int ncov = min(128, n - node0);
    if (t < 129) hist[t] = 0;
    __syncthreads();
    if (cnt <= BCAP) {
        for (int i = t; i < cnt; i += 256) {
            int2 v = staging[base + i];
            st[i] = v;
            atomicAdd(&hist[v.x >> 16], 1);
        }
        __syncthreads();
        if (t == 0) {
            int run = 0;
            for (int j = 0; j < 128; ++j) { int h = hist[j]; hist[j] = run; run += h; }
            hist[128] = run;
        }
        __syncthreads();
        if (t < 128) cur[t] = hist[t];
        if (t < ncov) ptr[node0 + t] = base + hist[t];
        __syncthreads();
        for (int i = t; i < cnt; i += 256) {
            int2 v = st[i];
            int j = v.x >> 16;
            int p = atomicAdd(&cur[j], 1);
            outb[p] = make_int2(v.x & 0xFFFF, v.y);
        }
        __syncthreads();
        for (int i = t; i < cnt; i += 256) csr[base + i] = outb[i];
        if (t < ncov) {
            float s = 1.f;
            int a = hist[t], b2 = hist[t + 1];
            for (int p = a; p < b2; ++p) s += __int_as_float(outb[p].y);
            dis[node0 + t] = rsqrtf(s);
        }
    } else {
        for (int i = t; i < cnt; i += 256) atomicAdd(&hist[staging[base + i].x >> 16], 1);
        __syncthreads();
        if (t == 0) {
            int run = 0;
            for (int j = 0; j < 128; ++j) { int h = hist[j]; hist[j] = run; run += h; }
            hist[128] = run;
        }
        __syncthreads();
        if (t < 128) cur[t] = hist[t];
        if (t < ncov) ptr[node0 + t] = base + hist[t];
        __syncthreads();
        for (int i = t; i < cnt; i += 256) {
            int2 v = staging[base + i];
            int j = v.x >> 16;
            int p = atomicAdd(&cur[j], 1);
            csr[base + p] = make_int2(v.x & 0xFFFF, v.y);
        }
        __threadfence_block();
        __syncthreads();
        if (t < ncov) {
            float s = 1.f;
            int a = hist[t], b2 = hist[t + 1];
            for (int p = a; p < b2; ++p) s += __int_as_float(csr[base + p].y);
            dis[node0 + t] = rsqrtf(s);
        }
    }
    if (k == gridDim.x - 1 && t == 0) ptr[n] = bucketbase[NBKT];
}

// csr[p] = {src, dis[src]*ew*dis[c]} -- FULL int2 store (no half-line RMW amplification)
__global__ void k_scale(const int* __restrict__ ptr, int2* __restrict__ csr,
                        const float* __restrict__ dis, int n) {
    int i = blockIdx.x * blockDim.x + threadIdx.x;
    if (i >= n) return;
    float dc = dis[i];
    int p1 = ptr[i + 1];
    for (int p = ptr[i]; p < p1; ++p) {
        int2 v = csr[p];
        v.y = __float_as_int(dis[v.x] * __int_as_float(v.y) * dc);
        csr[p] = v;
    }
}

// ---------------- gather ----------------
// EP: edge-parallel lanes per node. Lane layout: LPN = TPN*EP; r = e0*TPN + l4.
// POSTAFF (L2/L3/L4): out = sc*A + sh*(dis^2 + sum w); PREAFF (L5): per-edge relu(sc*u+sh);
// EPI (L1, EP==1 only): out = relu(A + bias), stats -> partOut.
template <int D, int EP, int POSTAFF, int PREAFF, int EPI>
__global__ void k_gather(const float* __restrict__ src, const int* __restrict__ ptr,
                         const int2* __restrict__ csr, const float* __restrict__ dis,
                         const float* __restrict__ partIn, const float* __restrict__ gmv,
                         const float* __restrict__ btv,
                         const float* __restrict__ bias, float* __restrict__ partOut,
                         float* __restrict__ out, int n) {
    const int TPN = D / 4;
    const int LPN = TPN * EP;
    const int CONSUME = POSTAFF || PREAFF;
    __shared__ float ls[EPI ? D : 1], lq[EPI ? D : 1];
    __shared__ float scs[CONSUME ? D : 4], shs[CONSUME ? D : 4];
    int tid = threadIdx.x;
    if (EPI && tid < D) { ls[tid] = 0.f; lq[tid] = 0.f; }
    if (CONSUME && tid < D) {
        float s = 0.f, q = 0.f;
#pragma unroll
        for (int b2 = 0; b2 < NBUCKET; ++b2) {
            s += partIn[b2 * 256 + tid];
            q += partIn[b2 * 256 + 128 + tid];
        }
        float mu = s / (float)n;
        float var = q / (float)n - mu * mu;
        float a = gmv[tid] * rsqrtf(var + 1e-5f);
        scs[tid] = a;
        shs[tid] = btv[tid] - mu * a;
    }
    if (EPI || CONSUME) __syncthreads();

    int t = blockIdx.x * blockDim.x + tid;
    int node = t / LPN;
    int r = t - node * LPN;
    int e0 = r / TPN;
    int l4 = r - e0 * TPN;
    bool valid = node < n;
    int nc = valid ? node : n - 1;

    float4 sc = {0,0,0,0}, sh = {0,0,0,0};
    if (CONSUME) {
        sc = ((const float4*)scs)[l4];
        sh = ((const float4*)shs)[l4];
    }
    const float4* s4 = (const float4*)src;
    float4 acc = {0.f, 0.f, 0.f, 0.f};
    float sumw = 0.f;
    if (e0 == 0) {
        float d = dis[nc];
        float w0 = d * d;
        float4 v = s4[nc * TPN + l4];
        if (PREAFF) {
            v.x = fmaxf(sc.x * v.x + sh.x, 0.f); v.y = fmaxf(sc.y * v.y + sh.y, 0.f);
            v.z = fmaxf(sc.z * v.z + sh.z, 0.f); v.w = fmaxf(sc.w * v.w + sh.w, 0.f);
        }
        acc.x = w0 * v.x; acc.y = w0 * v.y; acc.z = w0 * v.z; acc.w = w0 * v.w;
        sumw = w0;
    }
    int p0 = ptr[nc], p1 = ptr[nc + 1];
    int p = p0 + e0;
    for (; p + 3 * EP < p1; p += 4 * EP) {
        int2 c0 = csr[p], c1 = csr[p + EP], c2 = csr[p + 2 * EP], c3 = csr[p + 3 * EP];
        float e0w = __int_as_float(c0.y), e1w = __int_as_float(c1.y);
        float e2w = __int_as_float(c2.y), e3w = __int_as_float(c3.y);
        float4 u0 = s4[c0.x * TPN + l4];
        float4 u1 = s4[c1.x * TPN + l4];
        float4 u2 = s4[c2.x * TPN + l4];
        float4 u3 = s4[c3.x * TPN + l4];
        if (PREAFF) {
            u0.x = fmaxf(sc.x*u0.x+sh.x,0.f); u0.y = fmaxf(sc.y*u0.y+sh.y,0.f);
            u0.z = fmaxf(sc.z*u0.z+sh.z,0.f); u0.w = fmaxf(sc.w*u0.w+sh.w,0.f);
            u1.x = fmaxf(sc.x*u1.x+sh.x,0.f); u1.y = fmaxf(sc.y*u1.y+sh.y,0.f);
            u1.z = fmaxf(sc.z*u1.z+sh.z,0.f); u1.w = fmaxf(sc.w*u1.w+sh.w,0.f);
            u2.x = fmaxf(sc.x*u2.x+sh.x,0.f); u2.y = fmaxf(sc.y*u2.y+sh.y,0.f);
            u2.z = fmaxf(sc.z*u2.z+sh.z,0.f); u2.w = fmaxf(sc.w*u2.w+sh.w,0.f);
            u3.x = fmaxf(sc.x*u3.x+sh.x,0.f); u3.y = fmaxf(sc.y*u3.y+sh.y,0.f);
            u3.z = fmaxf(sc.z*u3.z+sh.z,0.f); u3.w = fmaxf(sc.w*u3.w+sh.w,0.f);
        }
        acc.x += e0w*u0.x + e1w*u1.x + e2w*u2.x + e3w*u3.x;
        acc.y += e0w*u0.y + e1w*u1.y + e2w*u2.y + e3w*u3.y;
        acc.z += e0w*u0.z + e1w*u1.z + e2w*u2.z + e3w*u3.z;
        acc.w += e0w*u0.w + e1w*u1.w + e2w*u2.w + e3w*u3.w;
        if (POSTAFF) sumw += e0w + e1w + e2w + e3w;
    }
    for (; p < p1; p += EP) {
        int2 ce = csr[p];
        float w = __int_as_float(ce.y);
        float4 u = s4[ce.x * TPN + l4];
        if (PREAFF) {
            u.x = fmaxf(sc.x*u.x+sh.x,0.f); u.y = fmaxf(sc.y*u.y+sh.y,0.f);
            u.z = fmaxf(sc.z*u.z+sh.z,0.f); u.w = fmaxf(sc.w*u.w+sh.w,0.f);
        }
        acc.x += w*u.x; acc.y += w*u.y; acc.z += w*u.z; acc.w += w*u.w;
        if (POSTAFF) sumw += w;
    }
    if (EP > 1) {
#pragma unroll
        for (int off = TPN; off < LPN; off <<= 1) {
            acc.x += __shfl_xor(acc.x, off, 64);
            acc.y += __shfl_xor(acc.y, off, 64);
            acc.z += __shfl_xor(acc.z, off, 64);
            acc.w += __shfl_xor(acc.w, off, 64);
            if (POSTAFF) sumw += __shfl_xor(sumw, off, 64);
        }
    }
    if (POSTAFF) {
        acc.x = sc.x * acc.x + sh.x * sumw;
        acc.y = sc.y * acc.y + sh.y * sumw;
        acc.z = sc.z * acc.z + sh.z * sumw;
        acc.w = sc.w * acc.w + sh.w * sumw;
    }
    if (EPI) {
        float4 b = ((const float4*)bias)[l4];
        acc.x = fmaxf(acc.x + b.x, 0.f);
        acc.y = fmaxf(acc.y + b.y, 0.f);
        acc.z = fmaxf(acc.z + b.z, 0.f);
        acc.w = fmaxf(acc.w + b.w, 0.f);
        if (valid) ((float4*)out)[nc * TPN + l4] = acc;
        float s0 = valid ? acc.x : 0.f, s1 = valid ? acc.y : 0.f;
        float s2 = valid ? acc.z : 0.f, s3 = valid ? acc.w : 0.f;
        float q0 = s0*s0, q1 = s1*s1, q2 = s2*s2, q3 = s3*s3;
        for (int off = TPN; off < 64; off <<= 1) {
            s0 += __shfl_down(s0, off, 64); s1 += __shfl_down(s1, off, 64);
            s2 += __shfl_down(s2, off, 64); s3 += __shfl_down(s3, off, 64);
            q0 += __shfl_down(q0, off, 64); q1 += __shfl_down(q1, off, 64);
            q2 += __shfl_down(q2, off, 64); q3 += __shfl_down(q3, off, 64);
        }
        int lane = tid & 63;
        if (lane < TPN) {
            atomicAdd(&ls[4*lane+0], s0); atomicAdd(&ls[4*lane+1], s1);
            atomicAdd(&ls[4*lane+2], s2); atomicAdd(&ls[4*lane+3], s3);
            atomicAdd(&lq[4*lane+0], q0); atomicAdd(&lq[4*lane+1], q1);
            atomicAdd(&lq[4*lane+2], q2); atomicAdd(&lq[4*lane+3], q3);
        }
        __syncthreads();
        int bkt = (blockIdx.x & (NBUCKET - 1)) * 256;
        if (tid < D) {
            atomicAdd(&partOut[bkt + tid], ls[tid]);
            atomicAdd(&partOut[bkt + 128 + tid], lq[tid]);
        }
    } else {
        if (valid && e0 == 0) ((float4*)out)[nc * TPN + l4] = acc;
    }
}

// ---------------- node-blocked GEMM: NPT nodes x 4 outputs per thread ----------------
template <int DIN, int DOUT, int RELU, int EPI, int NPT>
__global__ void k_gemm(const float* __restrict__ h, const float* __restrict__ W,
                       const float* __restrict__ bias, float* __restrict__ partOut,
                       float* __restrict__ m, int n) {
    const int TPN = DOUT / 4;
    const int GPB = 256 / TPN;
    __shared__ float Wl[DIN * DOUT];
    __shared__ float ls[EPI ? DOUT : 1], lq[EPI ? DOUT : 1];
    int tid = threadIdx.x;
    for (int i = tid; i < DIN * DOUT / 4; i += 256)
        ((float4*)Wl)[i] = ((const float4*)W)[i];
    if (EPI && tid < DOUT) { ls[tid] = 0.f; lq[tid] = 0.f; }
    __syncthreads();

    int jq = tid % TPN;
    int group = tid / TPN;
    int node0 = (blockIdx.x * GPB + group) * NPT;
    const float4* h4 = (const float4*)h;
    int hb[NPT];
    bool val[NPT];
#pragma unroll
    for (int i = 0; i < NPT; ++i) {
        int nd = node0 + i;
        val[i] = nd < n;
        hb[i] = (val[i] ? nd : n - 1) * (DIN / 4);
    }
    float4 acc[NPT];
#pragma unroll
    for (int i = 0; i < NPT; ++i) acc[i] = {0.f, 0.f, 0.f, 0.f};

#pragma unroll 4
    for (int k4 = 0; k4 < DIN / 4; ++k4) {
        const float* wb = &Wl[(k4 * 4) * DOUT + jq * 4];
        float4 w0 = *(const float4*)(wb);
        float4 w1 = *(const float4*)(wb + DOUT);
        float4 w2 = *(const float4*)(wb + 2 * DOUT);
        float4 w3 = *(const float4*)(wb + 3 * DOUT);
#pragma unroll
        for (int i = 0; i < NPT; ++i) {
            float4 hv = h4[hb[i] + k4];
            acc[i].x += hv.x*w0.x + hv.y*w1.x + hv.z*w2.x + hv.w*w3.x;
            acc[i].y += hv.x*w0.y + hv.y*w1.y + hv.z*w2.y + hv.w*w3.y;
            acc[i].z += hv.x*w0.z + hv.y*w1.z + hv.z*w2.z + hv.w*w3.z;
            acc[i].w += hv.x*w0.w + hv.y*w1.w + hv.z*w2.w + hv.w*w3.w;
        }
    }

    float4 bv = {0,0,0,0};
    if (EPI) bv = ((const float4*)bias)[jq];
    float4 sv = {0,0,0,0}, qv = {0,0,0,0};
#pragma unroll
    for (int i = 0; i < NPT; ++i) {
        float4 a = acc[i];
        if (EPI) {
            a.x += bv.x; a.y += bv.y; a.z += bv.z; a.w += bv.w;
            if (RELU) {
                a.x = fmaxf(a.x, 0.f); a.y = fmaxf(a.y, 0.f);
                a.z = fmaxf(a.z, 0.f); a.w = fmaxf(a.w, 0.f);
            }
        }
        if (val[i]) {
            ((float4*)m)[(node0 + i) * TPN + jq] = a;
            if (EPI) {
                sv.x += a.x; sv.y += a.y; sv.z += a.z; sv.w += a.w;
                qv.x += a.x*a.x; qv.y += a.y*a.y; qv.z += a.z*a.z; qv.w += a.w*a.w;
            }
        }
    }
    if (EPI) {
        for (int off = TPN; off < 64; off <<= 1) {
            sv.x += __shfl_down(sv.x, off, 64); sv.y += __shfl_down(sv.y, off, 64);
            sv.z += __shfl_down(sv.z, off, 64); sv.w += __shfl_down(sv.w, off, 64);
            qv.x += __shfl_down(qv.x, off, 64); qv.y += __shfl_down(qv.y, off, 64);
            qv.z += __shfl_down(qv.z, off, 64); qv.w += __shfl_down(qv.w, off, 64);
        }
        int lane = tid & 63;
        if (lane < TPN) {
            atomicAdd(&ls[4*lane+0], sv.x); atomicAdd(&ls[4*lane+1], sv.y);
            atomicAdd(&ls[4*lane+2], sv.z); atomicAdd(&ls[4*lane+3], sv.w);
            atomicAdd(&lq[4*lane+0], qv.x); atomicAdd(&lq[4*lane+1], qv.y);
            atomicAdd(&lq[4*lane+2], qv.z); atomicAdd(&lq[4*lane+3], qv.w);
        }
        __syncthreads();
        int bkt = (blockIdx.x & (NBUCKET - 1)) * 256;
        if (tid < DOUT) {
            atomicAdd(&partOut[bkt + tid], ls[tid]);
            atomicAdd(&partOut[bkt + 128 + tid], lq[tid]);
        }
    }
}

// ---------------- fused pool (BN5 consumed inline) + MLP head ----------------
__global__ void k_poolhead(const float* __restrict__ h, const int* __restrict__ batch,
                           const float* __restrict__ partIn, const float* __restrict__ gmv,
                           const float* __restrict__ btv,
                           const float* __restrict__ fc1w, const float* __restrict__ fc1b,
                           const float* __restrict__ fc2w, const float* __restrict__ fc2b,
                           float* __restrict__ out, int n) {
    __shared__ float tmp[256];
    __shared__ float pl[128];
    __shared__ float scs[128], shs[128];
    int g = blockIdx.x;
    int tid = threadIdx.x;
    if (tid < 128) {
        float s = 0.f, q = 0.f;
#pragma unroll
        for (int b2 = 0; b2 < NBUCKET; ++b2) {
            s += partIn[b2 * 256 + tid];
            q += partIn[b2 * 256 + 128 + tid];
        }
        float mu = s / (float)n;
        float var = q / (float)n - mu * mu;
        float a = gmv[tid] * rsqrtf(var + 1e-5f);
        scs[tid] = a;
        shs[tid] = btv[tid] - mu * a;
    }
    int j = tid & 127, prt = tid >> 7;
    int a = 0, b = n;
    while (a < b) { int mid = (a + b) >> 1; if (batch[mid] < g) a = mid + 1; else b = mid; }
    int lo = a;
    b = n;
    while (a < b) { int mid = (a + b) >> 1; if (batch[mid] < g + 1) a = mid + 1; else b = mid; }
    int hi = a;

    float acc = 0.f;
    for (int node = lo + prt; node < hi; node += 2) acc += h[(long)node * 128 + j];
    tmp[tid] = acc;
    __syncthreads();
    if (tid < 128) {
        float cnt = (float)(hi - lo);
        float p = scs[tid] * (tmp[tid] + tmp[tid + 128]) + shs[tid] * cnt;
        pl[tid] = fmaxf(p, 0.f);
    }
    __syncthreads();
    if (tid < 64) {
        float v1 = fc1b[tid];
        for (int k = 0; k < 128; ++k) v1 += pl[k] * fc1w[k * 64 + tid];
        v1 = fmaxf(v1, 0.f);
        float v = v1 * fc2w[tid];
        for (int off = 32; off > 0; off >>= 1) v += __shfl_down(v, off, 64);
        if (tid == 0) out[g] = v + fc2b[0];
    }
}

// ---------------- driver ----------------
extern "C" void kernel_launch(void* const* d_in, const int* in_sizes, int n_in,
                              void* d_out, int out_size, void* d_ws, size_t ws_size,
                              hipStream_t stream) {
    const float* x     = (const float*)d_in[0];
    const int*   ei    = (const int*)d_in[1];
    const float* ew    = (const float*)d_in[2];
    const int*   batch = (const int*)d_in[3];
    const float *W[5], *b[5], *gm[5], *bt[5];
    for (int i = 0; i < 5; ++i) {
        W[i]  = (const float*)d_in[4 + 4 * i];
        b[i]  = (const float*)d_in[5 + 4 * i];
        gm[i] = (const float*)d_in[6 + 4 * i];
        bt[i] = (const float*)d_in[7 + 4 * i];
    }
    const float* fc1w = (const float*)d_in[24];
    const float* fc1b = (const float*)d_in[25];
    const float* fc2w = (const float*)d_in[26];
    const float* fc2b = (const float*)d_in[27];
    float* out = (float*)d_out;

    // workspace layout
    char* wsb = (char*)d_ws;
    float* dis    = (float*)wsb;  wsb += sizeof(float) * NN;
    int*   ptr    = (int*)wsb;    wsb += sizeof(int) * (NN + 4);
    int*   bb     = (int*)wsb;    wsb += sizeof(int) * ABLK * NBKT;
    int*   totals = (int*)wsb;    wsb += sizeof(int) * (NBKT + 1);
    int*   bbase  = (int*)wsb;    wsb += sizeof(int) * (NBKT + 3);
    int2*  staging= (int2*)wsb;   wsb += sizeof(int2) * NE;
    int2*  csr    = (int2*)wsb;   wsb += sizeof(int2) * NE;
    float* part   = (float*)wsb;  wsb += sizeof(float) * 5 * PARTSZ;
    float* buf1   = (float*)wsb;  wsb += sizeof(float) * (long)NN * 128;
    float* buf2   = (float*)wsb;  wsb += sizeof(float) * (long)NN * 128;

    const int* row = ei;
    const int* col = ei + NE;
    const int B = 256;
    const int NB_N = (NN + B - 1) / B;   // 196

    // prologue: bucketed CSR build
    k_init<<<(5 * PARTSZ + B - 1) / B, B, 0, stream>>>(part);
    kA1<<<ABLK, B, 0, stream>>>(col, bb, NE);
    kA2a<<<NBKT, B, 0, stream>>>(bb, totals);
    kA2b<<<1, B, 0, stream>>>(totals, bbase);
    kA3<<<ABLK, B, 0, stream>>>(row, col, ew, bb, bbase, staging, NE);
    kB<<<NBKT, B, 0, stream>>>(bbase, staging, csr, ptr, dis, NN);
    k_scale<<<NB_N, B, 0, stream>>>(ptr, csr, dis, NN);

    auto grid4 = [](long threads) { return (int)((threads + 255) / 256); };
    auto ggrid = [](int npb) { return (NN + npb - 1) / npb; };

    // L1: gemm 128->16 (NPT=2), gather16 EPI (produce part[0])
    k_gemm<128, 16, 0, 0, 2><<<ggrid((256/4)*2), B, 0, stream>>>(x, W[0], b[0], nullptr, buf1, NN);
    k_gather<16, 1, 0, 0, 1><<<grid4((long)NN * 4), B, 0, stream>>>(buf1, ptr, csr, dis,
                                                                    nullptr, nullptr, nullptr,
                                                                    b[0], part + 0 * PARTSZ, buf2, NN);

    // L2: gather16 (consume part[0]), gemm 16->32 (produce part[1])
    k_gather<16, 1, 1, 0, 0><<<grid4((long)NN * 4), B, 0, stream>>>(buf2, ptr, csr, dis,
                                                                    part + 0 * PARTSZ, gm[0], bt[0],
                                                                    nullptr, nullptr, buf1, NN);
    k_gemm<16, 32, 1, 1, 4><<<ggrid((256/8)*4), B, 0, stream>>>(buf1, W[1], b[1], part + 1 * PARTSZ, buf2, NN);

    // L3: gather32 EP=4 (consume part[1]), gemm 32->64 (produce part[2])
    k_gather<32, 4, 1, 0, 0><<<grid4((long)NN * 32), B, 0, stream>>>(buf2, ptr, csr, dis,
                                                                     part + 1 * PARTSZ, gm[1], bt[1],
                                                                     nullptr, nullptr, buf1, NN);
    k_gemm<32, 64, 1, 1, 4><<<ggrid((256/16)*4), B, 0, stream>>>(buf1, W[2], b[2], part + 2 * PARTSZ, buf2, NN);

    // L4: gather64 EP=4 (consume part[2]), gemm 64->64 (produce part[3]; relu post-BN)
    k_gather<64, 4, 1, 0, 0><<<grid4((long)NN * 64), B, 0, stream>>>(buf2, ptr, csr, dis,
                                                                     part + 2 * PARTSZ, gm[2], bt[2],
                                                                     nullptr, nullptr, buf1, NN);
    k_gemm<64, 64, 0, 1, 4><<<ggrid((256/16)*4), B, 0, stream>>>(buf1, W[3], b[3], part + 3 * PARTSZ, buf2, NN);

    // L5: gather64 EP=4 (consume part[3]; BN4+relu per-edge), gemm 64->128 (produce part[4])
    k_gather<64, 4, 0, 1, 0><<<grid4((long)NN * 64), B, 0, stream>>>(buf2, ptr, csr, dis,
                                                                     part + 3 * PARTSZ, gm[3], bt[3],
                                                                     nullptr, nullptr, buf1, NN);
    k_gemm<64, 128, 0, 1, 4><<<ggrid((256/32)*4), B, 0, stream>>>(buf1, W[4], b[4], part + 4 * PARTSZ, buf2, NN);

    // fused pool (consume part[4] -> BN5) + head
    k_poolhead<<<NG, 256, 0, stream>>>(buf2, batch, part + 4 * PARTSZ, gm[4], bt[4],
                                       fc1w, fc1b, fc2w, fc2b, out, NN);
}

// Round 11
// 425.978 us; speedup vs baseline: 1.0932x; 1.0378x over previous
//
#include <hip/hip_runtime.h>

#define NN 50000
#define NE 800000
#define NG 256
#define NBUCKET 16
#define PARTSZ (NBUCKET * 256)

// bucketed CSR build params
#define NBKT 391      // node buckets of 128 (391*128 = 50048 >= NN)
#define ABLK 391      // A-pass blocks
#define ASLICE 2048   // edges per A-pass block (391*2048 >= NE)
#define BCAP 2560     // LDS staging capacity per bucket (mean 2046, +11 sigma)

__device__ __forceinline__ float bf2f(unsigned short u) {
    return __uint_as_float(((unsigned)u) << 16);
}
__device__ __forceinline__ unsigned short f2bf(float f) {
    unsigned b = __float_as_uint(f);
    return (unsigned short)((b + 0x7FFF + ((b >> 16) & 1)) >> 16);  // RNE
}

// ---------------- prologue ----------------
__global__ void k_init(float* part) {
    int i = blockIdx.x * blockDim.x + threadIdx.x;
    if (i < 5 * PARTSZ) part[i] = 0.f;
}

__global__ void kA1(const int* __restrict__ col, int* __restrict__ bb, int e) {
    __shared__ int cnt[NBKT];
    for (int j = threadIdx.x; j < NBKT; j += 256) cnt[j] = 0;
    __syncthreads();
    int start = blockIdx.x * ASLICE;
    int end = min(start + ASLICE, e);
    for (int i = start + threadIdx.x; i < end; i += 256)
        atomicAdd(&cnt[col[i] >> 7], 1);
    __syncthreads();
    for (int j = threadIdx.x; j < NBKT; j += 256) bb[blockIdx.x * NBKT + j] = cnt[j];
}

__global__ void kA2a(int* __restrict__ bb, int* __restrict__ totals) {
    __shared__ int v[ABLK];
    int k = blockIdx.x;
    for (int b = threadIdx.x; b < ABLK; b += 256) v[b] = bb[b * NBKT + k];
    __syncthreads();
    if (threadIdx.x == 0) {
        int run = 0;
        for (int b = 0; b < ABLK; ++b) { int t = v[b]; v[b] = run; run += t; }
        totals[k] = run;
    }
    __syncthreads();
    for (int b = threadIdx.x; b < ABLK; b += 256) bb[b * NBKT + k] = v[b];
}

__global__ void kA2b(const int* __restrict__ totals, int* __restrict__ bucketbase) {
    __shared__ int v[NBKT];
    for (int j = threadIdx.x; j < NBKT; j += 256) v[j] = totals[j];
    __syncthreads();
    if (threadIdx.x == 0) {
        int run = 0;
        for (int k = 0; k < NBKT; ++k) { int t = v[k]; v[k] = run; run += t; }
        bucketbase[NBKT] = run;
    }
    __syncthreads();
    for (int j = threadIdx.x; j < NBKT; j += 256) bucketbase[j] = v[j];
}

__global__ void kA3(const int* __restrict__ row, const int* __restrict__ col,
                    const float* __restrict__ ew, const int* __restrict__ bb,
                    const int* __restrict__ bucketbase, int2* __restrict__ staging, int e) {
    __shared__ int cur[NBKT];
    for (int j = threadIdx.x; j < NBKT; j += 256)
        cur[j] = bucketbase[j] + bb[blockIdx.x * NBKT + j];
    __syncthreads();
    int start = blockIdx.x * ASLICE;
    int end = min(start + ASLICE, e);
    for (int i = start + threadIdx.x; i < end; i += 256) {
        int c = col[i];
        int p = atomicAdd(&cur[c >> 7], 1);
        staging[p] = make_int2(row[i] | ((c & 127) << 16), __float_as_int(ew[i]));
    }
}

__global__ void __launch_bounds__(256) kB(const int* __restrict__ bucketbase,
                                          const int2* __restrict__ staging,
                                          int2* __restrict__ csr, int* __restrict__ ptr,
                                          float* __restrict__ dis, int n) {
    __shared__ int2 st[BCAP];
    __shared__ int2 outb[BCAP];
    __shared__ int hist[129];
    __shared__ int cur[128];
    int k = blockIdx.x, t = threadIdx.x;
    int base = bucketbase[k], cnt = bucketbase[k + 1] - base;
    int node0 = k << 7;
    int ncov = min(128, n - node0);
    if (t < 129) hist[t] = 0;
    __syncthreads();
    if (cnt <= BCAP) {
        for (int i = t; i < cnt; i += 256) {
            int2 v = staging[base + i];
            st[i] = v;
            atomicAdd(&hist[v.x >> 16], 1);
        }
        __syncthreads();
        if (t == 0) {
            int run = 0;
            for (int j = 0; j < 128; ++j) { int h = hist[j]; hist[j] = run; run += h; }
            hist[128] = run;
        }
        __syncthreads();
        if (t < 128) cur[t] = hist[t];
        if (t < ncov) ptr[node0 + t] = base + hist[t];
        __syncthreads();
        for (int i = t; i < cnt; i += 256) {
            int2 v = st[i];
            int j = v.x >> 16;
            int p = atomicAdd(&cur[j], 1);
            outb[p] = make_int2(v.x & 0xFFFF, v.y);
        }
        __syncthreads();
        for (int i = t; i < cnt; i += 256) csr[base + i] = outb[i];
        if (t < ncov) {
            float s = 1.f;
            int a = hist[t], b2 = hist[t + 1];
            for (int p = a; p < b2; ++p) s += __int_as_float(outb[p].y);
            dis[node0 + t] = rsqrtf(s);
        }
    } else {
        for (int i = t; i < cnt; i += 256) atomicAdd(&hist[staging[base + i].x >> 16], 1);
        __syncthreads();
        if (t == 0) {
            int run = 0;
            for (int j = 0; j < 128; ++j) { int h = hist[j]; hist[j] = run; run += h; }
            hist[128] = run;
        }
        __syncthreads();
        if (t < 128) cur[t] = hist[t];
        if (t < ncov) ptr[node0 + t] = base + hist[t];
        __syncthreads();
        for (int i = t; i < cnt; i += 256) {
            int2 v = staging[base + i];
            int j = v.x >> 16;
            int p = atomicAdd(&cur[j], 1);
            csr[base + p] = make_int2(v.x & 0xFFFF, v.y);
        }
        __threadfence_block();
        __syncthreads();
        if (t < ncov) {
            float s = 1.f;
            int a = hist[t], b2 = hist[t + 1];
            for (int p = a; p < b2; ++p) s += __int_as_float(csr[base + p].y);
            dis[node0 + t] = rsqrtf(s);
        }
    }
    if (k == gridDim.x - 1 && t == 0) ptr[n] = bucketbase[NBKT];
}

// csr[p] = {src, dis[src]*ew*dis[c]} -- FULL int2 store (no half-line RMW)
__global__ void k_scale(const int* __restrict__ ptr, int2* __restrict__ csr,
                        const float* __restrict__ dis, int n) {
    int i = blockIdx.x * blockDim.x + threadIdx.x;
    if (i >= n) return;
    float dc = dis[i];
    int p1 = ptr[i + 1];
    for (int p = ptr[i]; p < p1; ++p) {
        int2 v = csr[p];
        v.y = __float_as_int(dis[v.x] * __int_as_float(v.y) * dc);
        csr[p] = v;
    }
}

// row loader: fp32 float4 or bf16 ushort4 -> float4
template <int D, int BF16>
__device__ __forceinline__ float4 load_row(const void* src, int node, int l4) {
    if (BF16) {
        const unsigned short* sb = (const unsigned short*)src;
        ushort4 r = *(const ushort4*)(sb + (size_t)node * D + (l4 << 2));
        float4 f;
        f.x = bf2f(r.x); f.y = bf2f(r.y); f.z = bf2f(r.z); f.w = bf2f(r.w);
        return f;
    } else {
        const float4* s4 = (const float4*)src;
        return s4[(size_t)node * (D / 4) + l4];
    }
}

// ---------------- gather ----------------
// EP edge-parallel lanes per node; BF16IN selects bf16 feature rows.
// POSTAFF (L2/L3/L4): out = sc*A + sh*(dis^2 + sum w); PREAFF (L5): per-edge relu(sc*u+sh);
// EPI (L1, EP==1): out = relu(A + bias), stats -> partOut.
template <int D, int EP, int POSTAFF, int PREAFF, int EPI, int BF16IN>
__global__ void k_gather(const void* __restrict__ src, const int* __restrict__ ptr,
                         const int2* __restrict__ csr, const float* __restrict__ dis,
                         const float* __restrict__ partIn, const float* __restrict__ gmv,
                         const float* __restrict__ btv,
                         const float* __restrict__ bias, float* __restrict__ partOut,
                         float* __restrict__ out, int n) {
    const int TPN = D / 4;
    const int LPN = TPN * EP;
    const int CONSUME = POSTAFF || PREAFF;
    __shared__ float ls[EPI ? D : 1], lq[EPI ? D : 1];
    __shared__ float scs[CONSUME ? D : 4], shs[CONSUME ? D : 4];
    int tid = threadIdx.x;
    if (EPI && tid < D) { ls[tid] = 0.f; lq[tid] = 0.f; }
    if (CONSUME && tid < D) {
        float s = 0.f, q = 0.f;
#pragma unroll
        for (int b2 = 0; b2 < NBUCKET; ++b2) {
            s += partIn[b2 * 256 + tid];
            q += partIn[b2 * 256 + 128 + tid];
        }
        float mu = s / (float)n;
        float var = q / (float)n - mu * mu;
        float a = gmv[tid] * rsqrtf(var + 1e-5f);
        scs[tid] = a;
        shs[tid] = btv[tid] - mu * a;
    }
    if (EPI || CONSUME) __syncthreads();

    int t = blockIdx.x * blockDim.x + tid;
    int node = t / LPN;
    int r = t - node * LPN;
    int e0 = r / TPN;
    int l4 = r - e0 * TPN;
    bool valid = node < n;
    int nc = valid ? node : n - 1;

    float4 sc = {0,0,0,0}, sh = {0,0,0,0};
    if (CONSUME) {
        sc = ((const float4*)scs)[l4];
        sh = ((const float4*)shs)[l4];
    }
    float4 acc = {0.f, 0.f, 0.f, 0.f};
    float sumw = 0.f;
    if (e0 == 0) {
        float d = dis[nc];
        float w0 = d * d;
        float4 v = load_row<D, BF16IN>(src, nc, l4);
        if (PREAFF) {
            v.x = fmaxf(sc.x * v.x + sh.x, 0.f); v.y = fmaxf(sc.y * v.y + sh.y, 0.f);
            v.z = fmaxf(sc.z * v.z + sh.z, 0.f); v.w = fmaxf(sc.w * v.w + sh.w, 0.f);
        }
        acc.x = w0 * v.x; acc.y = w0 * v.y; acc.z = w0 * v.z; acc.w = w0 * v.w;
        sumw = w0;
    }
    int p0 = ptr[nc], p1 = ptr[nc + 1];
    int p = p0 + e0;
    for (; p + 3 * EP < p1; p += 4 * EP) {
        int2 c0 = csr[p], c1 = csr[p + EP], c2 = csr[p + 2 * EP], c3 = csr[p + 3 * EP];
        float e0w = __int_as_float(c0.y), e1w = __int_as_float(c1.y);
        float e2w = __int_as_float(c2.y), e3w = __int_as_float(c3.y);
        float4 u0 = load_row<D, BF16IN>(src, c0.x, l4);
        float4 u1 = load_row<D, BF16IN>(src, c1.x, l4);
        float4 u2 = load_row<D, BF16IN>(src, c2.x, l4);
        float4 u3 = load_row<D, BF16IN>(src, c3.x, l4);
        if (PREAFF) {
            u0.x = fmaxf(sc.x*u0.x+sh.x,0.f); u0.y = fmaxf(sc.y*u0.y+sh.y,0.f);
            u0.z = fmaxf(sc.z*u0.z+sh.z,0.f); u0.w = fmaxf(sc.w*u0.w+sh.w,0.f);
            u1.x = fmaxf(sc.x*u1.x+sh.x,0.f); u1.y = fmaxf(sc.y*u1.y+sh.y,0.f);
            u1.z = fmaxf(sc.z*u1.z+sh.z,0.f); u1.w = fmaxf(sc.w*u1.w+sh.w,0.f);
            u2.x = fmaxf(sc.x*u2.x+sh.x,0.f); u2.y = fmaxf(sc.y*u2.y+sh.y,0.f);
            u2.z = fmaxf(sc.z*u2.z+sh.z,0.f); u2.w = fmaxf(sc.w*u2.w+sh.w,0.f);
            u3.x = fmaxf(sc.x*u3.x+sh.x,0.f); u3.y = fmaxf(sc.y*u3.y+sh.y,0.f);
            u3.z = fmaxf(sc.z*u3.z+sh.z,0.f); u3.w = fmaxf(sc.w*u3.w+sh.w,0.f);
        }
        acc.x += e0w*u0.x + e1w*u1.x + e2w*u2.x + e3w*u3.x;
        acc.y += e0w*u0.y + e1w*u1.y + e2w*u2.y + e3w*u3.y;
        acc.z += e0w*u0.z + e1w*u1.z + e2w*u2.z + e3w*u3.z;
        acc.w += e0w*u0.w + e1w*u1.w + e2w*u2.w + e3w*u3.w;
        if (POSTAFF) sumw += e0w + e1w + e2w + e3w;
    }
    for (; p < p1; p += EP) {
        int2 ce = csr[p];
        float w = __int_as_float(ce.y);
        float4 u = load_row<D, BF16IN>(src, ce.x, l4);
        if (PREAFF) {
            u.x = fmaxf(sc.x*u.x+sh.x,0.f); u.y = fmaxf(sc.y*u.y+sh.y,0.f);
            u.z = fmaxf(sc.z*u.z+sh.z,0.f); u.w = fmaxf(sc.w*u.w+sh.w,0.f);
        }
        acc.x += w*u.x; acc.y += w*u.y; acc.z += w*u.z; acc.w += w*u.w;
        if (POSTAFF) sumw += w;
    }
    if (EP > 1) {
#pragma unroll
        for (int off = TPN; off < LPN; off <<= 1) {
            acc.x += __shfl_xor(acc.x, off, 64);
            acc.y += __shfl_xor(acc.y, off, 64);
            acc.z += __shfl_xor(acc.z, off, 64);
            acc.w += __shfl_xor(acc.w, off, 64);
            if (POSTAFF) sumw += __shfl_xor(sumw, off, 64);
        }
    }
    if (POSTAFF) {
        acc.x = sc.x * acc.x + sh.x * sumw;
        acc.y = sc.y * acc.y + sh.y * sumw;
        acc.z = sc.z * acc.z + sh.z * sumw;
        acc.w = sc.w * acc.w + sh.w * sumw;
    }
    if (EPI) {
        float4 b = ((const float4*)bias)[l4];
        acc.x = fmaxf(acc.x + b.x, 0.f);
        acc.y = fmaxf(acc.y + b.y, 0.f);
        acc.z = fmaxf(acc.z + b.z, 0.f);
        acc.w = fmaxf(acc.w + b.w, 0.f);
        if (valid) ((float4*)out)[nc * TPN + l4] = acc;
        float s0 = valid ? acc.x : 0.f, s1 = valid ? acc.y : 0.f;
        float s2 = valid ? acc.z : 0.f, s3 = valid ? acc.w : 0.f;
        float q0 = s0*s0, q1 = s1*s1, q2 = s2*s2, q3 = s3*s3;
        for (int off = TPN; off < 64; off <<= 1) {
            s0 += __shfl_down(s0, off, 64); s1 += __shfl_down(s1, off, 64);
            s2 += __shfl_down(s2, off, 64); s3 += __shfl_down(s3, off, 64);
            q0 += __shfl_down(q0, off, 64); q1 += __shfl_down(q1, off, 64);
            q2 += __shfl_down(q2, off, 64); q3 += __shfl_down(q3, off, 64);
        }
        int lane = tid & 63;
        if (lane < TPN) {
            atomicAdd(&ls[4*lane+0], s0); atomicAdd(&ls[4*lane+1], s1);
            atomicAdd(&ls[4*lane+2], s2); atomicAdd(&ls[4*lane+3], s3);
            atomicAdd(&lq[4*lane+0], q0); atomicAdd(&lq[4*lane+1], q1);
            atomicAdd(&lq[4*lane+2], q2); atomicAdd(&lq[4*lane+3], q3);
        }
        __syncthreads();
        int bkt = (blockIdx.x & (NBUCKET - 1)) * 256;
        if (tid < D) {
            atomicAdd(&partOut[bkt + tid], ls[tid]);
            atomicAdd(&partOut[bkt + 128 + tid], lq[tid]);
        }
    } else {
        if (valid && e0 == 0) ((float4*)out)[nc * TPN + l4] = acc;
    }
}

// ---------------- node-blocked GEMM: NPT nodes x 4 outputs per thread ----------------
// BF16OUT: store m as bf16 (stats still fp32-accurate)
template <int DIN, int DOUT, int RELU, int EPI, int NPT, int BF16OUT>
__global__ void k_gemm(const float* __restrict__ h, const float* __restrict__ W,
                       const float* __restrict__ bias, float* __restrict__ partOut,
                       void* __restrict__ m, int n) {
    const int TPN = DOUT / 4;
    const int GPB = 256 / TPN;
    __shared__ float Wl[DIN * DOUT];
    __shared__ float ls[EPI ? DOUT : 1], lq[EPI ? DOUT : 1];
    int tid = threadIdx.x;
    for (int i = tid; i < DIN * DOUT / 4; i += 256)
        ((float4*)Wl)[i] = ((const float4*)W)[i];
    if (EPI && tid < DOUT) { ls[tid] = 0.f; lq[tid] = 0.f; }
    __syncthreads();

    int jq = tid % TPN;
    int group = tid / TPN;
    int node0 = (blockIdx.x * GPB + group) * NPT;
    const float4* h4 = (const float4*)h;
    int hb[NPT];
    bool val[NPT];
#pragma unroll
    for (int i = 0; i < NPT; ++i) {
        int nd = node0 + i;
        val[i] = nd < n;
        hb[i] = (val[i] ? nd : n - 1) * (DIN / 4);
    }
    float4 acc[NPT];
#pragma unroll
    for (int i = 0; i < NPT; ++i) acc[i] = {0.f, 0.f, 0.f, 0.f};

#pragma unroll 4
    for (int k4 = 0; k4 < DIN / 4; ++k4) {
        const float* wb = &Wl[(k4 * 4) * DOUT + jq * 4];
        float4 w0 = *(const float4*)(wb);
        float4 w1 = *(const float4*)(wb + DOUT);
        float4 w2 = *(const float4*)(wb + 2 * DOUT);
        float4 w3 = *(const float4*)(wb + 3 * DOUT);
#pragma unroll
        for (int i = 0; i < NPT; ++i) {
            float4 hv = h4[hb[i] + k4];
            acc[i].x += hv.x*w0.x + hv.y*w1.x + hv.z*w2.x + hv.w*w3.x;
            acc[i].y += hv.x*w0.y + hv.y*w1.y + hv.z*w2.y + hv.w*w3.y;
            acc[i].z += hv.x*w0.z + hv.y*w1.z + hv.z*w2.z + hv.w*w3.z;
            acc[i].w += hv.x*w0.w + hv.y*w1.w + hv.z*w2.w + hv.w*w3.w;
        }
    }

    float4 bv = {0,0,0,0};
    if (EPI) bv = ((const float4*)bias)[jq];
    float4 sv = {0,0,0,0}, qv = {0,0,0,0};
#pragma unroll
    for (int i = 0; i < NPT; ++i) {
        float4 a = acc[i];
        if (EPI) {
            a.x += bv.x; a.y += bv.y; a.z += bv.z; a.w += bv.w;
            if (RELU) {
                a.x = fmaxf(a.x, 0.f); a.y = fmaxf(a.y, 0.f);
                a.z = fmaxf(a.z, 0.f); a.w = fmaxf(a.w, 0.f);
            }
        }
        if (val[i]) {
            if (BF16OUT) {
                ushort4 o;
                o.x = f2bf(a.x); o.y = f2bf(a.y); o.z = f2bf(a.z); o.w = f2bf(a.w);
                *(ushort4*)((unsigned short*)m + (size_t)(node0 + i) * DOUT + (jq << 2)) = o;
            } else {
                ((float4*)m)[(size_t)(node0 + i) * TPN + jq] = a;
            }
            if (EPI) {
                sv.x += a.x; sv.y += a.y; sv.z += a.z; sv.w += a.w;
                qv.x += a.x*a.x; qv.y += a.y*a.y; qv.z += a.z*a.z; qv.w += a.w*a.w;
            }
        }
    }
    if (EPI) {
        for (int off = TPN; off < 64; off <<= 1) {
            sv.x += __shfl_down(sv.x, off, 64); sv.y += __shfl_down(sv.y, off, 64);
            sv.z += __shfl_down(sv.z, off, 64); sv.w += __shfl_down(sv.w, off, 64);
            qv.x += __shfl_down(qv.x, off, 64); qv.y += __shfl_down(qv.y, off, 64);
            qv.z += __shfl_down(qv.z, off, 64); qv.w += __shfl_down(qv.w, off, 64);
        }
        int lane = tid & 63;
        if (lane < TPN) {
            atomicAdd(&ls[4*lane+0], sv.x); atomicAdd(&ls[4*lane+1], sv.y);
            atomicAdd(&ls[4*lane+2], sv.z); atomicAdd(&ls[4*lane+3], sv.w);
            atomicAdd(&lq[4*lane+0], qv.x); atomicAdd(&lq[4*lane+1], qv.y);
            atomicAdd(&lq[4*lane+2], qv.z); atomicAdd(&lq[4*lane+3], qv.w);
        }
        __syncthreads();
        int bkt = (blockIdx.x & (NBUCKET - 1)) * 256;
        if (tid < DOUT) {
            atomicAdd(&partOut[bkt + tid], ls[tid]);
            atomicAdd(&partOut[bkt + 128 + tid], lq[tid]);
        }
    }
}

// ---------------- fused pool (BN5 consumed inline) + MLP head ----------------
__global__ void k_poolhead(const float* __restrict__ h, const int* __restrict__ batch,
                           const float* __restrict__ partIn, const float* __restrict__ gmv,
                           const float* __restrict__ btv,
                           const float* __restrict__ fc1w, const float* __restrict__ fc1b,
                           const float* __restrict__ fc2w, const float* __restrict__ fc2b,
                           float* __restrict__ out, int n) {
    __shared__ float tmp[256];
    __shared__ float pl[128];
    __shared__ float scs[128], shs[128];
    int g = blockIdx.x;
    int tid = threadIdx.x;
    if (tid < 128) {
        float s = 0.f, q = 0.f;
#pragma unroll
        for (int b2 = 0; b2 < NBUCKET; ++b2) {
            s += partIn[b2 * 256 + tid];
            q += partIn[b2 * 256 + 128 + tid];
        }
        float mu = s / (float)n;
        float var = q / (float)n - mu * mu;
        float a = gmv[tid] * rsqrtf(var + 1e-5f);
        scs[tid] = a;
        shs[tid] = btv[tid] - mu * a;
    }
    int j = tid & 127, prt = tid >> 7;
    int a = 0, b = n;
    while (a < b) { int mid = (a + b) >> 1; if (batch[mid] < g) a = mid + 1; else b = mid; }
    int lo = a;
    b = n;
    while (a < b) { int mid = (a + b) >> 1; if (batch[mid] < g + 1) a = mid + 1; else b = mid; }
    int hi = a;

    float acc = 0.f;
    for (int node = lo + prt; node < hi; node += 2) acc += h[(long)node * 128 + j];
    tmp[tid] = acc;
    __syncthreads();
    if (tid < 128) {
        float cnt = (float)(hi - lo);
        float p = scs[tid] * (tmp[tid] + tmp[tid + 128]) + shs[tid] * cnt;
        pl[tid] = fmaxf(p, 0.f);
    }
    __syncthreads();
    if (tid < 64) {
        float v1 = fc1b[tid];
        for (int k = 0; k < 128; ++k) v1 += pl[k] * fc1w[k * 64 + tid];
        v1 = fmaxf(v1, 0.f);
        float v = v1 * fc2w[tid];
        for (int off = 32; off > 0; off >>= 1) v += __shfl_down(v, off, 64);
        if (tid == 0) out[g] = v + fc2b[0];
    }
}

// ---------------- driver ----------------
extern "C" void kernel_launch(void* const* d_in, const int* in_sizes, int n_in,
                              void* d_out, int out_size, void* d_ws, size_t ws_size,
                              hipStream_t stream) {
    const float* x     = (const float*)d_in[0];
    const int*   ei    = (const int*)d_in[1];
    const float* ew    = (const float*)d_in[2];
    const int*   batch = (const int*)d_in[3];
    const float *W[5], *b[5], *gm[5], *bt[5];
    for (int i = 0; i < 5; ++i) {
        W[i]  = (const float*)d_in[4 + 4 * i];
        b[i]  = (const float*)d_in[5 + 4 * i];
        gm[i] = (const float*)d_in[6 + 4 * i];
        bt[i] = (const float*)d_in[7 + 4 * i];
    }
    const float* fc1w = (const float*)d_in[24];
    const float* fc1b = (const float*)d_in[25];
    const float* fc2w = (const float*)d_in[26];
    const float* fc2b = (const float*)d_in[27];
    float* out = (float*)d_out;

    // workspace layout
    char* wsb = (char*)d_ws;
    float* dis    = (float*)wsb;  wsb += sizeof(float) * NN;
    int*   ptr    = (int*)wsb;    wsb += sizeof(int) * (NN + 4);
    int*   bb     = (int*)wsb;    wsb += sizeof(int) * ABLK * NBKT;
    int*   totals = (int*)wsb;    wsb += sizeof(int) * (NBKT + 1);
    int*   bbase  = (int*)wsb;    wsb += sizeof(int) * (NBKT + 3);
    int2*  staging= (int2*)wsb;   wsb += sizeof(int2) * NE;
    int2*  csr    = (int2*)wsb;   wsb += sizeof(int2) * NE;
    float* part   = (float*)wsb;  wsb += sizeof(float) * 5 * PARTSZ;
    unsigned short* bufB = (unsigned short*)wsb;  wsb += sizeof(unsigned short) * (size_t)NN * 64;
    float* buf1   = (float*)wsb;  wsb += sizeof(float) * (long)NN * 128;
    float* buf2   = (float*)wsb;  wsb += sizeof(float) * (long)NN * 128;

    const int* row = ei;
    const int* col = ei + NE;
    const int B = 256;
    const int NB_N = (NN + B - 1) / B;   // 196

    // prologue: bucketed CSR build
    k_init<<<(5 * PARTSZ + B - 1) / B, B, 0, stream>>>(part);
    kA1<<<ABLK, B, 0, stream>>>(col, bb, NE);
    kA2a<<<NBKT, B, 0, stream>>>(bb, totals);
    kA2b<<<1, B, 0, stream>>>(totals, bbase);
    kA3<<<ABLK, B, 0, stream>>>(row, col, ew, bb, bbase, staging, NE);
    kB<<<NBKT, B, 0, stream>>>(bbase, staging, csr, ptr, dis, NN);
    k_scale<<<NB_N, B, 0, stream>>>(ptr, csr, dis, NN);

    auto grid4 = [](long threads) { return (int)((threads + 255) / 256); };
    auto ggrid = [](int npb) { return (NN + npb - 1) / npb; };

    // L1: gemm 128->16 (fp32), gather16 EPI fp32 (produce part[0])
    k_gemm<128, 16, 0, 0, 2, 0><<<ggrid((256/4)*2), B, 0, stream>>>(x, W[0], b[0], nullptr, buf1, NN);
    k_gather<16, 1, 0, 0, 1, 0><<<grid4((long)NN * 4), B, 0, stream>>>(buf1, ptr, csr, dis,
                                                                       nullptr, nullptr, nullptr,
                                                                       b[0], part + 0 * PARTSZ, buf2, NN);

    // L2: gather16 fp32 (consume part[0]), gemm 16->32 -> bf16 m2 (produce part[1])
    k_gather<16, 1, 1, 0, 0, 0><<<grid4((long)NN * 4), B, 0, stream>>>(buf2, ptr, csr, dis,
                                                                       part + 0 * PARTSZ, gm[0], bt[0],
                                                                       nullptr, nullptr, buf1, NN);
    k_gemm<16, 32, 1, 1, 4, 1><<<ggrid((256/8)*4), B, 0, stream>>>(buf1, W[1], b[1], part + 1 * PARTSZ, bufB, NN);

    // L3: gather32 EP=4 bf16-in (consume part[1]), gemm 32->64 -> bf16 m3 (produce part[2])
    k_gather<32, 4, 1, 0, 0, 1><<<grid4((long)NN * 32), B, 0, stream>>>(bufB, ptr, csr, dis,
                                                                        part + 1 * PARTSZ, gm[1], bt[1],
                                                                        nullptr, nullptr, buf1, NN);
    k_gemm<32, 64, 1, 1, 4, 1><<<ggrid((256/16)*4), B, 0, stream>>>(buf1, W[2], b[2], part + 2 * PARTSZ, bufB, NN);

    // L4: gather64 EP=4 bf16-in (consume part[2]), gemm 64->64 -> bf16 m4 (produce part[3])
    k_gather<64, 4, 1, 0, 0, 1><<<grid4((long)NN * 64), B, 0, stream>>>(bufB, ptr, csr, dis,
                                                                        part + 2 * PARTSZ, gm[2], bt[2],
                                                                        nullptr, nullptr, buf1, NN);
    k_gemm<64, 64, 0, 1, 4, 1><<<ggrid((256/16)*4), B, 0, stream>>>(buf1, W[3], b[3], part + 3 * PARTSZ, bufB, NN);

    // L5: gather64 EP=4 bf16-in (consume part[3]; BN4+relu per-edge), gemm 64->128 fp32 (produce part[4])
    k_gather<64, 4, 0, 1, 0, 1><<<grid4((long)NN * 64), B, 0, stream>>>(bufB, ptr, csr, dis,
                                                                        part + 3 * PARTSZ, gm[3], bt[3],
                                                                        nullptr, nullptr, buf1, NN);
    k_gemm<64, 128, 0, 1, 4, 0><<<ggrid((256/32)*4), B, 0, stream>>>(buf1, W[4], b[4], part + 4 * PARTSZ, buf2, NN);

    // fused pool (consume part[4] -> BN5) + head
    k_poolhead<<<NG, 256, 0, stream>>>(buf2, batch, part + 4 * PARTSZ, gm[4], bt[4],
                                       fc1w, fc1b, fc2w, fc2b, out, NN);
}

// Round 12
// 421.632 us; speedup vs baseline: 1.1045x; 1.0103x over previous
//
#include <hip/hip_runtime.h>
#include <stdint.h>

#define NN 50000
#define NE 800000
#define NG 256
#define NBUCKET 16
#define PARTSZ (NBUCKET * 256)

// bucketed CSR build params
#define NBKT 391      // node buckets of 128
#define ABLK 391
#define ASLICE 2048
#define BCAP 2560

__device__ __forceinline__ float bf2f(unsigned short u) {
    return __uint_as_float(((unsigned)u) << 16);
}
__device__ __forceinline__ unsigned short f2bf(float f) {
    unsigned b = __float_as_uint(f);
    return (unsigned short)((b + 0x7FFF + ((b >> 16) & 1)) >> 16);  // RNE
}

// ---------------- prologue ----------------
// A1: per-(block,bucket) edge counts via LDS histogram; also zeroes part (folded k_init)
__global__ void kA1(const int* __restrict__ col, int* __restrict__ bb, float* part, int e) {
    __shared__ int cnt[NBKT];
    for (int j = threadIdx.x; j < NBKT; j += 256) cnt[j] = 0;
    for (int i = blockIdx.x * 256 + threadIdx.x; i < 5 * PARTSZ; i += ABLK * 256) part[i] = 0.f;
    __syncthreads();
    int start = blockIdx.x * ASLICE;
    int end = min(start + ASLICE, e);
    for (int i = start + threadIdx.x; i < end; i += 256)
        atomicAdd(&cnt[col[i] >> 7], 1);
    __syncthreads();
    for (int j = threadIdx.x; j < NBKT; j += 256) bb[blockIdx.x * NBKT + j] = cnt[j];
}

__global__ void kA2a(int* __restrict__ bb, int* __restrict__ totals) {
    __shared__ int v[ABLK];
    int k = blockIdx.x;
    for (int b = threadIdx.x; b < ABLK; b += 256) v[b] = bb[b * NBKT + k];
    __syncthreads();
    if (threadIdx.x == 0) {
        int run = 0;
        for (int b = 0; b < ABLK; ++b) { int t = v[b]; v[b] = run; run += t; }
        totals[k] = run;
    }
    __syncthreads();
    for (int b = threadIdx.x; b < ABLK; b += 256) bb[b * NBKT + k] = v[b];
}

__global__ void kA2b(const int* __restrict__ totals, int* __restrict__ bucketbase) {
    __shared__ int v[NBKT];
    for (int j = threadIdx.x; j < NBKT; j += 256) v[j] = totals[j];
    __syncthreads();
    if (threadIdx.x == 0) {
        int run = 0;
        for (int k = 0; k < NBKT; ++k) { int t = v[k]; v[k] = run; run += t; }
        bucketbase[NBKT] = run;
    }
    __syncthreads();
    for (int j = threadIdx.x; j < NBKT; j += 256) bucketbase[j] = v[j];
}

__global__ void kA3(const int* __restrict__ row, const int* __restrict__ col,
                    const float* __restrict__ ew, const int* __restrict__ bb,
                    const int* __restrict__ bucketbase, int2* __restrict__ staging, int e) {
    __shared__ int cur[NBKT];
    for (int j = threadIdx.x; j < NBKT; j += 256)
        cur[j] = bucketbase[j] + bb[blockIdx.x * NBKT + j];
    __syncthreads();
    int start = blockIdx.x * ASLICE;
    int end = min(start + ASLICE, e);
    for (int i = start + threadIdx.x; i < end; i += 256) {
        int c = col[i];
        int p = atomicAdd(&cur[c >> 7], 1);
        staging[p] = make_int2(row[i] | ((c & 127) << 16), __float_as_int(ew[i]));
    }
}

__global__ void __launch_bounds__(256) kB(const int* __restrict__ bucketbase,
                                          const int2* __restrict__ staging,
                                          int2* __restrict__ csr, int* __restrict__ ptr,
                                          float* __restrict__ dis, int n) {
    __shared__ int2 st[BCAP];
    __shared__ int2 outb[BCAP];
    __shared__ int hist[129];
    __shared__ int cur[128];
    int k = blockIdx.x, t = threadIdx.x;
    int base = bucketbase[k], cnt = bucketbase[k + 1] - base;
    int node0 = k << 7;
    int ncov = min(128, n - node0);
    if (t < 129) hist[t] = 0;
    __syncthreads();
    if (cnt <= BCAP) {
        for (int i = t; i < cnt; i += 256) {
            int2 v = staging[base + i];
            st[i] = v;
            atomicAdd(&hist[v.x >> 16], 1);
        }
        __syncthreads();
        if (t == 0) {
            int run = 0;
            for (int j = 0; j < 128; ++j) { int h = hist[j]; hist[j] = run; run += h; }
            hist[128] = run;
        }
        __syncthreads();
        if (t < 128) cur[t] = hist[t];
        if (t < ncov) ptr[node0 + t] = base + hist[t];
        __syncthreads();
        for (int i = t; i < cnt; i += 256) {
            int2 v = st[i];
            int j = v.x >> 16;
            int p = atomicAdd(&cur[j], 1);
            outb[p] = make_int2(v.x & 0xFFFF, v.y);
        }
        __syncthreads();
        for (int i = t; i < cnt; i += 256) csr[base + i] = outb[i];
        if (t < ncov) {
            float s = 1.f;
            int a = hist[t], b2 = hist[t + 1];
            for (int p = a; p < b2; ++p) s += __int_as_float(outb[p].y);
            dis[node0 + t] = rsqrtf(s);
        }
    } else {
        for (int i = t; i < cnt; i += 256) atomicAdd(&hist[staging[base + i].x >> 16], 1);
        __syncthreads();
        if (t == 0) {
            int run = 0;
            for (int j = 0; j < 128; ++j) { int h = hist[j]; hist[j] = run; run += h; }
            hist[128] = run;
        }
        __syncthreads();
        if (t < 128) cur[t] = hist[t];
        if (t < ncov) ptr[node0 + t] = base + hist[t];
        __syncthreads();
        for (int i = t; i < cnt; i += 256) {
            int2 v = staging[base + i];
            int j = v.x >> 16;
            int p = atomicAdd(&cur[j], 1);
            csr[base + p] = make_int2(v.x & 0xFFFF, v.y);
        }
        __threadfence_block();
        __syncthreads();
        if (t < ncov) {
            float s = 1.f;
            int a = hist[t], b2 = hist[t + 1];
            for (int p = a; p < b2; ++p) s += __int_as_float(csr[base + p].y);
            dis[node0 + t] = rsqrtf(s);
        }
    }
    if (k == gridDim.x - 1 && t == 0) ptr[n] = bucketbase[NBKT];
}

// ---------------- L1: dense 128->16 ----------------
__global__ void k_gemm1(const float* __restrict__ h, const float* __restrict__ W,
                        float* __restrict__ m, int n) {
    __shared__ float Wl[128 * 16];
    int tid = threadIdx.x;
    for (int i = tid; i < 128 * 16 / 4; i += 256)
        ((float4*)Wl)[i] = ((const float4*)W)[i];
    __syncthreads();
    int jq = tid % 4, group = tid / 4;
    int node0 = (blockIdx.x * 64 + group) * 2;
    const float4* h4 = (const float4*)h;
    int hb[2]; bool val[2];
#pragma unroll
    for (int i = 0; i < 2; ++i) {
        int nd = node0 + i;
        val[i] = nd < n;
        hb[i] = (val[i] ? nd : n - 1) * 32;
    }
    float4 acc[2];
    acc[0] = {0,0,0,0}; acc[1] = {0,0,0,0};
#pragma unroll 4
    for (int k4 = 0; k4 < 32; ++k4) {
        const float* wb = &Wl[(k4 * 4) * 16 + jq * 4];
        float4 w0 = *(const float4*)(wb);
        float4 w1 = *(const float4*)(wb + 16);
        float4 w2 = *(const float4*)(wb + 32);
        float4 w3 = *(const float4*)(wb + 48);
#pragma unroll
        for (int i = 0; i < 2; ++i) {
            float4 hv = h4[hb[i] + k4];
            acc[i].x += hv.x*w0.x + hv.y*w1.x + hv.z*w2.x + hv.w*w3.x;
            acc[i].y += hv.x*w0.y + hv.y*w1.y + hv.z*w2.y + hv.w*w3.y;
            acc[i].z += hv.x*w0.z + hv.y*w1.z + hv.z*w2.z + hv.w*w3.z;
            acc[i].w += hv.x*w0.w + hv.y*w1.w + hv.z*w2.w + hv.w*w3.w;
        }
    }
#pragma unroll
    for (int i = 0; i < 2; ++i)
        if (val[i]) ((float4*)m)[(node0 + i) * 4 + jq] = acc[i];
}

// ---------------- L1 gather: EPI (bias+relu+stats) + CSR rescale write-back ----------------
__global__ void k_l1gather(const float* __restrict__ src, const int* __restrict__ ptr,
                           int2* __restrict__ csr, const float* __restrict__ dis,
                           const float* __restrict__ bias, float* __restrict__ partOut,
                           float* __restrict__ out, int n) {
    __shared__ float ls[16], lq[16];
    int tid = threadIdx.x;
    if (tid < 16) { ls[tid] = 0.f; lq[tid] = 0.f; }
    __syncthreads();
    int t = blockIdx.x * 256 + tid;
    int node = t >> 2;
    int l4 = t & 3;
    bool valid = node < n;
    int nc = valid ? node : n - 1;
    const float4* s4 = (const float4*)src;
    float dc = dis[nc];
    float w0 = dc * dc;
    float4 v = s4[nc * 4 + l4];
    float4 acc = { w0 * v.x, w0 * v.y, w0 * v.z, w0 * v.w };
    int p0 = ptr[nc], p1 = ptr[nc + 1];
    int p = p0;
    for (; p + 4 <= p1; p += 4) {
        int2 c0 = csr[p], c1 = csr[p+1], c2 = csr[p+2], c3 = csr[p+3];
        float e0 = dis[c0.x] * __int_as_float(c0.y) * dc;
        float e1 = dis[c1.x] * __int_as_float(c1.y) * dc;
        float e2 = dis[c2.x] * __int_as_float(c2.y) * dc;
        float e3 = dis[c3.x] * __int_as_float(c3.y) * dc;
        float4 u0 = s4[c0.x * 4 + l4];
        float4 u1 = s4[c1.x * 4 + l4];
        float4 u2 = s4[c2.x * 4 + l4];
        float4 u3 = s4[c3.x * 4 + l4];
        acc.x += e0*u0.x + e1*u1.x + e2*u2.x + e3*u3.x;
        acc.y += e0*u0.y + e1*u1.y + e2*u2.y + e3*u3.y;
        acc.z += e0*u0.z + e1*u1.z + e2*u2.z + e3*u3.z;
        acc.w += e0*u0.w + e1*u1.w + e2*u2.w + e3*u3.w;
        if (l4 == 0) {
            csr[p]   = make_int2(c0.x, __float_as_int(e0));
            csr[p+1] = make_int2(c1.x, __float_as_int(e1));
            csr[p+2] = make_int2(c2.x, __float_as_int(e2));
            csr[p+3] = make_int2(c3.x, __float_as_int(e3));
        }
    }
    for (; p < p1; ++p) {
        int2 ce = csr[p];
        float w = dis[ce.x] * __int_as_float(ce.y) * dc;
        float4 u = s4[ce.x * 4 + l4];
        acc.x += w*u.x; acc.y += w*u.y; acc.z += w*u.z; acc.w += w*u.w;
        if (l4 == 0) csr[p] = make_int2(ce.x, __float_as_int(w));
    }
    float4 b = ((const float4*)bias)[l4];
    acc.x = fmaxf(acc.x + b.x, 0.f);
    acc.y = fmaxf(acc.y + b.y, 0.f);
    acc.z = fmaxf(acc.z + b.z, 0.f);
    acc.w = fmaxf(acc.w + b.w, 0.f);
    if (valid) ((float4*)out)[nc * 4 + l4] = acc;
    float s0 = valid ? acc.x : 0.f, s1 = valid ? acc.y : 0.f;
    float s2 = valid ? acc.z : 0.f, s3 = valid ? acc.w : 0.f;
    float q0 = s0*s0, q1 = s1*s1, q2 = s2*s2, q3 = s3*s3;
    for (int off = 4; off < 64; off <<= 1) {
        s0 += __shfl_down(s0, off, 64); s1 += __shfl_down(s1, off, 64);
        s2 += __shfl_down(s2, off, 64); s3 += __shfl_down(s3, off, 64);
        q0 += __shfl_down(q0, off, 64); q1 += __shfl_down(q1, off, 64);
        q2 += __shfl_down(q2, off, 64); q3 += __shfl_down(q3, off, 64);
    }
    int lane = tid & 63;
    if (lane < 4) {
        atomicAdd(&ls[4*lane+0], s0); atomicAdd(&ls[4*lane+1], s1);
        atomicAdd(&ls[4*lane+2], s2); atomicAdd(&ls[4*lane+3], s3);
        atomicAdd(&lq[4*lane+0], q0); atomicAdd(&lq[4*lane+1], q1);
        atomicAdd(&lq[4*lane+2], q2); atomicAdd(&lq[4*lane+3], q3);
    }
    __syncthreads();
    int bkt = (blockIdx.x & (NBUCKET - 1)) * 256;
    if (tid < 16) {
        atomicAdd(&partOut[bkt + tid], ls[tid]);
        atomicAdd(&partOut[bkt + 128 + tid], lq[tid]);
    }
}

// row loader: fp32 float4 or bf16 ushort4 -> float4
template <int D, int BF16>
__device__ __forceinline__ float4 load_row(const void* src, int node, int l4) {
    if (BF16) {
        const unsigned short* sb = (const unsigned short*)src;
        ushort4 r = *(const ushort4*)(sb + (size_t)node * D + (l4 << 2));
        float4 f;
        f.x = bf2f(r.x); f.y = bf2f(r.y); f.z = bf2f(r.z); f.w = bf2f(r.w);
        return f;
    } else {
        const float4* s4 = (const float4*)src;
        return s4[(size_t)node * (D / 4) + l4];
    }
}

// ---------------- fused layer: gather (phase 1, LDS rows) + gemm (phase 2) ----------------
// Consumes partIn -> BN scale/shift; POSTAFF: affine hoisted out of edge loop;
// PREAFF: per-edge relu(sc*u+sh). Produces bias(+relu) gemm output + stats -> partOut.
template <int DIN, int DOUT, int EP, int POSTAFF, int PREAFF, int RELU,
          int BF16IN, int BF16OUT, int NPB>
__global__ void __launch_bounds__(256) k_fused(
        const void* __restrict__ src, const int* __restrict__ ptr,
        const int2* __restrict__ csr, const float* __restrict__ dis,
        const float* __restrict__ partIn, const float* __restrict__ gmv,
        const float* __restrict__ btv, const float* __restrict__ W,
        const float* __restrict__ bias, float* __restrict__ partOut,
        void* __restrict__ out, int n) {
    const int TPN1 = DIN / 4, LPN = TPN1 * EP, GN1 = 256 / LPN;
    const int TPN2 = DOUT / 4, G2 = 256 / TPN2;
    const int HS = DIN + 4;                    // padded row stride (bank-conflict-free)
    __shared__ float Wl[DIN * DOUT];
    __shared__ float hrow[NPB * HS];
    __shared__ float scs[DIN], shs[DIN];
    __shared__ float ls[DOUT], lq[DOUT];
    int tid = threadIdx.x;
    for (int i = tid; i < DIN * DOUT / 4; i += 256)
        ((float4*)Wl)[i] = ((const float4*)W)[i];
    if (tid < DIN) {
        float s = 0.f, q = 0.f;
#pragma unroll
        for (int b2 = 0; b2 < NBUCKET; ++b2) {
            s += partIn[b2 * 256 + tid];
            q += partIn[b2 * 256 + 128 + tid];
        }
        float mu = s / (float)n;
        float var = q / (float)n - mu * mu;
        float a = gmv[tid] * rsqrtf(var + 1e-5f);
        scs[tid] = a;
        shs[tid] = btv[tid] - mu * a;
    }
    if (tid < DOUT) { ls[tid] = 0.f; lq[tid] = 0.f; }
    __syncthreads();

    int nodebase = blockIdx.x * NPB;
    // ---- phase 1: gather into LDS rows ----
    {
        int grp = tid / LPN, r = tid % LPN;
        int e0 = r / TPN1, l4 = r % TPN1;
        float4 sc = ((const float4*)scs)[l4];
        float4 sh = ((const float4*)shs)[l4];
#pragma unroll
        for (int pass = 0; pass < NPB / GN1; ++pass) {
            int nl = pass * GN1 + grp;
            int node = nodebase + nl;
            int nc = node < n ? node : n - 1;
            float4 acc = {0.f, 0.f, 0.f, 0.f};
            float sumw = 0.f;
            if (e0 == 0) {
                float d = dis[nc];
                float w0 = d * d;
                float4 v = load_row<DIN, BF16IN>(src, nc, l4);
                if (PREAFF) {
                    v.x = fmaxf(sc.x*v.x+sh.x, 0.f); v.y = fmaxf(sc.y*v.y+sh.y, 0.f);
                    v.z = fmaxf(sc.z*v.z+sh.z, 0.f); v.w = fmaxf(sc.w*v.w+sh.w, 0.f);
                }
                acc.x = w0*v.x; acc.y = w0*v.y; acc.z = w0*v.z; acc.w = w0*v.w;
                sumw = w0;
            }
            int p0 = ptr[nc], p1 = ptr[nc + 1];
            int p = p0 + e0;
            for (; p + 3 * EP < p1; p += 4 * EP) {
                int2 c0 = csr[p], c1 = csr[p + EP], c2 = csr[p + 2*EP], c3 = csr[p + 3*EP];
                float e0w = __int_as_float(c0.y), e1w = __int_as_float(c1.y);
                float e2w = __int_as_float(c2.y), e3w = __int_as_float(c3.y);
                float4 u0 = load_row<DIN, BF16IN>(src, c0.x, l4);
                float4 u1 = load_row<DIN, BF16IN>(src, c1.x, l4);
                float4 u2 = load_row<DIN, BF16IN>(src, c2.x, l4);
                float4 u3 = load_row<DIN, BF16IN>(src, c3.x, l4);
                if (PREAFF) {
                    u0.x = fmaxf(sc.x*u0.x+sh.x,0.f); u0.y = fmaxf(sc.y*u0.y+sh.y,0.f);
                    u0.z = fmaxf(sc.z*u0.z+sh.z,0.f); u0.w = fmaxf(sc.w*u0.w+sh.w,0.f);
                    u1.x = fmaxf(sc.x*u1.x+sh.x,0.f); u1.y = fmaxf(sc.y*u1.y+sh.y,0.f);
                    u1.z = fmaxf(sc.z*u1.z+sh.z,0.f); u1.w = fmaxf(sc.w*u1.w+sh.w,0.f);
                    u2.x = fmaxf(sc.x*u2.x+sh.x,0.f); u2.y = fmaxf(sc.y*u2.y+sh.y,0.f);
                    u2.z = fmaxf(sc.z*u2.z+sh.z,0.f); u2.w = fmaxf(sc.w*u2.w+sh.w,0.f);
                    u3.x = fmaxf(sc.x*u3.x+sh.x,0.f); u3.y = fmaxf(sc.y*u3.y+sh.y,0.f);
                    u3.z = fmaxf(sc.z*u3.z+sh.z,0.f); u3.w = fmaxf(sc.w*u3.w+sh.w,0.f);
                }
                acc.x += e0w*u0.x + e1w*u1.x + e2w*u2.x + e3w*u3.x;
                acc.y += e0w*u0.y + e1w*u1.y + e2w*u2.y + e3w*u3.y;
                acc.z += e0w*u0.z + e1w*u1.z + e2w*u2.z + e3w*u3.z;
                acc.w += e0w*u0.w + e1w*u1.w + e2w*u2.w + e3w*u3.w;
                if (POSTAFF) sumw += e0w + e1w + e2w + e3w;
            }
            for (; p < p1; p += EP) {
                int2 ce = csr[p];
                float w = __int_as_float(ce.y);
                float4 u = load_row<DIN, BF16IN>(src, ce.x, l4);
                if (PREAFF) {
                    u.x = fmaxf(sc.x*u.x+sh.x,0.f); u.y = fmaxf(sc.y*u.y+sh.y,0.f);
                    u.z = fmaxf(sc.z*u.z+sh.z,0.f); u.w = fmaxf(sc.w*u.w+sh.w,0.f);
                }
                acc.x += w*u.x; acc.y += w*u.y; acc.z += w*u.z; acc.w += w*u.w;
                if (POSTAFF) sumw += w;
            }
#pragma unroll
            for (int off = TPN1; off < LPN; off <<= 1) {
                acc.x += __shfl_xor(acc.x, off, 64);
                acc.y += __shfl_xor(acc.y, off, 64);
                acc.z += __shfl_xor(acc.z, off, 64);
                acc.w += __shfl_xor(acc.w, off, 64);
                if (POSTAFF) sumw += __shfl_xor(sumw, off, 64);
            }
            if (POSTAFF) {
                acc.x = sc.x * acc.x + sh.x * sumw;
                acc.y = sc.y * acc.y + sh.y * sumw;
                acc.z = sc.z * acc.z + sh.z * sumw;
                acc.w = sc.w * acc.w + sh.w * sumw;
            }
            if (e0 == 0) *(float4*)&hrow[nl * HS + (l4 << 2)] = acc;
        }
    }
    __syncthreads();
    // ---- phase 2: gemm from LDS rows ----
    {
        int jq = tid % TPN2, g2 = tid / TPN2;
        float4 bv = ((const float4*)bias)[jq];
        float4 sv = {0,0,0,0}, qv = {0,0,0,0};
        for (int nl = g2; nl < NPB; nl += G2) {
            int node = nodebase + nl;
            bool valid = node < n;
            float4 a = {0.f, 0.f, 0.f, 0.f};
#pragma unroll
            for (int k4 = 0; k4 < DIN / 4; ++k4) {
                float4 hv = *(const float4*)&hrow[nl * HS + (k4 << 2)];
                const float* wb = &Wl[(k4 * 4) * DOUT + jq * 4];
                float4 w0 = *(const float4*)(wb);
                float4 w1 = *(const float4*)(wb + DOUT);
                float4 w2 = *(const float4*)(wb + 2 * DOUT);
                float4 w3 = *(const float4*)(wb + 3 * DOUT);
                a.x += hv.x*w0.x + hv.y*w1.x + hv.z*w2.x + hv.w*w3.x;
                a.y += hv.x*w0.y + hv.y*w1.y + hv.z*w2.y + hv.w*w3.y;
                a.z += hv.x*w0.z + hv.y*w1.z + hv.z*w2.z + hv.w*w3.z;
                a.w += hv.x*w0.w + hv.y*w1.w + hv.z*w2.w + hv.w*w3.w;
            }
            a.x += bv.x; a.y += bv.y; a.z += bv.z; a.w += bv.w;
            if (RELU) {
                a.x = fmaxf(a.x, 0.f); a.y = fmaxf(a.y, 0.f);
                a.z = fmaxf(a.z, 0.f); a.w = fmaxf(a.w, 0.f);
            }
            if (valid) {
                if (BF16OUT) {
                    ushort4 o;
                    o.x = f2bf(a.x); o.y = f2bf(a.y); o.z = f2bf(a.z); o.w = f2bf(a.w);
                    *(ushort4*)((unsigned short*)out + (size_t)node * DOUT + (jq << 2)) = o;
                } else {
                    ((float4*)out)[(size_t)node * TPN2 + jq] = a;
                }
                sv.x += a.x; sv.y += a.y; sv.z += a.z; sv.w += a.w;
                qv.x += a.x*a.x; qv.y += a.y*a.y; qv.z += a.z*a.z; qv.w += a.w*a.w;
            }
        }
        for (int off = TPN2; off < 64; off <<= 1) {
            sv.x += __shfl_down(sv.x, off, 64); sv.y += __shfl_down(sv.y, off, 64);
            sv.z += __shfl_down(sv.z, off, 64); sv.w += __shfl_down(sv.w, off, 64);
            qv.x += __shfl_down(qv.x, off, 64); qv.y += __shfl_down(qv.y, off, 64);
            qv.z += __shfl_down(qv.z, off, 64); qv.w += __shfl_down(qv.w, off, 64);
        }
        int lane = tid & 63;
        if (lane < TPN2) {
            atomicAdd(&ls[4*lane+0], sv.x); atomicAdd(&ls[4*lane+1], sv.y);
            atomicAdd(&ls[4*lane+2], sv.z); atomicAdd(&ls[4*lane+3], sv.w);
            atomicAdd(&lq[4*lane+0], qv.x); atomicAdd(&lq[4*lane+1], qv.y);
            atomicAdd(&lq[4*lane+2], qv.z); atomicAdd(&lq[4*lane+3], qv.w);
        }
        __syncthreads();
        int bkt = (blockIdx.x & (NBUCKET - 1)) * 256;
        if (tid < DOUT) {
            atomicAdd(&partOut[bkt + tid], ls[tid]);
            atomicAdd(&partOut[bkt + 128 + tid], lq[tid]);
        }
    }
}

// ---------------- fused pool (BN5 consumed inline) + MLP head ----------------
__global__ void k_poolhead(const float* __restrict__ h, const int* __restrict__ batch,
                           const float* __restrict__ partIn, const float* __restrict__ gmv,
                           const float* __restrict__ btv,
                           const float* __restrict__ fc1w, const float* __restrict__ fc1b,
                           const float* __restrict__ fc2w, const float* __restrict__ fc2b,
                           float* __restrict__ out, int n) {
    __shared__ float tmp[256];
    __shared__ float pl[128];
    __shared__ float scs[128], shs[128];
    int g = blockIdx.x;
    int tid = threadIdx.x;
    if (tid < 128) {
        float s = 0.f, q = 0.f;
#pragma unroll
        for (int b2 = 0; b2 < NBUCKET; ++b2) {
            s += partIn[b2 * 256 + tid];
            q += partIn[b2 * 256 + 128 + tid];
        }
        float mu = s / (float)n;
        float var = q / (float)n - mu * mu;
        float a = gmv[tid] * rsqrtf(var + 1e-5f);
        scs[tid] = a;
        shs[tid] = btv[tid] - mu * a;
    }
    int j = tid & 127, prt = tid >> 7;
    int a = 0, b = n;
    while (a < b) { int mid = (a + b) >> 1; if (batch[mid] < g) a = mid + 1; else b = mid; }
    int lo = a;
    b = n;
    while (a < b) { int mid = (a + b) >> 1; if (batch[mid] < g + 1) a = mid + 1; else b = mid; }
    int hi = a;

    float acc = 0.f;
    for (int node = lo + prt; node < hi; node += 2) acc += h[(long)node * 128 + j];
    tmp[tid] = acc;
    __syncthreads();
    if (tid < 128) {
        float cnt = (float)(hi - lo);
        float p = scs[tid] * (tmp[tid] + tmp[tid + 128]) + shs[tid] * cnt;
        pl[tid] = fmaxf(p, 0.f);
    }
    __syncthreads();
    if (tid < 64) {
        float v1 = fc1b[tid];
        for (int k = 0; k < 128; ++k) v1 += pl[k] * fc1w[k * 64 + tid];
        v1 = fmaxf(v1, 0.f);
        float v = v1 * fc2w[tid];
        for (int off = 32; off > 0; off >>= 1) v += __shfl_down(v, off, 64);
        if (tid == 0) out[g] = v + fc2b[0];
    }
}

// ---------------- driver ----------------
extern "C" void kernel_launch(void* const* d_in, const int* in_sizes, int n_in,
                              void* d_out, int out_size, void* d_ws, size_t ws_size,
                              hipStream_t stream) {
    const float* x     = (const float*)d_in[0];
    const int*   ei    = (const int*)d_in[1];
    const float* ew    = (const float*)d_in[2];
    const int*   batch = (const int*)d_in[3];
    const float *W[5], *b[5], *gm[5], *bt[5];
    for (int i = 0; i < 5; ++i) {
        W[i]  = (const float*)d_in[4 + 4 * i];
        b[i]  = (const float*)d_in[5 + 4 * i];
        gm[i] = (const float*)d_in[6 + 4 * i];
        bt[i] = (const float*)d_in[7 + 4 * i];
    }
    const float* fc1w = (const float*)d_in[24];
    const float* fc1b = (const float*)d_in[25];
    const float* fc2w = (const float*)d_in[26];
    const float* fc2b = (const float*)d_in[27];
    float* out = (float*)d_out;

    // workspace layout (16B-align the big arrays)
    char* wsb = (char*)d_ws;
    float* dis    = (float*)wsb;  wsb += sizeof(float) * NN;
    int*   ptr    = (int*)wsb;    wsb += sizeof(int) * (NN + 4);
    int*   bb     = (int*)wsb;    wsb += sizeof(int) * ABLK * NBKT;
    int*   totals = (int*)wsb;    wsb += sizeof(int) * (NBKT + 1);
    int*   bbase  = (int*)wsb;    wsb += sizeof(int) * (NBKT + 3);
    wsb = (char*)(((uintptr_t)wsb + 15) & ~(uintptr_t)15);
    int2*  staging= (int2*)wsb;   wsb += sizeof(int2) * NE;
    int2*  csr    = (int2*)wsb;   wsb += sizeof(int2) * NE;
    float* part   = (float*)wsb;  wsb += sizeof(float) * 5 * PARTSZ;
    unsigned short* bufB1 = (unsigned short*)wsb;  wsb += sizeof(unsigned short) * (size_t)NN * 64;
    unsigned short* bufB2 = (unsigned short*)wsb;  wsb += sizeof(unsigned short) * (size_t)NN * 64;
    float* buf1   = (float*)wsb;  wsb += sizeof(float) * (size_t)NN * 16;
    float* buf2   = (float*)wsb;  wsb += sizeof(float) * (size_t)NN * 128;

    const int* row = ei;
    const int* col = ei + NE;
    const int B = 256;
    const int NBF = (NN + 15) / 16;   // 3125 fused-layer blocks

    // prologue: bucketed CSR build (k_init folded into kA1)
    kA1<<<ABLK, B, 0, stream>>>(col, bb, part, NE);
    kA2a<<<NBKT, B, 0, stream>>>(bb, totals);
    kA2b<<<1, B, 0, stream>>>(totals, bbase);
    kA3<<<ABLK, B, 0, stream>>>(row, col, ew, bb, bbase, staging, NE);
    kB<<<NBKT, B, 0, stream>>>(bbase, staging, csr, ptr, dis, NN);

    // L1: dense 128->16, then gather+bias+relu+stats (+ CSR rescale write-back)
    k_gemm1<<<(NN + 127) / 128, B, 0, stream>>>(x, W[0], buf1, NN);
    k_l1gather<<<(NN * 4 + 255) / 256, B, 0, stream>>>(buf1, ptr, csr, dis,
                                                       b[0], part + 0 * PARTSZ, buf2, NN);

    // fused layers: gather(BN from part[i-1]) + gemm + stats -> part[i]
    // F2: 16->32, consume part[0], fp32 in, bf16 out
    k_fused<16, 32, 4, 1, 0, 1, 0, 1, 16><<<NBF, B, 0, stream>>>(
        buf2, ptr, csr, dis, part + 0 * PARTSZ, gm[0], bt[0],
        W[1], b[1], part + 1 * PARTSZ, bufB1, NN);
    // F3: 32->64, consume part[1], bf16 in/out
    k_fused<32, 64, 4, 1, 0, 1, 1, 1, 16><<<NBF, B, 0, stream>>>(
        bufB1, ptr, csr, dis, part + 1 * PARTSZ, gm[1], bt[1],
        W[2], b[2], part + 2 * PARTSZ, bufB2, NN);
    // F4: 64->64, consume part[2], bf16 in/out, no relu (post-BN relu in F5's PREAFF)
    k_fused<64, 64, 4, 1, 0, 0, 1, 1, 16><<<NBF, B, 0, stream>>>(
        bufB2, ptr, csr, dis, part + 2 * PARTSZ, gm[2], bt[2],
        W[3], b[3], part + 3 * PARTSZ, bufB1, NN);
    // F5: 64->128, consume part[3] (PREAFF: per-edge relu(BN4)), bf16 in, fp32 out
    k_fused<64, 128, 4, 0, 1, 0, 1, 0, 16><<<NBF, B, 0, stream>>>(
        bufB1, ptr, csr, dis, part + 3 * PARTSZ, gm[3], bt[3],
        W[4], b[4], part + 4 * PARTSZ, buf2, NN);

    // fused pool (consume part[4] -> BN5) + head
    k_poolhead<<<NG, B, 0, stream>>>(buf2, batch, part + 4 * PARTSZ, gm[4], bt[4],
                                     fc1w, fc1b, fc2w, fc2b, out, NN);
}

// Round 13
// 414.490 us; speedup vs baseline: 1.1235x; 1.0172x over previous
//
#include <hip/hip_runtime.h>
#include <stdint.h>

#define NN 50000
#define NE 800000
#define NG 256
#define NBUCKET 16
#define PARTSZ (NBUCKET * 256)

// bucketed CSR build params
#define NBKT 391      // node buckets of 128
#define ABLK 391
#define ASLICE 2048
#define BCAP 2560

__device__ __forceinline__ float bf2f(unsigned short u) {
    return __uint_as_float(((unsigned)u) << 16);
}
__device__ __forceinline__ unsigned short f2bf(float f) {
    unsigned b = __float_as_uint(f);
    return (unsigned short)((b + 0x7FFF + ((b >> 16) & 1)) >> 16);  // RNE
}

// ---------------- prologue ----------------
// A1: per-(block,bucket) edge counts via LDS histogram; also zeroes part (folded k_init)
__global__ void kA1(const int* __restrict__ col, int* __restrict__ bb, float* part, int e) {
    __shared__ int cnt[NBKT];
    for (int j = threadIdx.x; j < NBKT; j += 256) cnt[j] = 0;
    for (int i = blockIdx.x * 256 + threadIdx.x; i < 5 * PARTSZ; i += ABLK * 256) part[i] = 0.f;
    __syncthreads();
    int start = blockIdx.x * ASLICE;
    int end = min(start + ASLICE, e);
    for (int i = start + threadIdx.x; i < end; i += 256)
        atomicAdd(&cnt[col[i] >> 7], 1);
    __syncthreads();
    for (int j = threadIdx.x; j < NBKT; j += 256) bb[blockIdx.x * NBKT + j] = cnt[j];
}

__global__ void kA2a(int* __restrict__ bb, int* __restrict__ totals) {
    __shared__ int v[ABLK];
    int k = blockIdx.x;
    for (int b = threadIdx.x; b < ABLK; b += 256) v[b] = bb[b * NBKT + k];
    __syncthreads();
    if (threadIdx.x == 0) {
        int run = 0;
        for (int b = 0; b < ABLK; ++b) { int t = v[b]; v[b] = run; run += t; }
        totals[k] = run;
    }
    __syncthreads();
    for (int b = threadIdx.x; b < ABLK; b += 256) bb[b * NBKT + k] = v[b];
}

__global__ void kA2b(const int* __restrict__ totals, int* __restrict__ bucketbase) {
    __shared__ int v[NBKT];
    for (int j = threadIdx.x; j < NBKT; j += 256) v[j] = totals[j];
    __syncthreads();
    if (threadIdx.x == 0) {
        int run = 0;
        for (int k = 0; k < NBKT; ++k) { int t = v[k]; v[k] = run; run += t; }
        bucketbase[NBKT] = run;
    }
    __syncthreads();
    for (int j = threadIdx.x; j < NBKT; j += 256) bucketbase[j] = v[j];
}

__global__ void kA3(const int* __restrict__ row, const int* __restrict__ col,
                    const float* __restrict__ ew, const int* __restrict__ bb,
                    const int* __restrict__ bucketbase, int2* __restrict__ staging, int e) {
    __shared__ int cur[NBKT];
    for (int j = threadIdx.x; j < NBKT; j += 256)
        cur[j] = bucketbase[j] + bb[blockIdx.x * NBKT + j];
    __syncthreads();
    int start = blockIdx.x * ASLICE;
    int end = min(start + ASLICE, e);
    for (int i = start + threadIdx.x; i < end; i += 256) {
        int c = col[i];
        int p = atomicAdd(&cur[c >> 7], 1);
        staging[p] = make_int2(row[i] | ((c & 127) << 16), __float_as_int(ew[i]));
    }
}

__global__ void __launch_bounds__(256) kB(const int* __restrict__ bucketbase,
                                          const int2* __restrict__ staging,
                                          int2* __restrict__ csr, int* __restrict__ ptr,
                                          float* __restrict__ dis, int n) {
    __shared__ int2 st[BCAP];
    __shared__ int2 outb[BCAP];
    __shared__ int hist[129];
    __shared__ int cur[128];
    int k = blockIdx.x, t = threadIdx.x;
    int base = bucketbase[k], cnt = bucketbase[k + 1] - base;
    int node0 = k << 7;
    int ncov = min(128, n - node0);
    if (t < 129) hist[t] = 0;
    __syncthreads();
    if (cnt <= BCAP) {
        for (int i = t; i < cnt; i += 256) {
            int2 v = staging[base + i];
            st[i] = v;
            atomicAdd(&hist[v.x >> 16], 1);
        }
        __syncthreads();
        if (t == 0) {
            int run = 0;
            for (int j = 0; j < 128; ++j) { int h = hist[j]; hist[j] = run; run += h; }
            hist[128] = run;
        }
        __syncthreads();
        if (t < 128) cur[t] = hist[t];
        if (t < ncov) ptr[node0 + t] = base + hist[t];
        __syncthreads();
        for (int i = t; i < cnt; i += 256) {
            int2 v = st[i];
            int j = v.x >> 16;
            int p = atomicAdd(&cur[j], 1);
            outb[p] = make_int2(v.x & 0xFFFF, v.y);
        }
        __syncthreads();
        for (int i = t; i < cnt; i += 256) csr[base + i] = outb[i];
        if (t < ncov) {
            float s = 1.f;
            int a = hist[t], b2 = hist[t + 1];
            for (int p = a; p < b2; ++p) s += __int_as_float(outb[p].y);
            dis[node0 + t] = rsqrtf(s);
        }
    } else {
        for (int i = t; i < cnt; i += 256) atomicAdd(&hist[staging[base + i].x >> 16], 1);
        __syncthreads();
        if (t == 0) {
            int run = 0;
            for (int j = 0; j < 128; ++j) { int h = hist[j]; hist[j] = run; run += h; }
            hist[128] = run;
        }
        __syncthreads();
        if (t < 128) cur[t] = hist[t];
        if (t < ncov) ptr[node0 + t] = base + hist[t];
        __syncthreads();
        for (int i = t; i < cnt; i += 256) {
            int2 v = staging[base + i];
            int j = v.x >> 16;
            int p = atomicAdd(&cur[j], 1);
            csr[base + p] = make_int2(v.x & 0xFFFF, v.y);
        }
        __threadfence_block();
        __syncthreads();
        if (t < ncov) {
            float s = 1.f;
            int a = hist[t], b2 = hist[t + 1];
            for (int p = a; p < b2; ++p) s += __int_as_float(csr[base + p].y);
            dis[node0 + t] = rsqrtf(s);
        }
    }
    if (k == gridDim.x - 1 && t == 0) ptr[n] = bucketbase[NBKT];
}

// ---------------- L1: dense 128->16 ----------------
__global__ void k_gemm1(const float* __restrict__ h, const float* __restrict__ W,
                        float* __restrict__ m, int n) {
    __shared__ float Wl[128 * 16];
    int tid = threadIdx.x;
    for (int i = tid; i < 128 * 16 / 4; i += 256)
        ((float4*)Wl)[i] = ((const float4*)W)[i];
    __syncthreads();
    int jq = tid % 4, group = tid / 4;
    int node0 = (blockIdx.x * 64 + group) * 2;
    const float4* h4 = (const float4*)h;
    int hb[2]; bool val[2];
#pragma unroll
    for (int i = 0; i < 2; ++i) {
        int nd = node0 + i;
        val[i] = nd < n;
        hb[i] = (val[i] ? nd : n - 1) * 32;
    }
    float4 acc[2];
    acc[0] = {0,0,0,0}; acc[1] = {0,0,0,0};
#pragma unroll 4
    for (int k4 = 0; k4 < 32; ++k4) {
        const float* wb = &Wl[(k4 * 4) * 16 + jq * 4];
        float4 w0 = *(const float4*)(wb);
        float4 w1 = *(const float4*)(wb + 16);
        float4 w2 = *(const float4*)(wb + 32);
        float4 w3 = *(const float4*)(wb + 48);
#pragma unroll
        for (int i = 0; i < 2; ++i) {
            float4 hv = h4[hb[i] + k4];
            acc[i].x += hv.x*w0.x + hv.y*w1.x + hv.z*w2.x + hv.w*w3.x;
            acc[i].y += hv.x*w0.y + hv.y*w1.y + hv.z*w2.y + hv.w*w3.y;
            acc[i].z += hv.x*w0.z + hv.y*w1.z + hv.z*w2.z + hv.w*w3.z;
            acc[i].w += hv.x*w0.w + hv.y*w1.w + hv.z*w2.w + hv.w*w3.w;
        }
    }
#pragma unroll
    for (int i = 0; i < 2; ++i)
        if (val[i]) ((float4*)m)[(node0 + i) * 4 + jq] = acc[i];
}

// ---------------- L1 gather: EPI (bias+relu+stats) + CSR rescale write-back ----------------
__global__ void k_l1gather(const float* __restrict__ src, const int* __restrict__ ptr,
                           int2* __restrict__ csr, const float* __restrict__ dis,
                           const float* __restrict__ bias, float* __restrict__ partOut,
                           float* __restrict__ out, int n) {
    __shared__ float ls[16], lq[16];
    int tid = threadIdx.x;
    if (tid < 16) { ls[tid] = 0.f; lq[tid] = 0.f; }
    __syncthreads();
    int t = blockIdx.x * 256 + tid;
    int node = t >> 2;
    int l4 = t & 3;
    bool valid = node < n;
    int nc = valid ? node : n - 1;
    const float4* s4 = (const float4*)src;
    float dc = dis[nc];
    float w0 = dc * dc;
    float4 v = s4[nc * 4 + l4];
    float4 acc = { w0 * v.x, w0 * v.y, w0 * v.z, w0 * v.w };
    int p0 = ptr[nc], p1 = ptr[nc + 1];
    int p = p0;
    for (; p + 4 <= p1; p += 4) {
        int2 c0 = csr[p], c1 = csr[p+1], c2 = csr[p+2], c3 = csr[p+3];
        float e0 = dis[c0.x] * __int_as_float(c0.y) * dc;
        float e1 = dis[c1.x] * __int_as_float(c1.y) * dc;
        float e2 = dis[c2.x] * __int_as_float(c2.y) * dc;
        float e3 = dis[c3.x] * __int_as_float(c3.y) * dc;
        float4 u0 = s4[c0.x * 4 + l4];
        float4 u1 = s4[c1.x * 4 + l4];
        float4 u2 = s4[c2.x * 4 + l4];
        float4 u3 = s4[c3.x * 4 + l4];
        acc.x += e0*u0.x + e1*u1.x + e2*u2.x + e3*u3.x;
        acc.y += e0*u0.y + e1*u1.y + e2*u2.y + e3*u3.y;
        acc.z += e0*u0.z + e1*u1.z + e2*u2.z + e3*u3.z;
        acc.w += e0*u0.w + e1*u1.w + e2*u2.w + e3*u3.w;
        if (l4 == 0) {
            csr[p]   = make_int2(c0.x, __float_as_int(e0));
            csr[p+1] = make_int2(c1.x, __float_as_int(e1));
            csr[p+2] = make_int2(c2.x, __float_as_int(e2));
            csr[p+3] = make_int2(c3.x, __float_as_int(e3));
        }
    }
    for (; p < p1; ++p) {
        int2 ce = csr[p];
        float w = dis[ce.x] * __int_as_float(ce.y) * dc;
        float4 u = s4[ce.x * 4 + l4];
        acc.x += w*u.x; acc.y += w*u.y; acc.z += w*u.z; acc.w += w*u.w;
        if (l4 == 0) csr[p] = make_int2(ce.x, __float_as_int(w));
    }
    float4 b = ((const float4*)bias)[l4];
    acc.x = fmaxf(acc.x + b.x, 0.f);
    acc.y = fmaxf(acc.y + b.y, 0.f);
    acc.z = fmaxf(acc.z + b.z, 0.f);
    acc.w = fmaxf(acc.w + b.w, 0.f);
    if (valid) ((float4*)out)[nc * 4 + l4] = acc;
    float s0 = valid ? acc.x : 0.f, s1 = valid ? acc.y : 0.f;
    float s2 = valid ? acc.z : 0.f, s3 = valid ? acc.w : 0.f;
    float q0 = s0*s0, q1 = s1*s1, q2 = s2*s2, q3 = s3*s3;
    for (int off = 4; off < 64; off <<= 1) {
        s0 += __shfl_down(s0, off, 64); s1 += __shfl_down(s1, off, 64);
        s2 += __shfl_down(s2, off, 64); s3 += __shfl_down(s3, off, 64);
        q0 += __shfl_down(q0, off, 64); q1 += __shfl_down(q1, off, 64);
        q2 += __shfl_down(q2, off, 64); q3 += __shfl_down(q3, off, 64);
    }
    int lane = tid & 63;
    if (lane < 4) {
        atomicAdd(&ls[4*lane+0], s0); atomicAdd(&ls[4*lane+1], s1);
        atomicAdd(&ls[4*lane+2], s2); atomicAdd(&ls[4*lane+3], s3);
        atomicAdd(&lq[4*lane+0], q0); atomicAdd(&lq[4*lane+1], q1);
        atomicAdd(&lq[4*lane+2], q2); atomicAdd(&lq[4*lane+3], q3);
    }
    __syncthreads();
    int bkt = (blockIdx.x & (NBUCKET - 1)) * 256;
    if (tid < 16) {
        atomicAdd(&partOut[bkt + tid], ls[tid]);
        atomicAdd(&partOut[bkt + 128 + tid], lq[tid]);
    }
}

// row loader: fp32 float4 or bf16 ushort4 -> float4
template <int D, int BF16>
__device__ __forceinline__ float4 load_row(const void* src, int node, int l4) {
    if (BF16) {
        const unsigned short* sb = (const unsigned short*)src;
        ushort4 r = *(const ushort4*)(sb + (size_t)node * D + (l4 << 2));
        float4 f;
        f.x = bf2f(r.x); f.y = bf2f(r.y); f.z = bf2f(r.z); f.w = bf2f(r.w);
        return f;
    } else {
        const float4* s4 = (const float4*)src;
        return s4[(size_t)node * (D / 4) + l4];
    }
}

// ---------------- fused layer (F2-F4): gather -> LDS rows -> gemm ----------------
template <int DIN, int DOUT, int EP, int POSTAFF, int PREAFF, int RELU,
          int BF16IN, int BF16OUT, int NPB>
__global__ void __launch_bounds__(256) k_fused(
        const void* __restrict__ src, const int* __restrict__ ptr,
        const int2* __restrict__ csr, const float* __restrict__ dis,
        const float* __restrict__ partIn, const float* __restrict__ gmv,
        const float* __restrict__ btv, const float* __restrict__ W,
        const float* __restrict__ bias, float* __restrict__ partOut,
        void* __restrict__ out, int n) {
    const int TPN1 = DIN / 4, LPN = TPN1 * EP, GN1 = 256 / LPN;
    const int TPN2 = DOUT / 4, G2 = 256 / TPN2;
    const int HS = DIN + 4;
    __shared__ float Wl[DIN * DOUT];
    __shared__ float hrow[NPB * HS];
    __shared__ float scs[DIN], shs[DIN];
    __shared__ float ls[DOUT], lq[DOUT];
    int tid = threadIdx.x;
    for (int i = tid; i < DIN * DOUT / 4; i += 256)
        ((float4*)Wl)[i] = ((const float4*)W)[i];
    if (tid < DIN) {
        float s = 0.f, q = 0.f;
#pragma unroll
        for (int b2 = 0; b2 < NBUCKET; ++b2) {
            s += partIn[b2 * 256 + tid];
            q += partIn[b2 * 256 + 128 + tid];
        }
        float mu = s / (float)n;
        float var = q / (float)n - mu * mu;
        float a = gmv[tid] * rsqrtf(var + 1e-5f);
        scs[tid] = a;
        shs[tid] = btv[tid] - mu * a;
    }
    if (tid < DOUT) { ls[tid] = 0.f; lq[tid] = 0.f; }
    __syncthreads();

    int nodebase = blockIdx.x * NPB;
    {
        int grp = tid / LPN, r = tid % LPN;
        int e0 = r / TPN1, l4 = r % TPN1;
        float4 sc = ((const float4*)scs)[l4];
        float4 sh = ((const float4*)shs)[l4];
#pragma unroll
        for (int pass = 0; pass < NPB / GN1; ++pass) {
            int nl = pass * GN1 + grp;
            int node = nodebase + nl;
            int nc = node < n ? node : n - 1;
            float4 acc = {0.f, 0.f, 0.f, 0.f};
            float sumw = 0.f;
            if (e0 == 0) {
                float d = dis[nc];
                float w0 = d * d;
                float4 v = load_row<DIN, BF16IN>(src, nc, l4);
                if (PREAFF) {
                    v.x = fmaxf(sc.x*v.x+sh.x, 0.f); v.y = fmaxf(sc.y*v.y+sh.y, 0.f);
                    v.z = fmaxf(sc.z*v.z+sh.z, 0.f); v.w = fmaxf(sc.w*v.w+sh.w, 0.f);
                }
                acc.x = w0*v.x; acc.y = w0*v.y; acc.z = w0*v.z; acc.w = w0*v.w;
                sumw = w0;
            }
            int p0 = ptr[nc], p1 = ptr[nc + 1];
            int p = p0 + e0;
            for (; p + 3 * EP < p1; p += 4 * EP) {
                int2 c0 = csr[p], c1 = csr[p + EP], c2 = csr[p + 2*EP], c3 = csr[p + 3*EP];
                float e0w = __int_as_float(c0.y), e1w = __int_as_float(c1.y);
                float e2w = __int_as_float(c2.y), e3w = __int_as_float(c3.y);
                float4 u0 = load_row<DIN, BF16IN>(src, c0.x, l4);
                float4 u1 = load_row<DIN, BF16IN>(src, c1.x, l4);
                float4 u2 = load_row<DIN, BF16IN>(src, c2.x, l4);
                float4 u3 = load_row<DIN, BF16IN>(src, c3.x, l4);
                if (PREAFF) {
                    u0.x = fmaxf(sc.x*u0.x+sh.x,0.f); u0.y = fmaxf(sc.y*u0.y+sh.y,0.f);
                    u0.z = fmaxf(sc.z*u0.z+sh.z,0.f); u0.w = fmaxf(sc.w*u0.w+sh.w,0.f);
                    u1.x = fmaxf(sc.x*u1.x+sh.x,0.f); u1.y = fmaxf(sc.y*u1.y+sh.y,0.f);
                    u1.z = fmaxf(sc.z*u1.z+sh.z,0.f); u1.w = fmaxf(sc.w*u1.w+sh.w,0.f);
                    u2.x = fmaxf(sc.x*u2.x+sh.x,0.f); u2.y = fmaxf(sc.y*u2.y+sh.y,0.f);
                    u2.z = fmaxf(sc.z*u2.z+sh.z,0.f); u2.w = fmaxf(sc.w*u2.w+sh.w,0.f);
                    u3.x = fmaxf(sc.x*u3.x+sh.x,0.f); u3.y = fmaxf(sc.y*u3.y+sh.y,0.f);
                    u3.z = fmaxf(sc.z*u3.z+sh.z,0.f); u3.w = fmaxf(sc.w*u3.w+sh.w,0.f);
                }
                acc.x += e0w*u0.x + e1w*u1.x + e2w*u2.x + e3w*u3.x;
                acc.y += e0w*u0.y + e1w*u1.y + e2w*u2.y + e3w*u3.y;
                acc.z += e0w*u0.z + e1w*u1.z + e2w*u2.z + e3w*u3.z;
                acc.w += e0w*u0.w + e1w*u1.w + e2w*u2.w + e3w*u3.w;
                if (POSTAFF) sumw += e0w + e1w + e2w + e3w;
            }
            for (; p < p1; p += EP) {
                int2 ce = csr[p];
                float w = __int_as_float(ce.y);
                float4 u = load_row<DIN, BF16IN>(src, ce.x, l4);
                if (PREAFF) {
                    u.x = fmaxf(sc.x*u.x+sh.x,0.f); u.y = fmaxf(sc.y*u.y+sh.y,0.f);
                    u.z = fmaxf(sc.z*u.z+sh.z,0.f); u.w = fmaxf(sc.w*u.w+sh.w,0.f);
                }
                acc.x += w*u.x; acc.y += w*u.y; acc.z += w*u.z; acc.w += w*u.w;
                if (POSTAFF) sumw += w;
            }
#pragma unroll
            for (int off = TPN1; off < LPN; off <<= 1) {
                acc.x += __shfl_xor(acc.x, off, 64);
                acc.y += __shfl_xor(acc.y, off, 64);
                acc.z += __shfl_xor(acc.z, off, 64);
                acc.w += __shfl_xor(acc.w, off, 64);
                if (POSTAFF) sumw += __shfl_xor(sumw, off, 64);
            }
            if (POSTAFF) {
                acc.x = sc.x * acc.x + sh.x * sumw;
                acc.y = sc.y * acc.y + sh.y * sumw;
                acc.z = sc.z * acc.z + sh.z * sumw;
                acc.w = sc.w * acc.w + sh.w * sumw;
            }
            if (e0 == 0) *(float4*)&hrow[nl * HS + (l4 << 2)] = acc;
        }
    }
    __syncthreads();
    {
        int jq = tid % TPN2, g2 = tid / TPN2;
        float4 bv = ((const float4*)bias)[jq];
        float4 sv = {0,0,0,0}, qv = {0,0,0,0};
        for (int nl = g2; nl < NPB; nl += G2) {
            int node = nodebase + nl;
            bool valid = node < n;
            float4 a = {0.f, 0.f, 0.f, 0.f};
#pragma unroll
            for (int k4 = 0; k4 < DIN / 4; ++k4) {
                float4 hv = *(const float4*)&hrow[nl * HS + (k4 << 2)];
                const float* wb = &Wl[(k4 * 4) * DOUT + jq * 4];
                float4 w0 = *(const float4*)(wb);
                float4 w1 = *(const float4*)(wb + DOUT);
                float4 w2 = *(const float4*)(wb + 2 * DOUT);
                float4 w3 = *(const float4*)(wb + 3 * DOUT);
                a.x += hv.x*w0.x + hv.y*w1.x + hv.z*w2.x + hv.w*w3.x;
                a.y += hv.x*w0.y + hv.y*w1.y + hv.z*w2.y + hv.w*w3.y;
                a.z += hv.x*w0.z + hv.y*w1.z + hv.z*w2.z + hv.w*w3.z;
                a.w += hv.x*w0.w + hv.y*w1.w + hv.z*w2.w + hv.w*w3.w;
            }
            a.x += bv.x; a.y += bv.y; a.z += bv.z; a.w += bv.w;
            if (RELU) {
                a.x = fmaxf(a.x, 0.f); a.y = fmaxf(a.y, 0.f);
                a.z = fmaxf(a.z, 0.f); a.w = fmaxf(a.w, 0.f);
            }
            if (valid) {
                if (BF16OUT) {
                    ushort4 o;
                    o.x = f2bf(a.x); o.y = f2bf(a.y); o.z = f2bf(a.z); o.w = f2bf(a.w);
                    *(ushort4*)((unsigned short*)out + (size_t)node * DOUT + (jq << 2)) = o;
                } else {
                    ((float4*)out)[(size_t)node * TPN2 + jq] = a;
                }
                sv.x += a.x; sv.y += a.y; sv.z += a.z; sv.w += a.w;
                qv.x += a.x*a.x; qv.y += a.y*a.y; qv.z += a.z*a.z; qv.w += a.w*a.w;
            }
        }
        for (int off = TPN2; off < 64; off <<= 1) {
            sv.x += __shfl_down(sv.x, off, 64); sv.y += __shfl_down(sv.y, off, 64);
            sv.z += __shfl_down(sv.z, off, 64); sv.w += __shfl_down(sv.w, off, 64);
            qv.x += __shfl_down(qv.x, off, 64); qv.y += __shfl_down(qv.y, off, 64);
            qv.z += __shfl_down(qv.z, off, 64); qv.w += __shfl_down(qv.w, off, 64);
        }
        int lane = tid & 63;
        if (lane < TPN2) {
            atomicAdd(&ls[4*lane+0], sv.x); atomicAdd(&ls[4*lane+1], sv.y);
            atomicAdd(&ls[4*lane+2], sv.z); atomicAdd(&ls[4*lane+3], sv.w);
            atomicAdd(&lq[4*lane+0], qv.x); atomicAdd(&lq[4*lane+1], qv.y);
            atomicAdd(&lq[4*lane+2], qv.z); atomicAdd(&lq[4*lane+3], qv.w);
        }
        __syncthreads();
        int bkt = (blockIdx.x & (NBUCKET - 1)) * 256;
        if (tid < DOUT) {
            atomicAdd(&partOut[bkt + tid], ls[tid]);
            atomicAdd(&partOut[bkt + 128 + tid], lq[tid]);
        }
    }
}

// ---------------- standalone F5 gather: d=64, EP=4, PREAFF (relu(BN4)), bf16-in, fp32-out ----
__global__ void k_gather5(const unsigned short* __restrict__ src, const int* __restrict__ ptr,
                          const int2* __restrict__ csr, const float* __restrict__ dis,
                          const float* __restrict__ partIn, const float* __restrict__ gmv,
                          const float* __restrict__ btv, float* __restrict__ out, int n) {
    const int TPN = 16, EP = 4, LPN = 64;
    __shared__ float scs[64], shs[64];
    int tid = threadIdx.x;
    if (tid < 64) {
        float s = 0.f, q = 0.f;
#pragma unroll
        for (int b2 = 0; b2 < NBUCKET; ++b2) {
            s += partIn[b2 * 256 + tid];
            q += partIn[b2 * 256 + 128 + tid];
        }
        float mu = s / (float)n;
        float var = q / (float)n - mu * mu;
        float a = gmv[tid] * rsqrtf(var + 1e-5f);
        scs[tid] = a;
        shs[tid] = btv[tid] - mu * a;
    }
    __syncthreads();
    int t = blockIdx.x * 256 + tid;
    int node = t / LPN;
    int r = t - node * LPN;
    int e0 = r / TPN;
    int l4 = r - e0 * TPN;
    bool valid = node < n;
    int nc = valid ? node : n - 1;
    float4 sc = ((const float4*)scs)[l4];
    float4 sh = ((const float4*)shs)[l4];
    float4 acc = {0.f, 0.f, 0.f, 0.f};
    if (e0 == 0) {
        float d = dis[nc];
        float w0 = d * d;
        float4 v = load_row<64, 1>(src, nc, l4);
        v.x = fmaxf(sc.x*v.x+sh.x, 0.f); v.y = fmaxf(sc.y*v.y+sh.y, 0.f);
        v.z = fmaxf(sc.z*v.z+sh.z, 0.f); v.w = fmaxf(sc.w*v.w+sh.w, 0.f);
        acc.x = w0*v.x; acc.y = w0*v.y; acc.z = w0*v.z; acc.w = w0*v.w;
    }
    int p0 = ptr[nc], p1 = ptr[nc + 1];
    int p = p0 + e0;
    for (; p + 3 * EP < p1; p += 4 * EP) {
        int2 c0 = csr[p], c1 = csr[p + EP], c2 = csr[p + 2*EP], c3 = csr[p + 3*EP];
        float e0w = __int_as_float(c0.y), e1w = __int_as_float(c1.y);
        float e2w = __int_as_float(c2.y), e3w = __int_as_float(c3.y);
        float4 u0 = load_row<64, 1>(src, c0.x, l4);
        float4 u1 = load_row<64, 1>(src, c1.x, l4);
        float4 u2 = load_row<64, 1>(src, c2.x, l4);
        float4 u3 = load_row<64, 1>(src, c3.x, l4);
        u0.x = fmaxf(sc.x*u0.x+sh.x,0.f); u0.y = fmaxf(sc.y*u0.y+sh.y,0.f);
        u0.z = fmaxf(sc.z*u0.z+sh.z,0.f); u0.w = fmaxf(sc.w*u0.w+sh.w,0.f);
        u1.x = fmaxf(sc.x*u1.x+sh.x,0.f); u1.y = fmaxf(sc.y*u1.y+sh.y,0.f);
        u1.z = fmaxf(sc.z*u1.z+sh.z,0.f); u1.w = fmaxf(sc.w*u1.w+sh.w,0.f);
        u2.x = fmaxf(sc.x*u2.x+sh.x,0.f); u2.y = fmaxf(sc.y*u2.y+sh.y,0.f);
        u2.z = fmaxf(sc.z*u2.z+sh.z,0.f); u2.w = fmaxf(sc.w*u2.w+sh.w,0.f);
        u3.x = fmaxf(sc.x*u3.x+sh.x,0.f); u3.y = fmaxf(sc.y*u3.y+sh.y,0.f);
        u3.z = fmaxf(sc.z*u3.z+sh.z,0.f); u3.w = fmaxf(sc.w*u3.w+sh.w,0.f);
        acc.x += e0w*u0.x + e1w*u1.x + e2w*u2.x + e3w*u3.x;
        acc.y += e0w*u0.y + e1w*u1.y + e2w*u2.y + e3w*u3.y;
        acc.z += e0w*u0.z + e1w*u1.z + e2w*u2.z + e3w*u3.z;
        acc.w += e0w*u0.w + e1w*u1.w + e2w*u2.w + e3w*u3.w;
    }
    for (; p < p1; p += EP) {
        int2 ce = csr[p];
        float w = __int_as_float(ce.y);
        float4 u = load_row<64, 1>(src, ce.x, l4);
        u.x = fmaxf(sc.x*u.x+sh.x,0.f); u.y = fmaxf(sc.y*u.y+sh.y,0.f);
        u.z = fmaxf(sc.z*u.z+sh.z,0.f); u.w = fmaxf(sc.w*u.w+sh.w,0.f);
        acc.x += w*u.x; acc.y += w*u.y; acc.z += w*u.z; acc.w += w*u.w;
    }
#pragma unroll
    for (int off = TPN; off < LPN; off <<= 1) {
        acc.x += __shfl_xor(acc.x, off, 64);
        acc.y += __shfl_xor(acc.y, off, 64);
        acc.z += __shfl_xor(acc.z, off, 64);
        acc.w += __shfl_xor(acc.w, off, 64);
    }
    if (valid && e0 == 0) ((float4*)out)[nc * TPN + l4] = acc;
}

// ---------------- standalone F5 gemm: 64->128, bias + stats -> part[4] ----------------
__global__ void k_gemm5(const float* __restrict__ h, const float* __restrict__ W,
                        const float* __restrict__ bias, float* __restrict__ partOut,
                        float* __restrict__ m, int n) {
    const int TPN = 32, GPB = 8, NPT = 4;
    __shared__ float Wl[64 * 128];
    __shared__ float ls[128], lq[128];
    int tid = threadIdx.x;
    for (int i = tid; i < 64 * 128 / 4; i += 256)
        ((float4*)Wl)[i] = ((const float4*)W)[i];
    if (tid < 128) { ls[tid] = 0.f; lq[tid] = 0.f; }
    __syncthreads();

    int jq = tid % TPN;
    int group = tid / TPN;
    int node0 = (blockIdx.x * GPB + group) * NPT;
    const float4* h4 = (const float4*)h;
    int hb[NPT]; bool val[NPT];
#pragma unroll
    for (int i = 0; i < NPT; ++i) {
        int nd = node0 + i;
        val[i] = nd < n;
        hb[i] = (val[i] ? nd : n - 1) * 16;
    }
    float4 acc[NPT];
#pragma unroll
    for (int i = 0; i < NPT; ++i) acc[i] = {0.f, 0.f, 0.f, 0.f};
#pragma unroll 4
    for (int k4 = 0; k4 < 16; ++k4) {
        const float* wb = &Wl[(k4 * 4) * 128 + jq * 4];
        float4 w0 = *(const float4*)(wb);
        float4 w1 = *(const float4*)(wb + 128);
        float4 w2 = *(const float4*)(wb + 256);
        float4 w3 = *(const float4*)(wb + 384);
#pragma unroll
        for (int i = 0; i < NPT; ++i) {
            float4 hv = h4[hb[i] + k4];
            acc[i].x += hv.x*w0.x + hv.y*w1.x + hv.z*w2.x + hv.w*w3.x;
            acc[i].y += hv.x*w0.y + hv.y*w1.y + hv.z*w2.y + hv.w*w3.y;
            acc[i].z += hv.x*w0.z + hv.y*w1.z + hv.z*w2.z + hv.w*w3.z;
            acc[i].w += hv.x*w0.w + hv.y*w1.w + hv.z*w2.w + hv.w*w3.w;
        }
    }
    float4 bv = ((const float4*)bias)[jq];
    float4 sv = {0,0,0,0}, qv = {0,0,0,0};
#pragma unroll
    for (int i = 0; i < NPT; ++i) {
        float4 a = acc[i];
        a.x += bv.x; a.y += bv.y; a.z += bv.z; a.w += bv.w;
        if (val[i]) {
            ((float4*)m)[(size_t)(node0 + i) * TPN + jq] = a;
            sv.x += a.x; sv.y += a.y; sv.z += a.z; sv.w += a.w;
            qv.x += a.x*a.x; qv.y += a.y*a.y; qv.z += a.z*a.z; qv.w += a.w*a.w;
        }
    }
    for (int off = TPN; off < 64; off <<= 1) {
        sv.x += __shfl_down(sv.x, off, 64); sv.y += __shfl_down(sv.y, off, 64);
        sv.z += __shfl_down(sv.z, off, 64); sv.w += __shfl_down(sv.w, off, 64);
        qv.x += __shfl_down(qv.x, off, 64); qv.y += __shfl_down(qv.y, off, 64);
        qv.z += __shfl_down(qv.z, off, 64); qv.w += __shfl_down(qv.w, off, 64);
    }
    int lane = tid & 63;
    if (lane < TPN) {
        atomicAdd(&ls[4*lane+0], sv.x); atomicAdd(&ls[4*lane+1], sv.y);
        atomicAdd(&ls[4*lane+2], sv.z); atomicAdd(&ls[4*lane+3], sv.w);
        atomicAdd(&lq[4*lane+0], qv.x); atomicAdd(&lq[4*lane+1], qv.y);
        atomicAdd(&lq[4*lane+2], qv.z); atomicAdd(&lq[4*lane+3], qv.w);
    }
    __syncthreads();
    int bkt = (blockIdx.x & (NBUCKET - 1)) * 256;
    if (tid < 128) {
        atomicAdd(&partOut[bkt + tid], ls[tid]);
        atomicAdd(&partOut[bkt + 128 + tid], lq[tid]);
    }
}

// ---------------- fused pool (BN5 consumed inline) + MLP head ----------------
__global__ void k_poolhead(const float* __restrict__ h, const int* __restrict__ batch,
                           const float* __restrict__ partIn, const float* __restrict__ gmv,
                           const float* __restrict__ btv,
                           const float* __restrict__ fc1w, const float* __restrict__ fc1b,
                           const float* __restrict__ fc2w, const float* __restrict__ fc2b,
                           float* __restrict__ out, int n) {
    __shared__ float tmp[256];
    __shared__ float pl[128];
    __shared__ float scs[128], shs[128];
    int g = blockIdx.x;
    int tid = threadIdx.x;
    if (tid < 128) {
        float s = 0.f, q = 0.f;
#pragma unroll
        for (int b2 = 0; b2 < NBUCKET; ++b2) {
            s += partIn[b2 * 256 + tid];
            q += partIn[b2 * 256 + 128 + tid];
        }
        float mu = s / (float)n;
        float var = q / (float)n - mu * mu;
        float a = gmv[tid] * rsqrtf(var + 1e-5f);
        scs[tid] = a;
        shs[tid] = btv[tid] - mu * a;
    }
    int j = tid & 127, prt = tid >> 7;
    int a = 0, b = n;
    while (a < b) { int mid = (a + b) >> 1; if (batch[mid] < g) a = mid + 1; else b = mid; }
    int lo = a;
    b = n;
    while (a < b) { int mid = (a + b) >> 1; if (batch[mid] < g + 1) a = mid + 1; else b = mid; }
    int hi = a;

    float acc = 0.f;
    for (int node = lo + prt; node < hi; node += 2) acc += h[(long)node * 128 + j];
    tmp[tid] = acc;
    __syncthreads();
    if (tid < 128) {
        float cnt = (float)(hi - lo);
        float p = scs[tid] * (tmp[tid] + tmp[tid + 128]) + shs[tid] * cnt;
        pl[tid] = fmaxf(p, 0.f);
    }
    __syncthreads();
    if (tid < 64) {
        float v1 = fc1b[tid];
        for (int k = 0; k < 128; ++k) v1 += pl[k] * fc1w[k * 64 + tid];
        v1 = fmaxf(v1, 0.f);
        float v = v1 * fc2w[tid];
        for (int off = 32; off > 0; off >>= 1) v += __shfl_down(v, off, 64);
        if (tid == 0) out[g] = v + fc2b[0];
    }
}

// ---------------- driver ----------------
extern "C" void kernel_launch(void* const* d_in, const int* in_sizes, int n_in,
                              void* d_out, int out_size, void* d_ws, size_t ws_size,
                              hipStream_t stream) {
    const float* x     = (const float*)d_in[0];
    const int*   ei    = (const int*)d_in[1];
    const float* ew    = (const float*)d_in[2];
    const int*   batch = (const int*)d_in[3];
    const float *W[5], *b[5], *gm[5], *bt[5];
    for (int i = 0; i < 5; ++i) {
        W[i]  = (const float*)d_in[4 + 4 * i];
        b[i]  = (const float*)d_in[5 + 4 * i];
        gm[i] = (const float*)d_in[6 + 4 * i];
        bt[i] = (const float*)d_in[7 + 4 * i];
    }
    const float* fc1w = (const float*)d_in[24];
    const float* fc1b = (const float*)d_in[25];
    const float* fc2w = (const float*)d_in[26];
    const float* fc2b = (const float*)d_in[27];
    float* out = (float*)d_out;

    // workspace layout
    char* wsb = (char*)d_ws;
    float* dis    = (float*)wsb;  wsb += sizeof(float) * NN;
    int*   ptr    = (int*)wsb;    wsb += sizeof(int) * (NN + 4);
    int*   bb     = (int*)wsb;    wsb += sizeof(int) * ABLK * NBKT;
    int*   totals = (int*)wsb;    wsb += sizeof(int) * (NBKT + 1);
    int*   bbase  = (int*)wsb;    wsb += sizeof(int) * (NBKT + 3);
    wsb = (char*)(((uintptr_t)wsb + 15) & ~(uintptr_t)15);
    int2*  staging= (int2*)wsb;   wsb += sizeof(int2) * NE;
    int2*  csr    = (int2*)wsb;   wsb += sizeof(int2) * NE;
    float* part   = (float*)wsb;  wsb += sizeof(float) * 5 * PARTSZ;
    unsigned short* bufB1 = (unsigned short*)wsb;  wsb += sizeof(unsigned short) * (size_t)NN * 64;
    unsigned short* bufB2 = (unsigned short*)wsb;  wsb += sizeof(unsigned short) * (size_t)NN * 64;
    float* buf1   = (float*)wsb;  wsb += sizeof(float) * (size_t)NN * 64;   // L1 m (NN*16) / F5 agg (NN*64)
    float* buf2   = (float*)wsb;  wsb += sizeof(float) * (size_t)NN * 128;

    const int* row = ei;
    const int* col = ei + NE;
    const int B = 256;
    const int NBF = (NN + 15) / 16;   // 3125 fused-layer blocks

    // prologue: bucketed CSR build (k_init folded into kA1)
    kA1<<<ABLK, B, 0, stream>>>(col, bb, part, NE);
    kA2a<<<NBKT, B, 0, stream>>>(bb, totals);
    kA2b<<<1, B, 0, stream>>>(totals, bbase);
    kA3<<<ABLK, B, 0, stream>>>(row, col, ew, bb, bbase, staging, NE);
    kB<<<NBKT, B, 0, stream>>>(bbase, staging, csr, ptr, dis, NN);

    // L1: dense 128->16, then gather+bias+relu+stats (+ CSR rescale write-back)
    k_gemm1<<<(NN + 127) / 128, B, 0, stream>>>(x, W[0], buf1, NN);
    k_l1gather<<<(NN * 4 + 255) / 256, B, 0, stream>>>(buf1, ptr, csr, dis,
                                                       b[0], part + 0 * PARTSZ, buf2, NN);

    // F2: 16->32 fused, consume part[0], fp32 in, bf16 out
    k_fused<16, 32, 4, 1, 0, 1, 0, 1, 16><<<NBF, B, 0, stream>>>(
        buf2, ptr, csr, dis, part + 0 * PARTSZ, gm[0], bt[0],
        W[1], b[1], part + 1 * PARTSZ, bufB1, NN);
    // F3: 32->64 fused, consume part[1], bf16 in/out
    k_fused<32, 64, 4, 1, 0, 1, 1, 1, 16><<<NBF, B, 0, stream>>>(
        bufB1, ptr, csr, dis, part + 1 * PARTSZ, gm[1], bt[1],
        W[2], b[2], part + 2 * PARTSZ, bufB2, NN);
    // F4: 64->64 fused, consume part[2], bf16 in/out, no relu (relu in F5's PREAFF)
    k_fused<64, 64, 4, 1, 0, 0, 1, 1, 16><<<NBF, B, 0, stream>>>(
        bufB2, ptr, csr, dis, part + 2 * PARTSZ, gm[2], bt[2],
        W[3], b[3], part + 3 * PARTSZ, bufB1, NN);

    // F5 UNFUSED (84us fused: 32KB Wl -> 35% occupancy): gather then gemm
    k_gather5<<<(int)(((long)NN * 64 + 255) / 256), B, 0, stream>>>(
        bufB1, ptr, csr, dis, part + 3 * PARTSZ, gm[3], bt[3], buf1, NN);
    k_gemm5<<<(NN + 31) / 32, B, 0, stream>>>(buf1, W[4], b[4], part + 4 * PARTSZ, buf2, NN);

    // fused pool (consume part[4] -> BN5) + head
    k_poolhead<<<NG, B, 0, stream>>>(buf2, batch, part + 4 * PARTSZ, gm[4], bt[4],
                                     fc1w, fc1b, fc2w, fc2b, out, NN);
}

// Round 14
// 406.784 us; speedup vs baseline: 1.1448x; 1.0189x over previous
//
#include <hip/hip_runtime.h>
#include <stdint.h>

#define NN 50000
#define NE 800000
#define NG 256
#define NBUCKET 16
#define PARTSZ (NBUCKET * 256)

// bucketed CSR build params
#define NBKT 391      // node buckets of 128
#define ABLK 391
#define ASLICE 2048
#define BCAP 2560

__device__ __forceinline__ float bf2f(unsigned short u) {
    return __uint_as_float(((unsigned)u) << 16);
}
__device__ __forceinline__ unsigned short f2bf(float f) {
    unsigned b = __float_as_uint(f);
    return (unsigned short)((b + 0x7FFF + ((b >> 16) & 1)) >> 16);  // RNE
}

// ---------------- prologue ----------------
// A1: per-(block,bucket) edge counts via LDS histogram; also zeroes part (folded k_init)
__global__ void kA1(const int* __restrict__ col, int* __restrict__ bb, float* part, int e) {
    __shared__ int cnt[NBKT];
    for (int j = threadIdx.x; j < NBKT; j += 256) cnt[j] = 0;
    for (int i = blockIdx.x * 256 + threadIdx.x; i < 5 * PARTSZ; i += ABLK * 256) part[i] = 0.f;
    __syncthreads();
    int start = blockIdx.x * ASLICE;
    int end = min(start + ASLICE, e);
    for (int i = start + threadIdx.x; i < end; i += 256)
        atomicAdd(&cnt[col[i] >> 7], 1);
    __syncthreads();
    for (int j = threadIdx.x; j < NBKT; j += 256) bb[blockIdx.x * NBKT + j] = cnt[j];
}

__global__ void kA2a(int* __restrict__ bb, int* __restrict__ totals) {
    __shared__ int v[ABLK];
    int k = blockIdx.x;
    for (int b = threadIdx.x; b < ABLK; b += 256) v[b] = bb[b * NBKT + k];
    __syncthreads();
    if (threadIdx.x == 0) {
        int run = 0;
        for (int b = 0; b < ABLK; ++b) { int t = v[b]; v[b] = run; run += t; }
        totals[k] = run;
    }
    __syncthreads();
    for (int b = threadIdx.x; b < ABLK; b += 256) bb[b * NBKT + k] = v[b];
}

__global__ void kA2b(const int* __restrict__ totals, int* __restrict__ bucketbase) {
    __shared__ int v[NBKT];
    for (int j = threadIdx.x; j < NBKT; j += 256) v[j] = totals[j];
    __syncthreads();
    if (threadIdx.x == 0) {
        int run = 0;
        for (int k = 0; k < NBKT; ++k) { int t = v[k]; v[k] = run; run += t; }
        bucketbase[NBKT] = run;
    }
    __syncthreads();
    for (int j = threadIdx.x; j < NBKT; j += 256) bucketbase[j] = v[j];
}

// A3 (blocks [0,ABLK)) + independent L1 gemm 128->16 (blocks [ABLK, ABLK+391)) in one dispatch
__global__ void kA3g(const int* __restrict__ row, const int* __restrict__ col,
                     const float* __restrict__ ew, const int* __restrict__ bb,
                     const int* __restrict__ bucketbase, int2* __restrict__ staging,
                     const float* __restrict__ x, const float* __restrict__ W0,
                     float* __restrict__ m1, int e, int n) {
    __shared__ int cur[NBKT];
    __shared__ float Wl[128 * 16];
    int tid = threadIdx.x;
    if ((int)blockIdx.x < ABLK) {
        for (int j = tid; j < NBKT; j += 256)
            cur[j] = bucketbase[j] + bb[blockIdx.x * NBKT + j];
        __syncthreads();
        int start = blockIdx.x * ASLICE;
        int end = min(start + ASLICE, e);
        for (int i = start + tid; i < end; i += 256) {
            int c = col[i];
            int p = atomicAdd(&cur[c >> 7], 1);
            staging[p] = make_int2(row[i] | ((c & 127) << 16), __float_as_int(ew[i]));
        }
        return;
    }
    // ---- gemm1 body ----
    int bid = (int)blockIdx.x - ABLK;
    for (int i = tid; i < 128 * 16 / 4; i += 256)
        ((float4*)Wl)[i] = ((const float4*)W0)[i];
    __syncthreads();
    int jq = tid % 4, group = tid / 4;
    int node0 = (bid * 64 + group) * 2;
    const float4* h4 = (const float4*)x;
    int hb[2]; bool val[2];
#pragma unroll
    for (int i = 0; i < 2; ++i) {
        int nd = node0 + i;
        val[i] = nd < n;
        hb[i] = (val[i] ? nd : n - 1) * 32;
    }
    float4 acc[2];
    acc[0] = {0,0,0,0}; acc[1] = {0,0,0,0};
#pragma unroll 4
    for (int k4 = 0; k4 < 32; ++k4) {
        const float* wb = &Wl[(k4 * 4) * 16 + jq * 4];
        float4 w0 = *(const float4*)(wb);
        float4 w1 = *(const float4*)(wb + 16);
        float4 w2 = *(const float4*)(wb + 32);
        float4 w3 = *(const float4*)(wb + 48);
#pragma unroll
        for (int i = 0; i < 2; ++i) {
            float4 hv = h4[hb[i] + k4];
            acc[i].x += hv.x*w0.x + hv.y*w1.x + hv.z*w2.x + hv.w*w3.x;
            acc[i].y += hv.x*w0.y + hv.y*w1.y + hv.z*w2.y + hv.w*w3.y;
            acc[i].z += hv.x*w0.z + hv.y*w1.z + hv.z*w2.z + hv.w*w3.z;
            acc[i].w += hv.x*w0.w + hv.y*w1.w + hv.z*w2.w + hv.w*w3.w;
        }
    }
#pragma unroll
    for (int i = 0; i < 2; ++i)
        if (val[i]) ((float4*)m1)[(node0 + i) * 4 + jq] = acc[i];
}

__global__ void __launch_bounds__(256) kB(const int* __restrict__ bucketbase,
                                          const int2* __restrict__ staging,
                                          int2* __restrict__ csr, int* __restrict__ ptr,
                                          float* __restrict__ dis, int n) {
    __shared__ int2 st[BCAP];
    __shared__ int2 outb[BCAP];
    __shared__ int hist[129];
    __shared__ int cur[128];
    int k = blockIdx.x, t = threadIdx.x;
    int base = bucketbase[k], cnt = bucketbase[k + 1] - base;
    int node0 = k << 7;
    int ncov = min(128, n - node0);
    if (t < 129) hist[t] = 0;
    __syncthreads();
    if (cnt <= BCAP) {
        for (int i = t; i < cnt; i += 256) {
            int2 v = staging[base + i];
            st[i] = v;
            atomicAdd(&hist[v.x >> 16], 1);
        }
        __syncthreads();
        if (t == 0) {
            int run = 0;
            for (int j = 0; j < 128; ++j) { int h = hist[j]; hist[j] = run; run += h; }
            hist[128] = run;
        }
        __syncthreads();
        if (t < 128) cur[t] = hist[t];
        if (t < ncov) ptr[node0 + t] = base + hist[t];
        __syncthreads();
        for (int i = t; i < cnt; i += 256) {
            int2 v = st[i];
            int j = v.x >> 16;
            int p = atomicAdd(&cur[j], 1);
            outb[p] = make_int2(v.x & 0xFFFF, v.y);
        }
        __syncthreads();
        for (int i = t; i < cnt; i += 256) csr[base + i] = outb[i];
        if (t < ncov) {
            float s = 1.f;
            int a = hist[t], b2 = hist[t + 1];
            for (int p = a; p < b2; ++p) s += __int_as_float(outb[p].y);
            dis[node0 + t] = rsqrtf(s);
        }
    } else {
        for (int i = t; i < cnt; i += 256) atomicAdd(&hist[staging[base + i].x >> 16], 1);
        __syncthreads();
        if (t == 0) {
            int run = 0;
            for (int j = 0; j < 128; ++j) { int h = hist[j]; hist[j] = run; run += h; }
            hist[128] = run;
        }
        __syncthreads();
        if (t < 128) cur[t] = hist[t];
        if (t < ncov) ptr[node0 + t] = base + hist[t];
        __syncthreads();
        for (int i = t; i < cnt; i += 256) {
            int2 v = staging[base + i];
            int j = v.x >> 16;
            int p = atomicAdd(&cur[j], 1);
            csr[base + p] = make_int2(v.x & 0xFFFF, v.y);
        }
        __threadfence_block();
        __syncthreads();
        if (t < ncov) {
            float s = 1.f;
            int a = hist[t], b2 = hist[t + 1];
            for (int p = a; p < b2; ++p) s += __int_as_float(csr[base + p].y);
            dis[node0 + t] = rsqrtf(s);
        }
    }
    if (k == gridDim.x - 1 && t == 0) ptr[n] = bucketbase[NBKT];
}

// ---------------- L1 gather: EPI (bias+relu+stats) + CSR rescale write-back ----------------
__global__ void k_l1gather(const float* __restrict__ src, const int* __restrict__ ptr,
                           int2* __restrict__ csr, const float* __restrict__ dis,
                           const float* __restrict__ bias, float* __restrict__ partOut,
                           float* __restrict__ out, int n) {
    __shared__ float ls[16], lq[16];
    int tid = threadIdx.x;
    if (tid < 16) { ls[tid] = 0.f; lq[tid] = 0.f; }
    __syncthreads();
    int t = blockIdx.x * 256 + tid;
    int node = t >> 2;
    int l4 = t & 3;
    bool valid = node < n;
    int nc = valid ? node : n - 1;
    const float4* s4 = (const float4*)src;
    float dc = dis[nc];
    float w0 = dc * dc;
    float4 v = s4[nc * 4 + l4];
    float4 acc = { w0 * v.x, w0 * v.y, w0 * v.z, w0 * v.w };
    int p0 = ptr[nc], p1 = ptr[nc + 1];
    int p = p0;
    for (; p + 4 <= p1; p += 4) {
        int2 c0 = csr[p], c1 = csr[p+1], c2 = csr[p+2], c3 = csr[p+3];
        float e0 = dis[c0.x] * __int_as_float(c0.y) * dc;
        float e1 = dis[c1.x] * __int_as_float(c1.y) * dc;
        float e2 = dis[c2.x] * __int_as_float(c2.y) * dc;
        float e3 = dis[c3.x] * __int_as_float(c3.y) * dc;
        float4 u0 = s4[c0.x * 4 + l4];
        float4 u1 = s4[c1.x * 4 + l4];
        float4 u2 = s4[c2.x * 4 + l4];
        float4 u3 = s4[c3.x * 4 + l4];
        acc.x += e0*u0.x + e1*u1.x + e2*u2.x + e3*u3.x;
        acc.y += e0*u0.y + e1*u1.y + e2*u2.y + e3*u3.y;
        acc.z += e0*u0.z + e1*u1.z + e2*u2.z + e3*u3.z;
        acc.w += e0*u0.w + e1*u1.w + e2*u2.w + e3*u3.w;
        if (l4 == 0) {
            csr[p]   = make_int2(c0.x, __float_as_int(e0));
            csr[p+1] = make_int2(c1.x, __float_as_int(e1));
            csr[p+2] = make_int2(c2.x, __float_as_int(e2));
            csr[p+3] = make_int2(c3.x, __float_as_int(e3));
        }
    }
    for (; p < p1; ++p) {
        int2 ce = csr[p];
        float w = dis[ce.x] * __int_as_float(ce.y) * dc;
        float4 u = s4[ce.x * 4 + l4];
        acc.x += w*u.x; acc.y += w*u.y; acc.z += w*u.z; acc.w += w*u.w;
        if (l4 == 0) csr[p] = make_int2(ce.x, __float_as_int(w));
    }
    float4 b = ((const float4*)bias)[l4];
    acc.x = fmaxf(acc.x + b.x, 0.f);
    acc.y = fmaxf(acc.y + b.y, 0.f);
    acc.z = fmaxf(acc.z + b.z, 0.f);
    acc.w = fmaxf(acc.w + b.w, 0.f);
    if (valid) ((float4*)out)[nc * 4 + l4] = acc;
    float s0 = valid ? acc.x : 0.f, s1 = valid ? acc.y : 0.f;
    float s2 = valid ? acc.z : 0.f, s3 = valid ? acc.w : 0.f;
    float q0 = s0*s0, q1 = s1*s1, q2 = s2*s2, q3 = s3*s3;
    for (int off = 4; off < 64; off <<= 1) {
        s0 += __shfl_down(s0, off, 64); s1 += __shfl_down(s1, off, 64);
        s2 += __shfl_down(s2, off, 64); s3 += __shfl_down(s3, off, 64);
        q0 += __shfl_down(q0, off, 64); q1 += __shfl_down(q1, off, 64);
        q2 += __shfl_down(q2, off, 64); q3 += __shfl_down(q3, off, 64);
    }
    int lane = tid & 63;
    if (lane < 4) {
        atomicAdd(&ls[4*lane+0], s0); atomicAdd(&ls[4*lane+1], s1);
        atomicAdd(&ls[4*lane+2], s2); atomicAdd(&ls[4*lane+3], s3);
        atomicAdd(&lq[4*lane+0], q0); atomicAdd(&lq[4*lane+1], q1);
        atomicAdd(&lq[4*lane+2], q2); atomicAdd(&lq[4*lane+3], q3);
    }
    __syncthreads();
    int bkt = (blockIdx.x & (NBUCKET - 1)) * 256;
    if (tid < 16) {
        atomicAdd(&partOut[bkt + tid], ls[tid]);
        atomicAdd(&partOut[bkt + 128 + tid], lq[tid]);
    }
}

// row loader: fp32 float4 or bf16 ushort4 -> float4
template <int D, int BF16>
__device__ __forceinline__ float4 load_row(const void* src, int node, int l4) {
    if (BF16) {
        const unsigned short* sb = (const unsigned short*)src;
        ushort4 r = *(const ushort4*)(sb + (size_t)node * D + (l4 << 2));
        float4 f;
        f.x = bf2f(r.x); f.y = bf2f(r.y); f.z = bf2f(r.z); f.w = bf2f(r.w);
        return f;
    } else {
        const float4* s4 = (const float4*)src;
        return s4[(size_t)node * (D / 4) + l4];
    }
}

// ---------------- fused layer (F2/F3 only — small Wl): gather -> LDS rows -> gemm ----------
template <int DIN, int DOUT, int EP, int POSTAFF, int PREAFF, int RELU,
          int BF16IN, int BF16OUT, int NPB>
__global__ void __launch_bounds__(256) k_fused(
        const void* __restrict__ src, const int* __restrict__ ptr,
        const int2* __restrict__ csr, const float* __restrict__ dis,
        const float* __restrict__ partIn, const float* __restrict__ gmv,
        const float* __restrict__ btv, const float* __restrict__ W,
        const float* __restrict__ bias, float* __restrict__ partOut,
        void* __restrict__ out, int n) {
    const int TPN1 = DIN / 4, LPN = TPN1 * EP, GN1 = 256 / LPN;
    const int TPN2 = DOUT / 4, G2 = 256 / TPN2;
    const int HS = DIN + 4;
    __shared__ float Wl[DIN * DOUT];
    __shared__ float hrow[NPB * HS];
    __shared__ float scs[DIN], shs[DIN];
    __shared__ float ls[DOUT], lq[DOUT];
    int tid = threadIdx.x;
    for (int i = tid; i < DIN * DOUT / 4; i += 256)
        ((float4*)Wl)[i] = ((const float4*)W)[i];
    if (tid < DIN) {
        float s = 0.f, q = 0.f;
#pragma unroll
        for (int b2 = 0; b2 < NBUCKET; ++b2) {
            s += partIn[b2 * 256 + tid];
            q += partIn[b2 * 256 + 128 + tid];
        }
        float mu = s / (float)n;
        float var = q / (float)n - mu * mu;
        float a = gmv[tid] * rsqrtf(var + 1e-5f);
        scs[tid] = a;
        shs[tid] = btv[tid] - mu * a;
    }
    if (tid < DOUT) { ls[tid] = 0.f; lq[tid] = 0.f; }
    __syncthreads();

    int nodebase = blockIdx.x * NPB;
    {
        int grp = tid / LPN, r = tid % LPN;
        int e0 = r / TPN1, l4 = r % TPN1;
        float4 sc = ((const float4*)scs)[l4];
        float4 sh = ((const float4*)shs)[l4];
#pragma unroll
        for (int pass = 0; pass < NPB / GN1; ++pass) {
            int nl = pass * GN1 + grp;
            int node = nodebase + nl;
            int nc = node < n ? node : n - 1;
            float4 acc = {0.f, 0.f, 0.f, 0.f};
            float sumw = 0.f;
            if (e0 == 0) {
                float d = dis[nc];
                float w0 = d * d;
                float4 v = load_row<DIN, BF16IN>(src, nc, l4);
                if (PREAFF) {
                    v.x = fmaxf(sc.x*v.x+sh.x, 0.f); v.y = fmaxf(sc.y*v.y+sh.y, 0.f);
                    v.z = fmaxf(sc.z*v.z+sh.z, 0.f); v.w = fmaxf(sc.w*v.w+sh.w, 0.f);
                }
                acc.x = w0*v.x; acc.y = w0*v.y; acc.z = w0*v.z; acc.w = w0*v.w;
                sumw = w0;
            }
            int p0 = ptr[nc], p1 = ptr[nc + 1];
            int p = p0 + e0;
            for (; p + 3 * EP < p1; p += 4 * EP) {
                int2 c0 = csr[p], c1 = csr[p + EP], c2 = csr[p + 2*EP], c3 = csr[p + 3*EP];
                float e0w = __int_as_float(c0.y), e1w = __int_as_float(c1.y);
                float e2w = __int_as_float(c2.y), e3w = __int_as_float(c3.y);
                float4 u0 = load_row<DIN, BF16IN>(src, c0.x, l4);
                float4 u1 = load_row<DIN, BF16IN>(src, c1.x, l4);
                float4 u2 = load_row<DIN, BF16IN>(src, c2.x, l4);
                float4 u3 = load_row<DIN, BF16IN>(src, c3.x, l4);
                if (PREAFF) {
                    u0.x = fmaxf(sc.x*u0.x+sh.x,0.f); u0.y = fmaxf(sc.y*u0.y+sh.y,0.f);
                    u0.z = fmaxf(sc.z*u0.z+sh.z,0.f); u0.w = fmaxf(sc.w*u0.w+sh.w,0.f);
                    u1.x = fmaxf(sc.x*u1.x+sh.x,0.f); u1.y = fmaxf(sc.y*u1.y+sh.y,0.f);
                    u1.z = fmaxf(sc.z*u1.z+sh.z,0.f); u1.w = fmaxf(sc.w*u1.w+sh.w,0.f);
                    u2.x = fmaxf(sc.x*u2.x+sh.x,0.f); u2.y = fmaxf(sc.y*u2.y+sh.y,0.f);
                    u2.z = fmaxf(sc.z*u2.z+sh.z,0.f); u2.w = fmaxf(sc.w*u2.w+sh.w,0.f);
                    u3.x = fmaxf(sc.x*u3.x+sh.x,0.f); u3.y = fmaxf(sc.y*u3.y+sh.y,0.f);
                    u3.z = fmaxf(sc.z*u3.z+sh.z,0.f); u3.w = fmaxf(sc.w*u3.w+sh.w,0.f);
                }
                acc.x += e0w*u0.x + e1w*u1.x + e2w*u2.x + e3w*u3.x;
                acc.y += e0w*u0.y + e1w*u1.y + e2w*u2.y + e3w*u3.y;
                acc.z += e0w*u0.z + e1w*u1.z + e2w*u2.z + e3w*u3.z;
                acc.w += e0w*u0.w + e1w*u1.w + e2w*u2.w + e3w*u3.w;
                if (POSTAFF) sumw += e0w + e1w + e2w + e3w;
            }
            for (; p < p1; p += EP) {
                int2 ce = csr[p];
                float w = __int_as_float(ce.y);
                float4 u = load_row<DIN, BF16IN>(src, ce.x, l4);
                if (PREAFF) {
                    u.x = fmaxf(sc.x*u.x+sh.x,0.f); u.y = fmaxf(sc.y*u.y+sh.y,0.f);
                    u.z = fmaxf(sc.z*u.z+sh.z,0.f); u.w = fmaxf(sc.w*u.w+sh.w,0.f);
                }
                acc.x += w*u.x; acc.y += w*u.y; acc.z += w*u.z; acc.w += w*u.w;
                if (POSTAFF) sumw += w;
            }
#pragma unroll
            for (int off = TPN1; off < LPN; off <<= 1) {
                acc.x += __shfl_xor(acc.x, off, 64);
                acc.y += __shfl_xor(acc.y, off, 64);
                acc.z += __shfl_xor(acc.z, off, 64);
                acc.w += __shfl_xor(acc.w, off, 64);
                if (POSTAFF) sumw += __shfl_xor(sumw, off, 64);
            }
            if (POSTAFF) {
                acc.x = sc.x * acc.x + sh.x * sumw;
                acc.y = sc.y * acc.y + sh.y * sumw;
                acc.z = sc.z * acc.z + sh.z * sumw;
                acc.w = sc.w * acc.w + sh.w * sumw;
            }
            if (e0 == 0) *(float4*)&hrow[nl * HS + (l4 << 2)] = acc;
        }
    }
    __syncthreads();
    {
        int jq = tid % TPN2, g2 = tid / TPN2;
        float4 bv = ((const float4*)bias)[jq];
        float4 sv = {0,0,0,0}, qv = {0,0,0,0};
        for (int nl = g2; nl < NPB; nl += G2) {
            int node = nodebase + nl;
            bool valid = node < n;
            float4 a = {0.f, 0.f, 0.f, 0.f};
#pragma unroll
            for (int k4 = 0; k4 < DIN / 4; ++k4) {
                float4 hv = *(const float4*)&hrow[nl * HS + (k4 << 2)];
                const float* wb = &Wl[(k4 * 4) * DOUT + jq * 4];
                float4 w0 = *(const float4*)(wb);
                float4 w1 = *(const float4*)(wb + DOUT);
                float4 w2 = *(const float4*)(wb + 2 * DOUT);
                float4 w3 = *(const float4*)(wb + 3 * DOUT);
                a.x += hv.x*w0.x + hv.y*w1.x + hv.z*w2.x + hv.w*w3.x;
                a.y += hv.x*w0.y + hv.y*w1.y + hv.z*w2.y + hv.w*w3.y;
                a.z += hv.x*w0.z + hv.y*w1.z + hv.z*w2.z + hv.w*w3.z;
                a.w += hv.x*w0.w + hv.y*w1.w + hv.z*w2.w + hv.w*w3.w;
            }
            a.x += bv.x; a.y += bv.y; a.z += bv.z; a.w += bv.w;
            if (RELU) {
                a.x = fmaxf(a.x, 0.f); a.y = fmaxf(a.y, 0.f);
                a.z = fmaxf(a.z, 0.f); a.w = fmaxf(a.w, 0.f);
            }
            if (valid) {
                if (BF16OUT) {
                    ushort4 o;
                    o.x = f2bf(a.x); o.y = f2bf(a.y); o.z = f2bf(a.z); o.w = f2bf(a.w);
                    *(ushort4*)((unsigned short*)out + (size_t)node * DOUT + (jq << 2)) = o;
                } else {
                    ((float4*)out)[(size_t)node * TPN2 + jq] = a;
                }
                sv.x += a.x; sv.y += a.y; sv.z += a.z; sv.w += a.w;
                qv.x += a.x*a.x; qv.y += a.y*a.y; qv.z += a.z*a.z; qv.w += a.w*a.w;
            }
        }
        for (int off = TPN2; off < 64; off <<= 1) {
            sv.x += __shfl_down(sv.x, off, 64); sv.y += __shfl_down(sv.y, off, 64);
            sv.z += __shfl_down(sv.z, off, 64); sv.w += __shfl_down(sv.w, off, 64);
            qv.x += __shfl_down(qv.x, off, 64); qv.y += __shfl_down(qv.y, off, 64);
            qv.z += __shfl_down(qv.z, off, 64); qv.w += __shfl_down(qv.w, off, 64);
        }
        int lane = tid & 63;
        if (lane < TPN2) {
            atomicAdd(&ls[4*lane+0], sv.x); atomicAdd(&ls[4*lane+1], sv.y);
            atomicAdd(&ls[4*lane+2], sv.z); atomicAdd(&ls[4*lane+3], sv.w);
            atomicAdd(&lq[4*lane+0], qv.x); atomicAdd(&lq[4*lane+1], qv.y);
            atomicAdd(&lq[4*lane+2], qv.z); atomicAdd(&lq[4*lane+3], qv.w);
        }
        __syncthreads();
        int bkt = (blockIdx.x & (NBUCKET - 1)) * 256;
        if (tid < DOUT) {
            atomicAdd(&partOut[bkt + tid], ls[tid]);
            atomicAdd(&partOut[bkt + 128 + tid], lq[tid]);
        }
    }
}

// ---------------- standalone d=64 gather (L4/L5): EP=4, bf16-in, fp32-out ----------------
// POSTAFF: BN hoisted; PREAFF: per-edge relu(BN)
template <int POSTAFF, int PREAFF>
__global__ void k_sgather(const unsigned short* __restrict__ src, const int* __restrict__ ptr,
                          const int2* __restrict__ csr, const float* __restrict__ dis,
                          const float* __restrict__ partIn, const float* __restrict__ gmv,
                          const float* __restrict__ btv, float* __restrict__ out, int n) {
    const int TPN = 16, EP = 4, LPN = 64;
    __shared__ float scs[64], shs[64];
    int tid = threadIdx.x;
    if (tid < 64) {
        float s = 0.f, q = 0.f;
#pragma unroll
        for (int b2 = 0; b2 < NBUCKET; ++b2) {
            s += partIn[b2 * 256 + tid];
            q += partIn[b2 * 256 + 128 + tid];
        }
        float mu = s / (float)n;
        float var = q / (float)n - mu * mu;
        float a = gmv[tid] * rsqrtf(var + 1e-5f);
        scs[tid] = a;
        shs[tid] = btv[tid] - mu * a;
    }
    __syncthreads();
    int t = blockIdx.x * 256 + tid;
    int node = t / LPN;
    int r = t - node * LPN;
    int e0 = r / TPN;
    int l4 = r - e0 * TPN;
    bool valid = node < n;
    int nc = valid ? node : n - 1;
    float4 sc = ((const float4*)scs)[l4];
    float4 sh = ((const float4*)shs)[l4];
    float4 acc = {0.f, 0.f, 0.f, 0.f};
    float sumw = 0.f;
    if (e0 == 0) {
        float d = dis[nc];
        float w0 = d * d;
        float4 v = load_row<64, 1>(src, nc, l4);
        if (PREAFF) {
            v.x = fmaxf(sc.x*v.x+sh.x, 0.f); v.y = fmaxf(sc.y*v.y+sh.y, 0.f);
            v.z = fmaxf(sc.z*v.z+sh.z, 0.f); v.w = fmaxf(sc.w*v.w+sh.w, 0.f);
        }
        acc.x = w0*v.x; acc.y = w0*v.y; acc.z = w0*v.z; acc.w = w0*v.w;
        sumw = w0;
    }
    int p0 = ptr[nc], p1 = ptr[nc + 1];
    int p = p0 + e0;
    for (; p + 3 * EP < p1; p += 4 * EP) {
        int2 c0 = csr[p], c1 = csr[p + EP], c2 = csr[p + 2*EP], c3 = csr[p + 3*EP];
        float e0w = __int_as_float(c0.y), e1w = __int_as_float(c1.y);
        float e2w = __int_as_float(c2.y), e3w = __int_as_float(c3.y);
        float4 u0 = load_row<64, 1>(src, c0.x, l4);
        float4 u1 = load_row<64, 1>(src, c1.x, l4);
        float4 u2 = load_row<64, 1>(src, c2.x, l4);
        float4 u3 = load_row<64, 1>(src, c3.x, l4);
        if (PREAFF) {
            u0.x = fmaxf(sc.x*u0.x+sh.x,0.f); u0.y = fmaxf(sc.y*u0.y+sh.y,0.f);
            u0.z = fmaxf(sc.z*u0.z+sh.z,0.f); u0.w = fmaxf(sc.w*u0.w+sh.w,0.f);
            u1.x = fmaxf(sc.x*u1.x+sh.x,0.f); u1.y = fmaxf(sc.y*u1.y+sh.y,0.f);
            u1.z = fmaxf(sc.z*u1.z+sh.z,0.f); u1.w = fmaxf(sc.w*u1.w+sh.w,0.f);
            u2.x = fmaxf(sc.x*u2.x+sh.x,0.f); u2.y = fmaxf(sc.y*u2.y+sh.y,0.f);
            u2.z = fmaxf(sc.z*u2.z+sh.z,0.f); u2.w = fmaxf(sc.w*u2.w+sh.w,0.f);
            u3.x = fmaxf(sc.x*u3.x+sh.x,0.f); u3.y = fmaxf(sc.y*u3.y+sh.y,0.f);
            u3.z = fmaxf(sc.z*u3.z+sh.z,0.f); u3.w = fmaxf(sc.w*u3.w+sh.w,0.f);
        }
        acc.x += e0w*u0.x + e1w*u1.x + e2w*u2.x + e3w*u3.x;
        acc.y += e0w*u0.y + e1w*u1.y + e2w*u2.y + e3w*u3.y;
        acc.z += e0w*u0.z + e1w*u1.z + e2w*u2.z + e3w*u3.z;
        acc.w += e0w*u0.w + e1w*u1.w + e2w*u2.w + e3w*u3.w;
        if (POSTAFF) sumw += e0w + e1w + e2w + e3w;
    }
    for (; p < p1; p += EP) {
        int2 ce = csr[p];
        float w = __int_as_float(ce.y);
        float4 u = load_row<64, 1>(src, ce.x, l4);
        if (PREAFF) {
            u.x = fmaxf(sc.x*u.x+sh.x,0.f); u.y = fmaxf(sc.y*u.y+sh.y,0.f);
            u.z = fmaxf(sc.z*u.z+sh.z,0.f); u.w = fmaxf(sc.w*u.w+sh.w,0.f);
        }
        acc.x += w*u.x; acc.y += w*u.y; acc.z += w*u.z; acc.w += w*u.w;
        if (POSTAFF) sumw += w;
    }
#pragma unroll
    for (int off = TPN; off < LPN; off <<= 1) {
        acc.x += __shfl_xor(acc.x, off, 64);
        acc.y += __shfl_xor(acc.y, off, 64);
        acc.z += __shfl_xor(acc.z, off, 64);
        acc.w += __shfl_xor(acc.w, off, 64);
        if (POSTAFF) sumw += __shfl_xor(sumw, off, 64);
    }
    if (POSTAFF) {
        acc.x = sc.x * acc.x + sh.x * sumw;
        acc.y = sc.y * acc.y + sh.y * sumw;
        acc.z = sc.z * acc.z + sh.z * sumw;
        acc.w = sc.w * acc.w + sh.w * sumw;
    }
    if (valid && e0 == 0) ((float4*)out)[nc * TPN + l4] = acc;
}

// ---------------- standalone gemm DIN=64 -> DOUT, bias + stats -> partOut ----------------
template <int DOUT, int RELU, int BF16OUT>
__global__ void k_sgemm(const float* __restrict__ h, const float* __restrict__ W,
                        const float* __restrict__ bias, float* __restrict__ partOut,
                        void* __restrict__ m, int n) {
    const int TPN = DOUT / 4, GPB = 256 / TPN, NPT = 4;
    __shared__ float Wl[64 * DOUT];
    __shared__ float ls[DOUT], lq[DOUT];
    int tid = threadIdx.x;
    for (int i = tid; i < 64 * DOUT / 4; i += 256)
        ((float4*)Wl)[i] = ((const float4*)W)[i];
    if (tid < DOUT) { ls[tid] = 0.f; lq[tid] = 0.f; }
    __syncthreads();

    int jq = tid % TPN;
    int group = tid / TPN;
    int node0 = (blockIdx.x * GPB + group) * NPT;
    const float4* h4 = (const float4*)h;
    int hb[NPT]; bool val[NPT];
#pragma unroll
    for (int i = 0; i < NPT; ++i) {
        int nd = node0 + i;
        val[i] = nd < n;
        hb[i] = (val[i] ? nd : n - 1) * 16;
    }
    float4 acc[NPT];
#pragma unroll
    for (int i = 0; i < NPT; ++i) acc[i] = {0.f, 0.f, 0.f, 0.f};
#pragma unroll 4
    for (int k4 = 0; k4 < 16; ++k4) {
        const float* wb = &Wl[(k4 * 4) * DOUT + jq * 4];
        float4 w0 = *(const float4*)(wb);
        float4 w1 = *(const float4*)(wb + DOUT);
        float4 w2 = *(const float4*)(wb + 2 * DOUT);
        float4 w3 = *(const float4*)(wb + 3 * DOUT);
#pragma unroll
        for (int i = 0; i < NPT; ++i) {
            float4 hv = h4[hb[i] + k4];
            acc[i].x += hv.x*w0.x + hv.y*w1.x + hv.z*w2.x + hv.w*w3.x;
            acc[i].y += hv.x*w0.y + hv.y*w1.y + hv.z*w2.y + hv.w*w3.y;
            acc[i].z += hv.x*w0.z + hv.y*w1.z + hv.z*w2.z + hv.w*w3.z;
            acc[i].w += hv.x*w0.w + hv.y*w1.w + hv.z*w2.w + hv.w*w3.w;
        }
    }
    float4 bv = ((const float4*)bias)[jq];
    float4 sv = {0,0,0,0}, qv = {0,0,0,0};
#pragma unroll
    for (int i = 0; i < NPT; ++i) {
        float4 a = acc[i];
        a.x += bv.x; a.y += bv.y; a.z += bv.z; a.w += bv.w;
        if (RELU) {
            a.x = fmaxf(a.x, 0.f); a.y = fmaxf(a.y, 0.f);
            a.z = fmaxf(a.z, 0.f); a.w = fmaxf(a.w, 0.f);
        }
        if (val[i]) {
            if (BF16OUT) {
                ushort4 o;
                o.x = f2bf(a.x); o.y = f2bf(a.y); o.z = f2bf(a.z); o.w = f2bf(a.w);
                *(ushort4*)((unsigned short*)m + (size_t)(node0 + i) * DOUT + (jq << 2)) = o;
            } else {
                ((float4*)m)[(size_t)(node0 + i) * TPN + jq] = a;
            }
            sv.x += a.x; sv.y += a.y; sv.z += a.z; sv.w += a.w;
            qv.x += a.x*a.x; qv.y += a.y*a.y; qv.z += a.z*a.z; qv.w += a.w*a.w;
        }
    }
    for (int off = TPN; off < 64; off <<= 1) {
        sv.x += __shfl_down(sv.x, off, 64); sv.y += __shfl_down(sv.y, off, 64);
        sv.z += __shfl_down(sv.z, off, 64); sv.w += __shfl_down(sv.w, off, 64);
        qv.x += __shfl_down(qv.x, off, 64); qv.y += __shfl_down(qv.y, off, 64);
        qv.z += __shfl_down(qv.z, off, 64); qv.w += __shfl_down(qv.w, off, 64);
    }
    int lane = tid & 63;
    if (lane < TPN) {
        atomicAdd(&ls[4*lane+0], sv.x); atomicAdd(&ls[4*lane+1], sv.y);
        atomicAdd(&ls[4*lane+2], sv.z); atomicAdd(&ls[4*lane+3], sv.w);
        atomicAdd(&lq[4*lane+0], qv.x); atomicAdd(&lq[4*lane+1], qv.y);
        atomicAdd(&lq[4*lane+2], qv.z); atomicAdd(&lq[4*lane+3], qv.w);
    }
    __syncthreads();
    int bkt = (blockIdx.x & (NBUCKET - 1)) * 256;
    if (tid < DOUT) {
        atomicAdd(&partOut[bkt + tid], ls[tid]);
        atomicAdd(&partOut[bkt + 128 + tid], lq[tid]);
    }
}

// ---------------- fused pool (BN5 consumed inline) + MLP head ----------------
__global__ void k_poolhead(const float* __restrict__ h, const int* __restrict__ batch,
                           const float* __restrict__ partIn, const float* __restrict__ gmv,
                           const float* __restrict__ btv,
                           const float* __restrict__ fc1w, const float* __restrict__ fc1b,
                           const float* __restrict__ fc2w, const float* __restrict__ fc2b,
                           float* __restrict__ out, int n) {
    __shared__ float tmp[256];
    __shared__ float pl[128];
    __shared__ float scs[128], shs[128];
    int g = blockIdx.x;
    int tid = threadIdx.x;
    if (tid < 128) {
        float s = 0.f, q = 0.f;
#pragma unroll
        for (int b2 = 0; b2 < NBUCKET; ++b2) {
            s += partIn[b2 * 256 + tid];
            q += partIn[b2 * 256 + 128 + tid];
        }
        float mu = s / (float)n;
        float var = q / (float)n - mu * mu;
        float a = gmv[tid] * rsqrtf(var + 1e-5f);
        scs[tid] = a;
        shs[tid] = btv[tid] - mu * a;
    }
    int j = tid & 127, prt = tid >> 7;
    int a = 0, b = n;
    while (a < b) { int mid = (a + b) >> 1; if (batch[mid] < g) a = mid + 1; else b = mid; }
    int lo = a;
    b = n;
    while (a < b) { int mid = (a + b) >> 1; if (batch[mid] < g + 1) a = mid + 1; else b = mid; }
    int hi = a;

    float acc = 0.f;
    for (int node = lo + prt; node < hi; node += 2) acc += h[(long)node * 128 + j];
    tmp[tid] = acc;
    __syncthreads();
    if (tid < 128) {
        float cnt = (float)(hi - lo);
        float p = scs[tid] * (tmp[tid] + tmp[tid + 128]) + shs[tid] * cnt;
        pl[tid] = fmaxf(p, 0.f);
    }
    __syncthreads();
    if (tid < 64) {
        float v1 = fc1b[tid];
        for (int k = 0; k < 128; ++k) v1 += pl[k] * fc1w[k * 64 + tid];
        v1 = fmaxf(v1, 0.f);
        float v = v1 * fc2w[tid];
        for (int off = 32; off > 0; off >>= 1) v += __shfl_down(v, off, 64);
        if (tid == 0) out[g] = v + fc2b[0];
    }
}

// ---------------- driver ----------------
extern "C" void kernel_launch(void* const* d_in, const int* in_sizes, int n_in,
                              void* d_out, int out_size, void* d_ws, size_t ws_size,
                              hipStream_t stream) {
    const float* x     = (const float*)d_in[0];
    const int*   ei    = (const int*)d_in[1];
    const float* ew    = (const float*)d_in[2];
    const int*   batch = (const int*)d_in[3];
    const float *W[5], *b[5], *gm[5], *bt[5];
    for (int i = 0; i < 5; ++i) {
        W[i]  = (const float*)d_in[4 + 4 * i];
        b[i]  = (const float*)d_in[5 + 4 * i];
        gm[i] = (const float*)d_in[6 + 4 * i];
        bt[i] = (const float*)d_in[7 + 4 * i];
    }
    const float* fc1w = (const float*)d_in[24];
    const float* fc1b = (const float*)d_in[25];
    const float* fc2w = (const float*)d_in[26];
    const float* fc2b = (const float*)d_in[27];
    float* out = (float*)d_out;

    // workspace layout
    char* wsb = (char*)d_ws;
    float* dis    = (float*)wsb;  wsb += sizeof(float) * NN;
    int*   ptr    = (int*)wsb;    wsb += sizeof(int) * (NN + 4);
    int*   bb     = (int*)wsb;    wsb += sizeof(int) * ABLK * NBKT;
    int*   totals = (int*)wsb;    wsb += sizeof(int) * (NBKT + 1);
    int*   bbase  = (int*)wsb;    wsb += sizeof(int) * (NBKT + 3);
    wsb = (char*)(((uintptr_t)wsb + 15) & ~(uintptr_t)15);
    int2*  staging= (int2*)wsb;   wsb += sizeof(int2) * NE;
    int2*  csr    = (int2*)wsb;   wsb += sizeof(int2) * NE;
    float* part   = (float*)wsb;  wsb += sizeof(float) * 5 * PARTSZ;
    unsigned short* bufB1 = (unsigned short*)wsb;  wsb += sizeof(unsigned short) * (size_t)NN * 64;
    unsigned short* bufB2 = (unsigned short*)wsb;  wsb += sizeof(unsigned short) * (size_t)NN * 64;
    float* buf1   = (float*)wsb;  wsb += sizeof(float) * (size_t)NN * 64;   // L1 m / agg scratch
    float* buf2   = (float*)wsb;  wsb += sizeof(float) * (size_t)NN * 128;

    const int* row = ei;
    const int* col = ei + NE;
    const int B = 256;
    const int NBF = (NN + 15) / 16;   // 3125 fused-layer blocks
    const int GB1 = (NN + 127) / 128; // 391 gemm1 blocks

    // prologue: bucketed CSR build; gemm1 overlapped with kA3 (independent work)
    kA1<<<ABLK, B, 0, stream>>>(col, bb, part, NE);
    kA2a<<<NBKT, B, 0, stream>>>(bb, totals);
    kA2b<<<1, B, 0, stream>>>(totals, bbase);
    kA3g<<<ABLK + GB1, B, 0, stream>>>(row, col, ew, bb, bbase, staging, x, W[0], buf1, NE, NN);
    kB<<<NBKT, B, 0, stream>>>(bbase, staging, csr, ptr, dis, NN);

    // L1 gather: bias+relu+stats (+ CSR rescale write-back)
    k_l1gather<<<(NN * 4 + 255) / 256, B, 0, stream>>>(buf1, ptr, csr, dis,
                                                       b[0], part + 0 * PARTSZ, buf2, NN);

    // F2: 16->32 fused, consume part[0], fp32 in, bf16 out
    k_fused<16, 32, 4, 1, 0, 1, 0, 1, 16><<<NBF, B, 0, stream>>>(
        buf2, ptr, csr, dis, part + 0 * PARTSZ, gm[0], bt[0],
        W[1], b[1], part + 1 * PARTSZ, bufB1, NN);
    // F3: 32->64 fused, consume part[1], bf16 in/out
    k_fused<32, 64, 4, 1, 0, 1, 1, 1, 16><<<NBF, B, 0, stream>>>(
        bufB1, ptr, csr, dis, part + 1 * PARTSZ, gm[1], bt[1],
        W[2], b[2], part + 2 * PARTSZ, bufB2, NN);

    // L4 UNFUSED (fused was 57us @ 47% occ): gather (BN3 hoisted) then gemm 64->64
    k_sgather<1, 0><<<(int)(((long)NN * 64 + 255) / 256), B, 0, stream>>>(
        bufB2, ptr, csr, dis, part + 2 * PARTSZ, gm[2], bt[2], buf1, NN);
    k_sgemm<64, 0, 1><<<(NN + 63) / 64, B, 0, stream>>>(buf1, W[3], b[3], part + 3 * PARTSZ, bufB1, NN);

    // L5 UNFUSED: gather (per-edge relu(BN4)) then gemm 64->128
    k_sgather<0, 1><<<(int)(((long)NN * 64 + 255) / 256), B, 0, stream>>>(
        bufB1, ptr, csr, dis, part + 3 * PARTSZ, gm[3], bt[3], buf1, NN);
    k_sgemm<128, 0, 0><<<(NN + 31) / 32, B, 0, stream>>>(buf1, W[4], b[4], part + 4 * PARTSZ, buf2, NN);

    // fused pool (consume part[4] -> BN5) + head
    k_poolhead<<<NG, B, 0, stream>>>(buf2, batch, part + 4 * PARTSZ, gm[4], bt[4],
                                     fc1w, fc1b, fc2w, fc2b, out, NN);
}

// Round 15
// 396.457 us; speedup vs baseline: 1.1746x; 1.0260x over previous
//
#include <hip/hip_runtime.h>
#include <stdint.h>

#define NN 50000
#define NE 800000
#define NG 256
#define NBUCKET 16
#define PARTSZ (NBUCKET * 256)

// bucketed CSR build params
#define NBKT 391      // node buckets of 128
#define ABLK 391
#define ASLICE 2048
#define BCAP 2560

__device__ __forceinline__ float bf2f(unsigned short u) {
    return __uint_as_float(((unsigned)u) << 16);
}
__device__ __forceinline__ unsigned short f2bf(float f) {
    unsigned b = __float_as_uint(f);
    return (unsigned short)((b + 0x7FFF + ((b >> 16) & 1)) >> 16);  // RNE
}

// ---------------- prologue ----------------
__global__ void kA1(const int* __restrict__ col, int* __restrict__ bb, float* part, int e) {
    __shared__ int cnt[NBKT];
    for (int j = threadIdx.x; j < NBKT; j += 256) cnt[j] = 0;
    for (int i = blockIdx.x * 256 + threadIdx.x; i < 5 * PARTSZ; i += ABLK * 256) part[i] = 0.f;
    __syncthreads();
    int start = blockIdx.x * ASLICE;
    int end = min(start + ASLICE, e);
    for (int i = start + threadIdx.x; i < end; i += 256)
        atomicAdd(&cnt[col[i] >> 7], 1);
    __syncthreads();
    for (int j = threadIdx.x; j < NBKT; j += 256) bb[blockIdx.x * NBKT + j] = cnt[j];
}

__global__ void kA2a(int* __restrict__ bb, int* __restrict__ totals) {
    __shared__ int v[ABLK];
    int k = blockIdx.x;
    for (int b = threadIdx.x; b < ABLK; b += 256) v[b] = bb[b * NBKT + k];
    __syncthreads();
    if (threadIdx.x == 0) {
        int run = 0;
        for (int b = 0; b < ABLK; ++b) { int t = v[b]; v[b] = run; run += t; }
        totals[k] = run;
    }
    __syncthreads();
    for (int b = threadIdx.x; b < ABLK; b += 256) bb[b * NBKT + k] = v[b];
}

__global__ void kA2b(const int* __restrict__ totals, int* __restrict__ bucketbase) {
    __shared__ int v[NBKT];
    for (int j = threadIdx.x; j < NBKT; j += 256) v[j] = totals[j];
    __syncthreads();
    if (threadIdx.x == 0) {
        int run = 0;
        for (int k = 0; k < NBKT; ++k) { int t = v[k]; v[k] = run; run += t; }
        bucketbase[NBKT] = run;
    }
    __syncthreads();
    for (int j = threadIdx.x; j < NBKT; j += 256) bucketbase[j] = v[j];
}

// A3 (blocks [0,ABLK)) + independent L1 gemm 128->16 (blocks [ABLK,..)) in one dispatch
__global__ void kA3g(const int* __restrict__ row, const int* __restrict__ col,
                     const float* __restrict__ ew, const int* __restrict__ bb,
                     const int* __restrict__ bucketbase, int2* __restrict__ staging,
                     const float* __restrict__ x, const float* __restrict__ W0,
                     float* __restrict__ m1, int e, int n) {
    __shared__ int cur[NBKT];
    __shared__ float Wl[128 * 16];
    int tid = threadIdx.x;
    if ((int)blockIdx.x < ABLK) {
        for (int j = tid; j < NBKT; j += 256)
            cur[j] = bucketbase[j] + bb[blockIdx.x * NBKT + j];
        __syncthreads();
        int start = blockIdx.x * ASLICE;
        int end = min(start + ASLICE, e);
        for (int i = start + tid; i < end; i += 256) {
            int c = col[i];
            int p = atomicAdd(&cur[c >> 7], 1);
            staging[p] = make_int2(row[i] | ((c & 127) << 16), __float_as_int(ew[i]));
        }
        return;
    }
    int bid = (int)blockIdx.x - ABLK;
    for (int i = tid; i < 128 * 16 / 4; i += 256)
        ((float4*)Wl)[i] = ((const float4*)W0)[i];
    __syncthreads();
    int jq = tid % 4, group = tid / 4;
    int node0 = (bid * 64 + group) * 2;
    const float4* h4 = (const float4*)x;
    int hb[2]; bool val[2];
#pragma unroll
    for (int i = 0; i < 2; ++i) {
        int nd = node0 + i;
        val[i] = nd < n;
        hb[i] = (val[i] ? nd : n - 1) * 32;
    }
    float4 acc[2];
    acc[0] = {0,0,0,0}; acc[1] = {0,0,0,0};
#pragma unroll 4
    for (int k4 = 0; k4 < 32; ++k4) {
        const float* wb = &Wl[(k4 * 4) * 16 + jq * 4];
        float4 w0 = *(const float4*)(wb);
        float4 w1 = *(const float4*)(wb + 16);
        float4 w2 = *(const float4*)(wb + 32);
        float4 w3 = *(const float4*)(wb + 48);
#pragma unroll
        for (int i = 0; i < 2; ++i) {
            float4 hv = h4[hb[i] + k4];
            acc[i].x += hv.x*w0.x + hv.y*w1.x + hv.z*w2.x + hv.w*w3.x;
            acc[i].y += hv.x*w0.y + hv.y*w1.y + hv.z*w2.y + hv.w*w3.y;
            acc[i].z += hv.x*w0.z + hv.y*w1.z + hv.z*w2.z + hv.w*w3.z;
            acc[i].w += hv.x*w0.w + hv.y*w1.w + hv.z*w2.w + hv.w*w3.w;
        }
    }
#pragma unroll
    for (int i = 0; i < 2; ++i)
        if (val[i]) ((float4*)m1)[(node0 + i) * 4 + jq] = acc[i];
}

__global__ void __launch_bounds__(256) kB(const int* __restrict__ bucketbase,
                                          const int2* __restrict__ staging,
                                          int2* __restrict__ csr, int* __restrict__ ptr,
                                          float* __restrict__ dis, int n) {
    __shared__ int2 st[BCAP];
    __shared__ int2 outb[BCAP];
    __shared__ int hist[129];
    __shared__ int cur[128];
    int k = blockIdx.x, t = threadIdx.x;
    int base = bucketbase[k], cnt = bucketbase[k + 1] - base;
    int node0 = k << 7;
    int ncov = min(128, n - node0);
    if (t < 129) hist[t] = 0;
    __syncthreads();
    if (cnt <= BCAP) {
        for (int i = t; i < cnt; i += 256) {
            int2 v = staging[base + i];
            st[i] = v;
            atomicAdd(&hist[v.x >> 16], 1);
        }
        __syncthreads();
        if (t == 0) {
            int run = 0;
            for (int j = 0; j < 128; ++j) { int h = hist[j]; hist[j] = run; run += h; }
            hist[128] = run;
        }
        __syncthreads();
        if (t < 128) cur[t] = hist[t];
        if (t < ncov) ptr[node0 + t] = base + hist[t];
        __syncthreads();
        for (int i = t; i < cnt; i += 256) {
            int2 v = st[i];
            int j = v.x >> 16;
            int p = atomicAdd(&cur[j], 1);
            outb[p] = make_int2(v.x & 0xFFFF, v.y);
        }
        __syncthreads();
        for (int i = t; i < cnt; i += 256) csr[base + i] = outb[i];
        if (t < ncov) {
            float s = 1.f;
            int a = hist[t], b2 = hist[t + 1];
            for (int p = a; p < b2; ++p) s += __int_as_float(outb[p].y);
            dis[node0 + t] = rsqrtf(s);
        }
    } else {
        for (int i = t; i < cnt; i += 256) atomicAdd(&hist[staging[base + i].x >> 16], 1);
        __syncthreads();
        if (t == 0) {
            int run = 0;
            for (int j = 0; j < 128; ++j) { int h = hist[j]; hist[j] = run; run += h; }
            hist[128] = run;
        }
        __syncthreads();
        if (t < 128) cur[t] = hist[t];
        if (t < ncov) ptr[node0 + t] = base + hist[t];
        __syncthreads();
        for (int i = t; i < cnt; i += 256) {
            int2 v = staging[base + i];
            int j = v.x >> 16;
            int p = atomicAdd(&cur[j], 1);
            csr[base + p] = make_int2(v.x & 0xFFFF, v.y);
        }
        __threadfence_block();
        __syncthreads();
        if (t < ncov) {
            float s = 1.f;
            int a = hist[t], b2 = hist[t + 1];
            for (int p = a; p < b2; ++p) s += __int_as_float(csr[base + p].y);
            dis[node0 + t] = rsqrtf(s);
        }
    }
    if (k == gridDim.x - 1 && t == 0) ptr[n] = bucketbase[NBKT];
}

// ---------------- L1 gather: EPI (bias+relu+stats) + CSR rescale write-back ----------------
__global__ void k_l1gather(const float* __restrict__ src, const int* __restrict__ ptr,
                           int2* __restrict__ csr, const float* __restrict__ dis,
                           const float* __restrict__ bias, float* __restrict__ partOut,
                           float* __restrict__ out, int n) {
    __shared__ float ls[16], lq[16];
    int tid = threadIdx.x;
    if (tid < 16) { ls[tid] = 0.f; lq[tid] = 0.f; }
    __syncthreads();
    int t = blockIdx.x * 256 + tid;
    int node = t >> 2;
    int l4 = t & 3;
    bool valid = node < n;
    int nc = valid ? node : n - 1;
    const float4* s4 = (const float4*)src;
    float dc = dis[nc];
    float w0 = dc * dc;
    float4 v = s4[nc * 4 + l4];
    float4 acc = { w0 * v.x, w0 * v.y, w0 * v.z, w0 * v.w };
    int p0 = ptr[nc], p1 = ptr[nc + 1];
    int p = p0;
    for (; p + 4 <= p1; p += 4) {
        int2 c0 = csr[p], c1 = csr[p+1], c2 = csr[p+2], c3 = csr[p+3];
        float e0 = dis[c0.x] * __int_as_float(c0.y) * dc;
        float e1 = dis[c1.x] * __int_as_float(c1.y) * dc;
        float e2 = dis[c2.x] * __int_as_float(c2.y) * dc;
        float e3 = dis[c3.x] * __int_as_float(c3.y) * dc;
        float4 u0 = s4[c0.x * 4 + l4];
        float4 u1 = s4[c1.x * 4 + l4];
        float4 u2 = s4[c2.x * 4 + l4];
        float4 u3 = s4[c3.x * 4 + l4];
        acc.x += e0*u0.x + e1*u1.x + e2*u2.x + e3*u3.x;
        acc.y += e0*u0.y + e1*u1.y + e2*u2.y + e3*u3.y;
        acc.z += e0*u0.z + e1*u1.z + e2*u2.z + e3*u3.z;
        acc.w += e0*u0.w + e1*u1.w + e2*u2.w + e3*u3.w;
        if (l4 == 0) {
            csr[p]   = make_int2(c0.x, __float_as_int(e0));
            csr[p+1] = make_int2(c1.x, __float_as_int(e1));
            csr[p+2] = make_int2(c2.x, __float_as_int(e2));
            csr[p+3] = make_int2(c3.x, __float_as_int(e3));
        }
    }
    for (; p < p1; ++p) {
        int2 ce = csr[p];
        float w = dis[ce.x] * __int_as_float(ce.y) * dc;
        float4 u = s4[ce.x * 4 + l4];
        acc.x += w*u.x; acc.y += w*u.y; acc.z += w*u.z; acc.w += w*u.w;
        if (l4 == 0) csr[p] = make_int2(ce.x, __float_as_int(w));
    }
    float4 b = ((const float4*)bias)[l4];
    acc.x = fmaxf(acc.x + b.x, 0.f);
    acc.y = fmaxf(acc.y + b.y, 0.f);
    acc.z = fmaxf(acc.z + b.z, 0.f);
    acc.w = fmaxf(acc.w + b.w, 0.f);
    if (valid) ((float4*)out)[nc * 4 + l4] = acc;
    float s0 = valid ? acc.x : 0.f, s1 = valid ? acc.y : 0.f;
    float s2 = valid ? acc.z : 0.f, s3 = valid ? acc.w : 0.f;
    float q0 = s0*s0, q1 = s1*s1, q2 = s2*s2, q3 = s3*s3;
    for (int off = 4; off < 64; off <<= 1) {
        s0 += __shfl_down(s0, off, 64); s1 += __shfl_down(s1, off, 64);
        s2 += __shfl_down(s2, off, 64); s3 += __shfl_down(s3, off, 64);
        q0 += __shfl_down(q0, off, 64); q1 += __shfl_down(q1, off, 64);
        q2 += __shfl_down(q2, off, 64); q3 += __shfl_down(q3, off, 64);
    }
    int lane = tid & 63;
    if (lane < 4) {
        atomicAdd(&ls[4*lane+0], s0); atomicAdd(&ls[4*lane+1], s1);
        atomicAdd(&ls[4*lane+2], s2); atomicAdd(&ls[4*lane+3], s3);
        atomicAdd(&lq[4*lane+0], q0); atomicAdd(&lq[4*lane+1], q1);
        atomicAdd(&lq[4*lane+2], q2); atomicAdd(&lq[4*lane+3], q3);
    }
    __syncthreads();
    int bkt = (blockIdx.x & (NBUCKET - 1)) * 256;
    if (tid < 16) {
        atomicAdd(&partOut[bkt + tid], ls[tid]);
        atomicAdd(&partOut[bkt + 128 + tid], lq[tid]);
    }
}

// row loader: fp32 float4 or bf16 ushort4 -> float4
template <int D, int BF16>
__device__ __forceinline__ float4 load_row(const void* src, int node, int l4) {
    if (BF16) {
        const unsigned short* sb = (const unsigned short*)src;
        ushort4 r = *(const ushort4*)(sb + (size_t)node * D + (l4 << 2));
        float4 f;
        f.x = bf2f(r.x); f.y = bf2f(r.y); f.z = bf2f(r.z); f.w = bf2f(r.w);
        return f;
    } else {
        const float4* s4 = (const float4*)src;
        return s4[(size_t)node * (D / 4) + l4];
    }
}

// ---------------- fused layer (F2 only — 2KB Wl): gather -> LDS rows -> gemm ------------
template <int DIN, int DOUT, int EP, int POSTAFF, int PREAFF, int RELU,
          int BF16IN, int BF16OUT, int NPB>
__global__ void __launch_bounds__(256) k_fused(
        const void* __restrict__ src, const int* __restrict__ ptr,
        const int2* __restrict__ csr, const float* __restrict__ dis,
        const float* __restrict__ partIn, const float* __restrict__ gmv,
        const float* __restrict__ btv, const float* __restrict__ W,
        const float* __restrict__ bias, float* __restrict__ partOut,
        void* __restrict__ out, int n) {
    const int TPN1 = DIN / 4, LPN = TPN1 * EP, GN1 = 256 / LPN;
    const int TPN2 = DOUT / 4, G2 = 256 / TPN2;
    const int HS = DIN + 4;
    __shared__ float Wl[DIN * DOUT];
    __shared__ float hrow[NPB * HS];
    __shared__ float scs[DIN], shs[DIN];
    __shared__ float ls[DOUT], lq[DOUT];
    int tid = threadIdx.x;
    for (int i = tid; i < DIN * DOUT / 4; i += 256)
        ((float4*)Wl)[i] = ((const float4*)W)[i];
    if (tid < DIN) {
        float s = 0.f, q = 0.f;
#pragma unroll
        for (int b2 = 0; b2 < NBUCKET; ++b2) {
            s += partIn[b2 * 256 + tid];
            q += partIn[b2 * 256 + 128 + tid];
        }
        float mu = s / (float)n;
        float var = q / (float)n - mu * mu;
        float a = gmv[tid] * rsqrtf(var + 1e-5f);
        scs[tid] = a;
        shs[tid] = btv[tid] - mu * a;
    }
    if (tid < DOUT) { ls[tid] = 0.f; lq[tid] = 0.f; }
    __syncthreads();

    int nodebase = blockIdx.x * NPB;
    {
        int grp = tid / LPN, r = tid % LPN;
        int e0 = r / TPN1, l4 = r % TPN1;
        float4 sc = ((const float4*)scs)[l4];
        float4 sh = ((const float4*)shs)[l4];
#pragma unroll
        for (int pass = 0; pass < NPB / GN1; ++pass) {
            int nl = pass * GN1 + grp;
            int node = nodebase + nl;
            int nc = node < n ? node : n - 1;
            float4 acc = {0.f, 0.f, 0.f, 0.f};
            float sumw = 0.f;
            if (e0 == 0) {
                float d = dis[nc];
                float w0 = d * d;
                float4 v = load_row<DIN, BF16IN>(src, nc, l4);
                if (PREAFF) {
                    v.x = fmaxf(sc.x*v.x+sh.x, 0.f); v.y = fmaxf(sc.y*v.y+sh.y, 0.f);
                    v.z = fmaxf(sc.z*v.z+sh.z, 0.f); v.w = fmaxf(sc.w*v.w+sh.w, 0.f);
                }
                acc.x = w0*v.x; acc.y = w0*v.y; acc.z = w0*v.z; acc.w = w0*v.w;
                sumw = w0;
            }
            int p0 = ptr[nc], p1 = ptr[nc + 1];
            int p = p0 + e0;
            for (; p + 3 * EP < p1; p += 4 * EP) {
                int2 c0 = csr[p], c1 = csr[p + EP], c2 = csr[p + 2*EP], c3 = csr[p + 3*EP];
                float e0w = __int_as_float(c0.y), e1w = __int_as_float(c1.y);
                float e2w = __int_as_float(c2.y), e3w = __int_as_float(c3.y);
                float4 u0 = load_row<DIN, BF16IN>(src, c0.x, l4);
                float4 u1 = load_row<DIN, BF16IN>(src, c1.x, l4);
                float4 u2 = load_row<DIN, BF16IN>(src, c2.x, l4);
                float4 u3 = load_row<DIN, BF16IN>(src, c3.x, l4);
                if (PREAFF) {
                    u0.x = fmaxf(sc.x*u0.x+sh.x,0.f); u0.y = fmaxf(sc.y*u0.y+sh.y,0.f);
                    u0.z = fmaxf(sc.z*u0.z+sh.z,0.f); u0.w = fmaxf(sc.w*u0.w+sh.w,0.f);
                    u1.x = fmaxf(sc.x*u1.x+sh.x,0.f); u1.y = fmaxf(sc.y*u1.y+sh.y,0.f);
                    u1.z = fmaxf(sc.z*u1.z+sh.z,0.f); u1.w = fmaxf(sc.w*u1.w+sh.w,0.f);
                    u2.x = fmaxf(sc.x*u2.x+sh.x,0.f); u2.y = fmaxf(sc.y*u2.y+sh.y,0.f);
                    u2.z = fmaxf(sc.z*u2.z+sh.z,0.f); u2.w = fmaxf(sc.w*u2.w+sh.w,0.f);
                    u3.x = fmaxf(sc.x*u3.x+sh.x,0.f); u3.y = fmaxf(sc.y*u3.y+sh.y,0.f);
                    u3.z = fmaxf(sc.z*u3.z+sh.z,0.f); u3.w = fmaxf(sc.w*u3.w+sh.w,0.f);
                }
                acc.x += e0w*u0.x + e1w*u1.x + e2w*u2.x + e3w*u3.x;
                acc.y += e0w*u0.y + e1w*u1.y + e2w*u2.y + e3w*u3.y;
                acc.z += e0w*u0.z + e1w*u1.z + e2w*u2.z + e3w*u3.z;
                acc.w += e0w*u0.w + e1w*u1.w + e2w*u2.w + e3w*u3.w;
                if (POSTAFF) sumw += e0w + e1w + e2w + e3w;
            }
            for (; p < p1; p += EP) {
                int2 ce = csr[p];
                float w = __int_as_float(ce.y);
                float4 u = load_row<DIN, BF16IN>(src, ce.x, l4);
                if (PREAFF) {
                    u.x = fmaxf(sc.x*u.x+sh.x,0.f); u.y = fmaxf(sc.y*u.y+sh.y,0.f);
                    u.z = fmaxf(sc.z*u.z+sh.z,0.f); u.w = fmaxf(sc.w*u.w+sh.w,0.f);
                }
                acc.x += w*u.x; acc.y += w*u.y; acc.z += w*u.z; acc.w += w*u.w;
                if (POSTAFF) sumw += w;
            }
#pragma unroll
            for (int off = TPN1; off < LPN; off <<= 1) {
                acc.x += __shfl_xor(acc.x, off, 64);
                acc.y += __shfl_xor(acc.y, off, 64);
                acc.z += __shfl_xor(acc.z, off, 64);
                acc.w += __shfl_xor(acc.w, off, 64);
                if (POSTAFF) sumw += __shfl_xor(sumw, off, 64);
            }
            if (POSTAFF) {
                acc.x = sc.x * acc.x + sh.x * sumw;
                acc.y = sc.y * acc.y + sh.y * sumw;
                acc.z = sc.z * acc.z + sh.z * sumw;
                acc.w = sc.w * acc.w + sh.w * sumw;
            }
            if (e0 == 0) *(float4*)&hrow[nl * HS + (l4 << 2)] = acc;
        }
    }
    __syncthreads();
    {
        int jq = tid % TPN2, g2 = tid / TPN2;
        float4 bv = ((const float4*)bias)[jq];
        float4 sv = {0,0,0,0}, qv = {0,0,0,0};
        for (int nl = g2; nl < NPB; nl += G2) {
            int node = nodebase + nl;
            bool valid = node < n;
            float4 a = {0.f, 0.f, 0.f, 0.f};
#pragma unroll
            for (int k4 = 0; k4 < DIN / 4; ++k4) {
                float4 hv = *(const float4*)&hrow[nl * HS + (k4 << 2)];
                const float* wb = &Wl[(k4 * 4) * DOUT + jq * 4];
                float4 w0 = *(const float4*)(wb);
                float4 w1 = *(const float4*)(wb + DOUT);
                float4 w2 = *(const float4*)(wb + 2 * DOUT);
                float4 w3 = *(const float4*)(wb + 3 * DOUT);
                a.x += hv.x*w0.x + hv.y*w1.x + hv.z*w2.x + hv.w*w3.x;
                a.y += hv.x*w0.y + hv.y*w1.y + hv.z*w2.y + hv.w*w3.y;
                a.z += hv.x*w0.z + hv.y*w1.z + hv.z*w2.z + hv.w*w3.z;
                a.w += hv.x*w0.w + hv.y*w1.w + hv.z*w2.w + hv.w*w3.w;
            }
            a.x += bv.x; a.y += bv.y; a.z += bv.z; a.w += bv.w;
            if (RELU) {
                a.x = fmaxf(a.x, 0.f); a.y = fmaxf(a.y, 0.f);
                a.z = fmaxf(a.z, 0.f); a.w = fmaxf(a.w, 0.f);
            }
            if (valid) {
                if (BF16OUT) {
                    ushort4 o;
                    o.x = f2bf(a.x); o.y = f2bf(a.y); o.z = f2bf(a.z); o.w = f2bf(a.w);
                    *(ushort4*)((unsigned short*)out + (size_t)node * DOUT + (jq << 2)) = o;
                } else {
                    ((float4*)out)[(size_t)node * TPN2 + jq] = a;
                }
                sv.x += a.x; sv.y += a.y; sv.z += a.z; sv.w += a.w;
                qv.x += a.x*a.x; qv.y += a.y*a.y; qv.z += a.z*a.z; qv.w += a.w*a.w;
            }
        }
        for (int off = TPN2; off < 64; off <<= 1) {
            sv.x += __shfl_down(sv.x, off, 64); sv.y += __shfl_down(sv.y, off, 64);
            sv.z += __shfl_down(sv.z, off, 64); sv.w += __shfl_down(sv.w, off, 64);
            qv.x += __shfl_down(qv.x, off, 64); qv.y += __shfl_down(qv.y, off, 64);
            qv.z += __shfl_down(qv.z, off, 64); qv.w += __shfl_down(qv.w, off, 64);
        }
        int lane = tid & 63;
        if (lane < TPN2) {
            atomicAdd(&ls[4*lane+0], sv.x); atomicAdd(&ls[4*lane+1], sv.y);
            atomicAdd(&ls[4*lane+2], sv.z); atomicAdd(&ls[4*lane+3], sv.w);
            atomicAdd(&lq[4*lane+0], qv.x); atomicAdd(&lq[4*lane+1], qv.y);
            atomicAdd(&lq[4*lane+2], qv.z); atomicAdd(&lq[4*lane+3], qv.w);
        }
        __syncthreads();
        int bkt = (blockIdx.x & (NBUCKET - 1)) * 256;
        if (tid < DOUT) {
            atomicAdd(&partOut[bkt + tid], ls[tid]);
            atomicAdd(&partOut[bkt + 128 + tid], lq[tid]);
        }
    }
}

// ---------------- standalone gather (L3/L4/L5): EP=4, bf16-in, fp32-out ----------------
// POSTAFF: BN hoisted out of edge loop; PREAFF: per-edge relu(BN)
template <int D, int POSTAFF, int PREAFF>
__global__ void k_sgather(const unsigned short* __restrict__ src, const int* __restrict__ ptr,
                          const int2* __restrict__ csr, const float* __restrict__ dis,
                          const float* __restrict__ partIn, const float* __restrict__ gmv,
                          const float* __restrict__ btv, float* __restrict__ out, int n) {
    const int TPN = D / 4, EP = 4, LPN = TPN * EP;
    __shared__ float scs[D], shs[D];
    int tid = threadIdx.x;
    if (tid < D) {
        float s = 0.f, q = 0.f;
#pragma unroll
        for (int b2 = 0; b2 < NBUCKET; ++b2) {
            s += partIn[b2 * 256 + tid];
            q += partIn[b2 * 256 + 128 + tid];
        }
        float mu = s / (float)n;
        float var = q / (float)n - mu * mu;
        float a = gmv[tid] * rsqrtf(var + 1e-5f);
        scs[tid] = a;
        shs[tid] = btv[tid] - mu * a;
    }
    __syncthreads();
    int t = blockIdx.x * 256 + tid;
    int node = t / LPN;
    int r = t - node * LPN;
    int e0 = r / TPN;
    int l4 = r - e0 * TPN;
    bool valid = node < n;
    int nc = valid ? node : n - 1;
    float4 sc = ((const float4*)scs)[l4];
    float4 sh = ((const float4*)shs)[l4];
    float4 acc = {0.f, 0.f, 0.f, 0.f};
    float sumw = 0.f;
    if (e0 == 0) {
        float d = dis[nc];
        float w0 = d * d;
        float4 v = load_row<D, 1>(src, nc, l4);
        if (PREAFF) {
            v.x = fmaxf(sc.x*v.x+sh.x, 0.f); v.y = fmaxf(sc.y*v.y+sh.y, 0.f);
            v.z = fmaxf(sc.z*v.z+sh.z, 0.f); v.w = fmaxf(sc.w*v.w+sh.w, 0.f);
        }
        acc.x = w0*v.x; acc.y = w0*v.y; acc.z = w0*v.z; acc.w = w0*v.w;
        sumw = w0;
    }
    int p0 = ptr[nc], p1 = ptr[nc + 1];
    int p = p0 + e0;
    for (; p + 3 * EP < p1; p += 4 * EP) {
        int2 c0 = csr[p], c1 = csr[p + EP], c2 = csr[p + 2*EP], c3 = csr[p + 3*EP];
        float e0w = __int_as_float(c0.y), e1w = __int_as_float(c1.y);
        float e2w = __int_as_float(c2.y), e3w = __int_as_float(c3.y);
        float4 u0 = load_row<D, 1>(src, c0.x, l4);
        float4 u1 = load_row<D, 1>(src, c1.x, l4);
        float4 u2 = load_row<D, 1>(src, c2.x, l4);
        float4 u3 = load_row<D, 1>(src, c3.x, l4);
        if (PREAFF) {
            u0.x = fmaxf(sc.x*u0.x+sh.x,0.f); u0.y = fmaxf(sc.y*u0.y+sh.y,0.f);
            u0.z = fmaxf(sc.z*u0.z+sh.z,0.f); u0.w = fmaxf(sc.w*u0.w+sh.w,0.f);
            u1.x = fmaxf(sc.x*u1.x+sh.x,0.f); u1.y = fmaxf(sc.y*u1.y+sh.y,0.f);
            u1.z = fmaxf(sc.z*u1.z+sh.z,0.f); u1.w = fmaxf(sc.w*u1.w+sh.w,0.f);
            u2.x = fmaxf(sc.x*u2.x+sh.x,0.f); u2.y = fmaxf(sc.y*u2.y+sh.y,0.f);
            u2.z = fmaxf(sc.z*u2.z+sh.z,0.f); u2.w = fmaxf(sc.w*u2.w+sh.w,0.f);
            u3.x = fmaxf(sc.x*u3.x+sh.x,0.f); u3.y = fmaxf(sc.y*u3.y+sh.y,0.f);
            u3.z = fmaxf(sc.z*u3.z+sh.z,0.f); u3.w = fmaxf(sc.w*u3.w+sh.w,0.f);
        }
        acc.x += e0w*u0.x + e1w*u1.x + e2w*u2.x + e3w*u3.x;
        acc.y += e0w*u0.y + e1w*u1.y + e2w*u2.y + e3w*u3.y;
        acc.z += e0w*u0.z + e1w*u1.z + e2w*u2.z + e3w*u3.z;
        acc.w += e0w*u0.w + e1w*u1.w + e2w*u2.w + e3w*u3.w;
        if (POSTAFF) sumw += e0w + e1w + e2w + e3w;
    }
    for (; p < p1; p += EP) {
        int2 ce = csr[p];
        float w = __int_as_float(ce.y);
        float4 u = load_row<D, 1>(src, ce.x, l4);
        if (PREAFF) {
            u.x = fmaxf(sc.x*u.x+sh.x,0.f); u.y = fmaxf(sc.y*u.y+sh.y,0.f);
            u.z = fmaxf(sc.z*u.z+sh.z,0.f); u.w = fmaxf(sc.w*u.w+sh.w,0.f);
        }
        acc.x += w*u.x; acc.y += w*u.y; acc.z += w*u.z; acc.w += w*u.w;
        if (POSTAFF) sumw += w;
    }
#pragma unroll
    for (int off = TPN; off < LPN; off <<= 1) {
        acc.x += __shfl_xor(acc.x, off, 64);
        acc.y += __shfl_xor(acc.y, off, 64);
        acc.z += __shfl_xor(acc.z, off, 64);
        acc.w += __shfl_xor(acc.w, off, 64);
        if (POSTAFF) sumw += __shfl_xor(sumw, off, 64);
    }
    if (POSTAFF) {
        acc.x = sc.x * acc.x + sh.x * sumw;
        acc.y = sc.y * acc.y + sh.y * sumw;
        acc.z = sc.z * acc.z + sh.z * sumw;
        acc.w = sc.w * acc.w + sh.w * sumw;
    }
    if (valid && e0 == 0) ((float4*)out)[nc * TPN + l4] = acc;
}

// ---------------- standalone gemm DIN -> DOUT, bias + optional relu + stats ----------------
template <int DIN, int DOUT, int RELU, int BF16OUT>
__global__ void k_sgemm(const float* __restrict__ h, const float* __restrict__ W,
                        const float* __restrict__ bias, float* __restrict__ partOut,
                        void* __restrict__ m, int n) {
    const int TPN = DOUT / 4, GPB = 256 / TPN, NPT = 4;
    __shared__ float Wl[DIN * DOUT];
    __shared__ float ls[DOUT], lq[DOUT];
    int tid = threadIdx.x;
    for (int i = tid; i < DIN * DOUT / 4; i += 256)
        ((float4*)Wl)[i] = ((const float4*)W)[i];
    if (tid < DOUT) { ls[tid] = 0.f; lq[tid] = 0.f; }
    __syncthreads();

    int jq = tid % TPN;
    int group = tid / TPN;
    int node0 = (blockIdx.x * GPB + group) * NPT;
    const float4* h4 = (const float4*)h;
    int hb[NPT]; bool val[NPT];
#pragma unroll
    for (int i = 0; i < NPT; ++i) {
        int nd = node0 + i;
        val[i] = nd < n;
        hb[i] = (val[i] ? nd : n - 1) * (DIN / 4);
    }
    float4 acc[NPT];
#pragma unroll
    for (int i = 0; i < NPT; ++i) acc[i] = {0.f, 0.f, 0.f, 0.f};
#pragma unroll 4
    for (int k4 = 0; k4 < DIN / 4; ++k4) {
        const float* wb = &Wl[(k4 * 4) * DOUT + jq * 4];
        float4 w0 = *(const float4*)(wb);
        float4 w1 = *(const float4*)(wb + DOUT);
        float4 w2 = *(const float4*)(wb + 2 * DOUT);
        float4 w3 = *(const float4*)(wb + 3 * DOUT);
#pragma unroll
        for (int i = 0; i < NPT; ++i) {
            float4 hv = h4[hb[i] + k4];
            acc[i].x += hv.x*w0.x + hv.y*w1.x + hv.z*w2.x + hv.w*w3.x;
            acc[i].y += hv.x*w0.y + hv.y*w1.y + hv.z*w2.y + hv.w*w3.y;
            acc[i].z += hv.x*w0.z + hv.y*w1.z + hv.z*w2.z + hv.w*w3.z;
            acc[i].w += hv.x*w0.w + hv.y*w1.w + hv.z*w2.w + hv.w*w3.w;
        }
    }
    float4 bv = ((const float4*)bias)[jq];
    float4 sv = {0,0,0,0}, qv = {0,0,0,0};
#pragma unroll
    for (int i = 0; i < NPT; ++i) {
        float4 a = acc[i];
        a.x += bv.x; a.y += bv.y; a.z += bv.z; a.w += bv.w;
        if (RELU) {
            a.x = fmaxf(a.x, 0.f); a.y = fmaxf(a.y, 0.f);
            a.z = fmaxf(a.z, 0.f); a.w = fmaxf(a.w, 0.f);
        }
        if (val[i]) {
            if (BF16OUT) {
                ushort4 o;
                o.x = f2bf(a.x); o.y = f2bf(a.y); o.z = f2bf(a.z); o.w = f2bf(a.w);
                *(ushort4*)((unsigned short*)m + (size_t)(node0 + i) * DOUT + (jq << 2)) = o;
            } else {
                ((float4*)m)[(size_t)(node0 + i) * TPN + jq] = a;
            }
            sv.x += a.x; sv.y += a.y; sv.z += a.z; sv.w += a.w;
            qv.x += a.x*a.x; qv.y += a.y*a.y; qv.z += a.z*a.z; qv.w += a.w*a.w;
        }
    }
    for (int off = TPN; off < 64; off <<= 1) {
        sv.x += __shfl_down(sv.x, off, 64); sv.y += __shfl_down(sv.y, off, 64);
        sv.z += __shfl_down(sv.z, off, 64); sv.w += __shfl_down(sv.w, off, 64);
        qv.x += __shfl_down(qv.x, off, 64); qv.y += __shfl_down(qv.y, off, 64);
        qv.z += __shfl_down(qv.z, off, 64); qv.w += __shfl_down(qv.w, off, 64);
    }
    int lane = tid & 63;
    if (lane < TPN) {
        atomicAdd(&ls[4*lane+0], sv.x); atomicAdd(&ls[4*lane+1], sv.y);
        atomicAdd(&ls[4*lane+2], sv.z); atomicAdd(&ls[4*lane+3], sv.w);
        atomicAdd(&lq[4*lane+0], qv.x); atomicAdd(&lq[4*lane+1], qv.y);
        atomicAdd(&lq[4*lane+2], qv.z); atomicAdd(&lq[4*lane+3], qv.w);
    }
    __syncthreads();
    int bkt = (blockIdx.x & (NBUCKET - 1)) * 256;
    if (tid < DOUT) {
        atomicAdd(&partOut[bkt + tid], ls[tid]);
        atomicAdd(&partOut[bkt + 128 + tid], lq[tid]);
    }
}

// ---------------- fused pool (BN5 consumed inline) + MLP head ----------------
__global__ void k_poolhead(const float* __restrict__ h, const int* __restrict__ batch,
                           const float* __restrict__ partIn, const float* __restrict__ gmv,
                           const float* __restrict__ btv,
                           const float* __restrict__ fc1w, const float* __restrict__ fc1b,
                           const float* __restrict__ fc2w, const float* __restrict__ fc2b,
                           float* __restrict__ out, int n) {
    __shared__ float tmp[256];
    __shared__ float pl[128];
    __shared__ float scs[128], shs[128];
    int g = blockIdx.x;
    int tid = threadIdx.x;
    if (tid < 128) {
        float s = 0.f, q = 0.f;
#pragma unroll
        for (int b2 = 0; b2 < NBUCKET; ++b2) {
            s += partIn[b2 * 256 + tid];
            q += partIn[b2 * 256 + 128 + tid];
        }
        float mu = s / (float)n;
        float var = q / (float)n - mu * mu;
        float a = gmv[tid] * rsqrtf(var + 1e-5f);
        scs[tid] = a;
        shs[tid] = btv[tid] - mu * a;
    }
    int j = tid & 127, prt = tid >> 7;
    int a = 0, b = n;
    while (a < b) { int mid = (a + b) >> 1; if (batch[mid] < g) a = mid + 1; else b = mid; }
    int lo = a;
    b = n;
    while (a < b) { int mid = (a + b) >> 1; if (batch[mid] < g + 1) a = mid + 1; else b = mid; }
    int hi = a;

    float acc = 0.f;
    for (int node = lo + prt; node < hi; node += 2) acc += h[(long)node * 128 + j];
    tmp[tid] = acc;
    __syncthreads();
    if (tid < 128) {
        float cnt = (float)(hi - lo);
        float p = scs[tid] * (tmp[tid] + tmp[tid + 128]) + shs[tid] * cnt;
        pl[tid] = fmaxf(p, 0.f);
    }
    __syncthreads();
    if (tid < 64) {
        float v1 = fc1b[tid];
        for (int k = 0; k < 128; ++k) v1 += pl[k] * fc1w[k * 64 + tid];
        v1 = fmaxf(v1, 0.f);
        float v = v1 * fc2w[tid];
        for (int off = 32; off > 0; off >>= 1) v += __shfl_down(v, off, 64);
        if (tid == 0) out[g] = v + fc2b[0];
    }
}

// ---------------- driver ----------------
extern "C" void kernel_launch(void* const* d_in, const int* in_sizes, int n_in,
                              void* d_out, int out_size, void* d_ws, size_t ws_size,
                              hipStream_t stream) {
    const float* x     = (const float*)d_in[0];
    const int*   ei    = (const int*)d_in[1];
    const float* ew    = (const float*)d_in[2];
    const int*   batch = (const int*)d_in[3];
    const float *W[5], *b[5], *gm[5], *bt[5];
    for (int i = 0; i < 5; ++i) {
        W[i]  = (const float*)d_in[4 + 4 * i];
        b[i]  = (const float*)d_in[5 + 4 * i];
        gm[i] = (const float*)d_in[6 + 4 * i];
        bt[i] = (const float*)d_in[7 + 4 * i];
    }
    const float* fc1w = (const float*)d_in[24];
    const float* fc1b = (const float*)d_in[25];
    const float* fc2w = (const float*)d_in[26];
    const float* fc2b = (const float*)d_in[27];
    float* out = (float*)d_out;

    // workspace layout
    char* wsb = (char*)d_ws;
    float* dis    = (float*)wsb;  wsb += sizeof(float) * NN;
    int*   ptr    = (int*)wsb;    wsb += sizeof(int) * (NN + 4);
    int*   bb     = (int*)wsb;    wsb += sizeof(int) * ABLK * NBKT;
    int*   totals = (int*)wsb;    wsb += sizeof(int) * (NBKT + 1);
    int*   bbase  = (int*)wsb;    wsb += sizeof(int) * (NBKT + 3);
    wsb = (char*)(((uintptr_t)wsb + 15) & ~(uintptr_t)15);
    int2*  staging= (int2*)wsb;   wsb += sizeof(int2) * NE;
    int2*  csr    = (int2*)wsb;   wsb += sizeof(int2) * NE;
    float* part   = (float*)wsb;  wsb += sizeof(float) * 5 * PARTSZ;
    unsigned short* bufB1 = (unsigned short*)wsb;  wsb += sizeof(unsigned short) * (size_t)NN * 64;
    unsigned short* bufB2 = (unsigned short*)wsb;  wsb += sizeof(unsigned short) * (size_t)NN * 64;
    float* buf1   = (float*)wsb;  wsb += sizeof(float) * (size_t)NN * 64;   // L1 m / agg scratch
    float* buf2   = (float*)wsb;  wsb += sizeof(float) * (size_t)NN * 128;

    const int* row = ei;
    const int* col = ei + NE;
    const int B = 256;
    const int NBF = (NN + 15) / 16;   // fused F2 blocks
    const int GB1 = (NN + 127) / 128; // gemm1 blocks

    // prologue: bucketed CSR build; gemm1 overlapped with kA3 (independent work)
    kA1<<<ABLK, B, 0, stream>>>(col, bb, part, NE);
    kA2a<<<NBKT, B, 0, stream>>>(bb, totals);
    kA2b<<<1, B, 0, stream>>>(totals, bbase);
    kA3g<<<ABLK + GB1, B, 0, stream>>>(row, col, ew, bb, bbase, staging, x, W[0], buf1, NE, NN);
    kB<<<NBKT, B, 0, stream>>>(bbase, staging, csr, ptr, dis, NN);

    // L1 gather: bias+relu+stats (+ CSR rescale write-back)
    k_l1gather<<<(NN * 4 + 255) / 256, B, 0, stream>>>(buf1, ptr, csr, dis,
                                                       b[0], part + 0 * PARTSZ, buf2, NN);

    // F2: 16->32 fused (2KB Wl), consume part[0], fp32 in, bf16 out
    k_fused<16, 32, 4, 1, 0, 1, 0, 1, 16><<<NBF, B, 0, stream>>>(
        buf2, ptr, csr, dis, part + 0 * PARTSZ, gm[0], bt[0],
        W[1], b[1], part + 1 * PARTSZ, bufB1, NN);

    // L3 UNFUSED (fused was 45.6us @ 31% occ): gather32 (BN2 hoisted) then gemm 32->64
    k_sgather<32, 1, 0><<<(int)(((long)NN * 32 + 255) / 256), B, 0, stream>>>(
        bufB1, ptr, csr, dis, part + 1 * PARTSZ, gm[1], bt[1], buf1, NN);
    k_sgemm<32, 64, 1, 1><<<(NN + 63) / 64, B, 0, stream>>>(buf1, W[2], b[2], part + 2 * PARTSZ, bufB2, NN);

    // L4 UNFUSED: gather64 (BN3 hoisted) then gemm 64->64
    k_sgather<64, 1, 0><<<(int)(((long)NN * 64 + 255) / 256), B, 0, stream>>>(
        bufB2, ptr, csr, dis, part + 2 * PARTSZ, gm[2], bt[2], buf1, NN);
    k_sgemm<64, 64, 0, 1><<<(NN + 63) / 64, B, 0, stream>>>(buf1, W[3], b[3], part + 3 * PARTSZ, bufB1, NN);

    // L5 UNFUSED: gather64 (per-edge relu(BN4)) then gemm 64->128
    k_sgather<64, 0, 1><<<(int)(((long)NN * 64 + 255) / 256), B, 0, stream>>>(
        bufB1, ptr, csr, dis, part + 3 * PARTSZ, gm[3], bt[3], buf1, NN);
    k_sgemm<64, 128, 0, 0><<<(NN + 31) / 32, B, 0, stream>>>(buf1, W[4], b[4], part + 4 * PARTSZ, buf2, NN);

    // fused pool (consume part[4] -> BN5) + head
    k_poolhead<<<NG, B, 0, stream>>>(buf2, batch, part + 4 * PARTSZ, gm[4], bt[4],
                                     fc1w, fc1b, fc2w, fc2b, out, NN);
}